// Round 11
// baseline (871.907 us; speedup 1.0000x reference)
//
#include <hip/hip_runtime.h>
#include <math.h>

#define NN 30000
#define PP 8
#define DM 128
#define EE 1000
#define NNZC 120000
#define DIN (PP*DM)   // 1024

typedef __attribute__((ext_vector_type(8))) short bf16x8;
typedef __attribute__((ext_vector_type(4))) float f32x4;

__device__ __forceinline__ short f2bf(float f) {
    union { float f; unsigned u; } v; v.f = f;
    unsigned r = v.u + 0x7fffu + ((v.u >> 16) & 1u);
    return (short)(r >> 16);
}
__device__ __forceinline__ float bf2f(short s) {
    union { unsigned u; float f; } v;
    v.u = ((unsigned)(unsigned short)s) << 16;
    return v.f;
}

// ---------------------------------------------------------------- CSR build
__global__ void count_kernel(const int* __restrict__ ei, const int* __restrict__ ni,
                             int* __restrict__ ecnt, int* __restrict__ ncnt) {
    int k = blockIdx.x * 256 + threadIdx.x;
    if (k >= NNZC) return;
    atomicAdd(&ecnt[ei[k]], 1);
    atomicAdd(&ncnt[ni[k]], 1);
}

__global__ __launch_bounds__(1024)
void scan_two(const int* __restrict__ ecnt, int* __restrict__ eoff,
              const int* __restrict__ ncnt, int* __restrict__ noff) {
    const int* cnt; int* off; int len;
    if (blockIdx.x == 0) { cnt = ecnt; off = eoff; len = EE; }
    else                 { cnt = ncnt; off = noff; len = NN; }
    __shared__ int wsum[16];
    __shared__ int carrysh;
    int t = threadIdx.x;
    int lane = t & 63, w = t >> 6;
    if (t == 0) carrysh = 0;
    __syncthreads();
    for (int base = 0; base < len; base += 1024) {
        int v = (base + t < len) ? cnt[base + t] : 0;
        int s = v;
        #pragma unroll
        for (int d = 1; d < 64; d <<= 1) {
            int u = __shfl_up(s, d);
            if (lane >= d) s += u;
        }
        if (lane == 63) wsum[w] = s;
        __syncthreads();
        if (t < 16) {
            int ws = wsum[t];
            #pragma unroll
            for (int d = 1; d < 16; d <<= 1) {
                int u = __shfl_up(ws, d);
                if (t >= d) ws += u;
            }
            wsum[t] = ws;
        }
        __syncthreads();
        int c = carrysh;
        int woff = (w > 0) ? wsum[w - 1] : 0;
        if (base + t < len) off[base + t] = c + woff + s - v;
        int total = wsum[15];
        __syncthreads();
        if (t == 0) carrysh = c + total;
    }
    __syncthreads();
    if (t == 0) off[len] = carrysh;
}

__global__ void fill_lists(const int* __restrict__ ei, const int* __restrict__ ni,
                           const int* __restrict__ eoff, const int* __restrict__ noff,
                           int* __restrict__ ecur, int* __restrict__ ncur,
                           int* __restrict__ elist, int* __restrict__ nlist) {
    int k = blockIdx.x * 256 + threadIdx.x;
    if (k >= NNZC) return;
    int e = ei[k];
    int p = atomicAdd(&ecur[e], 1);
    elist[eoff[e] + p] = k;
    int n = ni[k];
    int q = atomicAdd(&ncur[n], 1);
    nlist[noff[n] + q] = k;
}

// ---------------------------------------------------------------- weight transpose+convert
__global__ void transpose_to_bf16(const float* __restrict__ B, short* __restrict__ BT,
                                  int K, int N) {
    __shared__ float tile[32][33];
    int bn = blockIdx.x * 32, bk = blockIdx.y * 32;
    int tx = threadIdx.x & 31, ty = threadIdx.x >> 5;
    #pragma unroll
    for (int yy = ty; yy < 32; yy += 8) {
        int k = bk + yy, n = bn + tx;
        tile[yy][tx] = (k < K && n < N) ? B[(size_t)k * N + n] : 0.f;
    }
    __syncthreads();
    #pragma unroll
    for (int yy = ty; yy < 32; yy += 8) {
        int n = bn + yy, k = bk + tx;
        if (n < N && k < K) BT[(size_t)n * K + k] = f2bf(tile[tx][yy]);
    }
}

// ---------------------------------------------------------------- f32 -> bf16 bulk convert
__global__ void cvt_f2b(const float* __restrict__ in, short* __restrict__ outb, long long total4) {
    long long idx = (long long)blockIdx.x * 256 + threadIdx.x;
    long long stride = (long long)gridDim.x * 256;
    const float4* i4 = (const float4*)in;
    short4* o4 = (short4*)outb;
    for (; idx < total4; idx += stride) {
        float4 v = i4[idx];
        o4[idx] = make_short4(f2bf(v.x), f2bf(v.y), f2bf(v.z), f2bf(v.w));
    }
}

// ---------------------------------------------------------------- bf16 MFMA GEMM  (R10 structure, bf16 A/src)
// C[M,Nc] = A[M,K](bf16) @ B^T[Nc,K](bf16)  [+bias][leaky][+bf16 src][BN-stats]
// BM=BN=128, BK=32, 4 waves (2x2 of 64x64), 16x16x32 MFMA, f32 accum.
// Epilogue: wave-coalesced register stores (lane&15 -> consecutive cols).
template<bool HASBIAS, bool LEAKY, bool ADDSRC, bool STATS, bool OUTBF16>
__global__ __launch_bounds__(256)
void gemm_mfma(const short* __restrict__ A, const short* __restrict__ BT,
               const float* __restrict__ bias, const short* __restrict__ srcb,
               void* __restrict__ Cout, float* __restrict__ accum, int M, int K, int Nc) {
    __shared__ short As[128 * 40];   // row stride 40 shorts (80B): bank-uniform
    __shared__ short Bs[128 * 40];
    const int tid = threadIdx.x;
    const int lane = tid & 63, wid = tid >> 6;
    const int wm = wid >> 1, wn = wid & 1;
    const int row0 = blockIdx.y * 128, col0 = blockIdx.x * 128;
    const int srow = tid >> 2, skq = tid & 3;

    f32x4 acc[4][4] = {};
    const int NT = K >> 5;

    struct Stage { bf16x8 a[2]; bf16x8 b[2]; };
    Stage s0, s1;

    auto loadT = [&](int t, Stage& s) {
        int k0 = t << 5;
        #pragma unroll
        for (int c = 0; c < 2; ++c) {
            int gr = row0 + srow + 64 * c;
            s.a[c] = bf16x8{0, 0, 0, 0, 0, 0, 0, 0};
            if (gr < M)
                s.a[c] = *(const bf16x8*)(A + (size_t)gr * K + k0 + skq * 8);
            int gc = col0 + srow + 64 * c;
            s.b[c] = *(const bf16x8*)(BT + (size_t)gc * K + k0 + skq * 8);
        }
    };
    auto writeT = [&](Stage& s) {
        #pragma unroll
        for (int c = 0; c < 2; ++c) {
            *(bf16x8*)&As[(srow + 64 * c) * 40 + skq * 8] = s.a[c];
            *(bf16x8*)&Bs[(srow + 64 * c) * 40 + skq * 8] = s.b[c];
        }
    };
    auto compute = [&]() {
        bf16x8 av[4], bv[4];
        #pragma unroll
        for (int i = 0; i < 4; ++i)
            av[i] = *(const bf16x8*)&As[(wm * 64 + i * 16 + (lane & 15)) * 40 + (lane >> 4) * 8];
        #pragma unroll
        for (int j = 0; j < 4; ++j)
            bv[j] = *(const bf16x8*)&Bs[(wn * 64 + j * 16 + (lane & 15)) * 40 + (lane >> 4) * 8];
        #pragma unroll
        for (int i = 0; i < 4; ++i)
            #pragma unroll
            for (int j = 0; j < 4; ++j)
                acc[i][j] = __builtin_amdgcn_mfma_f32_16x16x32_bf16(av[i], bv[j], acc[i][j], 0, 0, 0);
    };

    loadT(0, s0);
    for (int t = 0; t < NT; t += 2) {
        __syncthreads();
        loadT(t + 1, s1);
        writeT(s0);
        __syncthreads();
        compute();
        __syncthreads();
        if (t + 2 < NT) loadT(t + 2, s0);
        writeT(s1);
        __syncthreads();
        compute();
    }

    // epilogue: C/D layout col=lane&15 (consecutive across lanes -> wave-coalesced),
    // row=(lane>>4)*4+q
    float* Cf = (float*)Cout;
    short* Cb = (short*)Cout;
    float lsum[4] = {0.f, 0.f, 0.f, 0.f}, lsq[4] = {0.f, 0.f, 0.f, 0.f};
    #pragma unroll
    for (int i = 0; i < 4; ++i) {
        #pragma unroll
        for (int q = 0; q < 4; ++q) {
            int row = row0 + wm * 64 + i * 16 + (lane >> 4) * 4 + q;
            if (row < M) {
                #pragma unroll
                for (int j = 0; j < 4; ++j) {
                    int col = col0 + wn * 64 + j * 16 + (lane & 15);
                    float val = acc[i][j][q];
                    if (HASBIAS) val += bias[col];
                    if (LEAKY)   val = val > 0.f ? val : 0.2f * val;
                    if (ADDSRC)  val += bf2f(srcb[(size_t)row * Nc + col]);
                    if (STATS) { lsum[j] += val; lsq[j] += val * val; }
                    if (OUTBF16) Cb[(size_t)row * Nc + col] = f2bf(val);
                    else         Cf[(size_t)row * Nc + col] = val;
                }
            }
        }
    }
    if (STATS) {
        __syncthreads();                  // done with As
        float* sred = (float*)As;         // 256 floats scratch
        sred[tid] = 0.f;
        __syncthreads();
        int ch = wn * 64 + (lane & 15);   // channel = in-block col (col0 % 128 == 0)
        #pragma unroll
        for (int j = 0; j < 4; ++j) {
            atomicAdd(&sred[ch + j * 16], lsum[j]);
            atomicAdd(&sred[128 + ch + j * 16], lsq[j]);
        }
        __syncthreads();
        atomicAdd(&accum[tid], sred[tid]);
    }
}

// ---------------------------------------------------------------- BatchNorm stats (float4)
__global__ void bn_stats(const float* __restrict__ a, long long total4, float* __restrict__ accum) {
    int t = threadIdx.x;
    long long idx = (long long)blockIdx.x * 256 + t;
    long long stride = (long long)gridDim.x * 256;
    const float4* a4 = (const float4*)a;
    float s1[4] = {0.f,0.f,0.f,0.f}, s2[4] = {0.f,0.f,0.f,0.f};
    for (; idx < total4; idx += stride) {
        float4 v = a4[idx];
        s1[0] += v.x; s2[0] += v.x * v.x;
        s1[1] += v.y; s2[1] += v.y * v.y;
        s1[2] += v.z; s2[2] += v.z * v.z;
        s1[3] += v.w; s2[3] += v.w * v.w;
    }
    __shared__ float r1[256][4], r2[256][4];
    #pragma unroll
    for (int k = 0; k < 4; ++k) { r1[t][k] = s1[k]; r2[t][k] = s2[k]; }
    __syncthreads();
    if (t < 32) {
        #pragma unroll
        for (int k = 0; k < 4; ++k) {
            float a1 = 0.f, a2 = 0.f;
            #pragma unroll
            for (int u = 0; u < 8; ++u) { a1 += r1[t + u * 32][k]; a2 += r2[t + u * 32][k]; }
            atomicAdd(&accum[t * 4 + k], a1);
            atomicAdd(&accum[128 + t * 4 + k], a2);
        }
    }
}

// ---------------------------------------------------------------- BN finalize+apply (f32 in/out, optional bf16 shadow)
template<bool SHADOW>
__global__ void bn_apply_f(float* __restrict__ a, short* __restrict__ shadow, long long total4,
                           const float* __restrict__ accum, const float* __restrict__ g,
                           const float* __restrict__ b, float invM) {
    __shared__ float scs[256];
    int t = threadIdx.x;
    if (t < 128) {
        float mean = accum[t] * invM;
        float var = accum[128 + t] * invM - mean * mean;
        float s = g[t] * rsqrtf(var + 1e-5f);
        scs[t] = s;
        scs[128 + t] = b[t] - mean * s;
    }
    __syncthreads();
    long long idx = (long long)blockIdx.x * 256 + t;
    long long stride = (long long)gridDim.x * 256;
    float4* a4 = (float4*)a;
    short4* s4p = (short4*)shadow;
    for (; idx < total4; idx += stride) {
        int c = (int)((idx & 31) * 4);
        float4 v = a4[idx];
        v.x = v.x * scs[c + 0] + scs[128 + c + 0];
        v.y = v.y * scs[c + 1] + scs[128 + c + 1];
        v.z = v.z * scs[c + 2] + scs[128 + c + 2];
        v.w = v.w * scs[c + 3] + scs[128 + c + 3];
        a4[idx] = v;
        if (SHADOW)
            s4p[idx] = make_short4(f2bf(v.x), f2bf(v.y), f2bf(v.z), f2bf(v.w));
    }
}

// ---------------------------------------------------------------- BN apply bf16 -> f32
__global__ void bn_apply_b2f(const short* __restrict__ inb, float* __restrict__ outp,
                             long long total4, const float* __restrict__ accum,
                             const float* __restrict__ g, const float* __restrict__ b, float invM) {
    __shared__ float scs[256];
    int t = threadIdx.x;
    if (t < 128) {
        float mean = accum[t] * invM;
        float var = accum[128 + t] * invM - mean * mean;
        float s = g[t] * rsqrtf(var + 1e-5f);
        scs[t] = s;
        scs[128 + t] = b[t] - mean * s;
    }
    __syncthreads();
    long long idx = (long long)blockIdx.x * 256 + t;
    long long stride = (long long)gridDim.x * 256;
    const short4* in4 = (const short4*)inb;
    float4* o4 = (float4*)outp;
    for (; idx < total4; idx += stride) {
        int c = (int)((idx & 31) * 4);
        short4 sv = in4[idx];
        float4 v;
        v.x = bf2f(sv.x) * scs[c + 0] + scs[128 + c + 0];
        v.y = bf2f(sv.y) * scs[c + 1] + scs[128 + c + 1];
        v.z = bf2f(sv.z) * scs[c + 2] + scs[128 + c + 2];
        v.w = bf2f(sv.w) * scs[c + 3] + scs[128 + c + 3];
        o4[idx] = v;
    }
}

// ---------------------------------------------------------------- he_attr[e] = sum_{k in edge e} h[node_idx[k]]
__global__ void edge_feat(const int* __restrict__ elist, const int* __restrict__ eoff,
                          const int* __restrict__ nidx, const float* __restrict__ h,
                          float* __restrict__ he, short* __restrict__ heb) {
    int e = blockIdx.x;
    int off = eoff[e], cnt = eoff[e + 1] - off;
    int d = threadIdx.x;  // 128
    float acc = 0.f;
    for (int p = 0; p < cnt; ++p) {
        int k = elist[off + p];
        int n = nidx[k];
        acc += h[(size_t)n * 128 + d];
    }
    he[(size_t)e * 128 + d] = acc;
    heb[(size_t)e * 128 + d] = f2bf(acc);
}

// ---------------------------------------------------------------- attention dots
template<int H>
__global__ void att_dots(const float* __restrict__ feat, const float* __restrict__ att,
                         int attOff, float* __restrict__ out, int M) {
    int wid = threadIdx.x >> 6;
    int lane = threadIdx.x & 63;
    int row = blockIdx.x * 4 + wid;
    if (row >= M) return;
    #pragma unroll
    for (int h = 0; h < H; ++h) {
        const float* fr = feat + (size_t)row * (H * 128) + h * 128;
        const float* ar = att + h * 256 + attOff;
        float v = fr[lane] * ar[lane] + fr[lane + 64] * ar[lane + 64];
        #pragma unroll
        for (int s = 32; s > 0; s >>= 1) v += __shfl_xor(v, s);
        if (lane == 0) out[(size_t)row * H + h] = v;
    }
}

// ---------------------------------------------------------------- per-edge segment softmax
template<int H>
__global__ void edge_softmax(const int* __restrict__ elist, const int* __restrict__ eoff,
                             const int* __restrict__ nidx, const float* __restrict__ ax,
                             const float* __restrict__ ae, float* __restrict__ alpha) {
    constexpr int SLOTS = 256 / H;
    __shared__ float red[256];
    int e = blockIdx.x;
    int off = eoff[e], cnt = eoff[e + 1] - off;
    int t = threadIdx.x;
    int h = t % H, slot = t / H;
    float aeh = ae[(size_t)e * H + h];
    float lmax = -1e30f;
    for (int p = slot; p < cnt; p += SLOTS) {
        int k = elist[off + p];
        int n = nidx[k];
        float v = ax[(size_t)n * H + h] + aeh;
        v = v > 0.f ? v : 0.2f * v;
        alpha[(size_t)k * H + h] = v;
        lmax = fmaxf(lmax, v);
    }
    red[t] = lmax;
    __syncthreads();
    for (int s = SLOTS / 2; s > 0; s >>= 1) {
        if (slot < s) red[slot * H + h] = fmaxf(red[slot * H + h], red[(slot + s) * H + h]);
        __syncthreads();
    }
    float m = red[h];
    __syncthreads();
    float lsum = 0.f;
    for (int p = slot; p < cnt; p += SLOTS) {
        int k = elist[off + p];
        float ex = expf(alpha[(size_t)k * H + h] - m);
        alpha[(size_t)k * H + h] = ex;
        lsum += ex;
    }
    red[t] = lsum;
    __syncthreads();
    for (int s = SLOTS / 2; s > 0; s >>= 1) {
        if (slot < s) red[slot * H + h] += red[(slot + s) * H + h];
        __syncthreads();
    }
    float inv = 1.0f / (red[h] + 1e-16f);
    for (int p = slot; p < cnt; p += SLOTS) {
        int k = elist[off + p];
        alpha[(size_t)k * H + h] *= inv;
    }
}

// ---------------------------------------------------------------- out_e
template<int H>
__global__ void edge_aggregate(const int* __restrict__ elist, const int* __restrict__ eoff,
                               const int* __restrict__ nidx, const float* __restrict__ alpha,
                               const float* __restrict__ xh, float* __restrict__ out_e) {
    int e = blockIdx.x;
    int off = eoff[e], cnt = eoff[e + 1] - off;
    int t = threadIdx.x;            // H*128 threads
    int h = t >> 7;
    float acc = 0.f;
    for (int p = 0; p < cnt; ++p) {
        int k = elist[off + p];
        int n = nidx[k];
        acc += alpha[(size_t)k * H + h] * xh[(size_t)n * (H * 128) + t];
    }
    float binv = cnt > 0 ? 1.0f / (float)cnt : 0.0f;
    out_e[(size_t)e * (H * 128) + t] = acc * binv;
}

// ---------------------------------------------------------------- node side
template<int H>
__global__ void node_aggregate(const int* __restrict__ nlist, const int* __restrict__ noff,
                               const int* __restrict__ eidx, const float* __restrict__ alpha,
                               const float* __restrict__ out_e, const float* __restrict__ bias,
                               float* __restrict__ hout) {
    __shared__ float red[H * 128];
    int n = blockIdx.x;
    int off = noff[n], cnt = noff[n + 1] - off;
    int t = threadIdx.x;            // H*128 threads
    int h = t >> 7;
    float acc = 0.f;
    for (int p = 0; p < cnt; ++p) {
        int k = nlist[off + p];
        int e = eidx[k];
        acc += alpha[(size_t)k * H + h] * out_e[(size_t)e * (H * 128) + t];
    }
    float dinv = cnt > 0 ? 1.0f / (float)cnt : 0.0f;
    acc *= dinv;
    if (H == 1) {
        hout[(size_t)n * 128 + t] += acc + bias[t];
    } else {
        red[t] = acc;
        __syncthreads();
        if (t < 128) {
            float s = 0.f;
            #pragma unroll
            for (int hh = 0; hh < H; ++hh) s += red[hh * 128 + t];
            hout[(size_t)n * 128 + t] += s * (1.0f / H) + bias[t];
        }
    }
}

// ---------------------------------------------------------------- launch
extern "C" void kernel_launch(void* const* d_in, const int* in_sizes, int n_in,
                              void* d_out, int out_size, void* d_ws, size_t ws_size,
                              hipStream_t stream) {
    (void)in_sizes; (void)n_in; (void)out_size; (void)ws_size;
    const float* x        = (const float*)d_in[0];
    const int*   node_idx = (const int*)d_in[1];
    const int*   edge_idx = (const int*)d_in[2];
    const float* W1    = (const float*)d_in[4];
    const float* b1    = (const float*)d_in[5];
    const float* bn1_g = (const float*)d_in[6];
    const float* bn1_b = (const float*)d_in[7];
    const float* h1_lin  = (const float*)d_in[8];
    const float* h1_att  = (const float*)d_in[9];
    const float* h1_bias = (const float*)d_in[10];
    const float* bn2_g = (const float*)d_in[11];
    const float* bn2_b = (const float*)d_in[12];
    const float* h2_lin  = (const float*)d_in[13];
    const float* h2_att  = (const float*)d_in[14];
    const float* h2_bias = (const float*)d_in[15];
    const float* bn3_g = (const float*)d_in[16];
    const float* bn3_b = (const float*)d_in[17];
    const float* W2    = (const float*)d_in[18];
    const float* b2    = (const float*)d_in[19];
    const float* bn4_g = (const float*)d_in[20];
    const float* bn4_b = (const float*)d_in[21];
    float* out = (float*)d_out;

    char* ws = (char*)d_ws;
    size_t off = 0;
    auto alloc = [&](size_t bytes) -> void* {
        void* p = ws + off;
        off = (off + bytes + 255) & ~(size_t)255;
        return p;
    };
    float* h     = (float*)alloc((size_t)NN * 128 * 4);
    float* xh    = (float*)alloc((size_t)NN * 512 * 4);
    float* he    = (float*)alloc((size_t)EE * 128 * 4);
    float* eh    = (float*)alloc((size_t)EE * 512 * 4);
    float* oute  = (float*)alloc((size_t)EE * 512 * 4);
    float* ax    = (float*)alloc((size_t)NN * 4 * 4);
    float* ae    = (float*)alloc((size_t)EE * 4 * 4);
    float* alpha = (float*)alloc((size_t)NNZC * 4 * 4);
    float* accum = (float*)alloc(256 * 4);
    short* hb    = (short*)alloc((size_t)NN * 128 * 2);    // bf16 shadow of h
    short* heb   = (short*)alloc((size_t)EE * 128 * 2);    // bf16 shadow of he
    short* W1T   = (short*)alloc((size_t)128 * DIN * 2);
    short* h1T   = (short*)alloc((size_t)512 * 128 * 2);
    short* h2T   = (short*)alloc((size_t)128 * 128 * 2);
    short* W2T   = (short*)alloc((size_t)DIN * 128 * 2);
    int* ecnt  = (int*)alloc(EE * 4);
    int* eoff  = (int*)alloc((EE + 1) * 4);
    int* ecur  = (int*)alloc(EE * 4);
    int* elist = (int*)alloc(NNZC * 4);
    int* ncnt  = (int*)alloc(NN * 4);
    int* noff  = (int*)alloc((NN + 1) * 4);
    int* ncur  = (int*)alloc(NN * 4);
    int* nlist = (int*)alloc(NNZC * 4);

    short* xb   = (short*)d_out;   // bf16 copy of x in dead space of d_out
    short* outb = (short*)xh;      // pre-BN4 bf16 scratch (xh dead by then)

    hipMemsetAsync(ecnt, 0, EE * 4, stream);
    hipMemsetAsync(ncnt, 0, NN * 4, stream);
    hipMemsetAsync(ecur, 0, EE * 4, stream);
    hipMemsetAsync(ncur, 0, NN * 4, stream);

    count_kernel<<<(NNZC + 255) / 256, 256, 0, stream>>>(edge_idx, node_idx, ecnt, ncnt);
    cvt_f2b<<<2048, 256, 0, stream>>>(x, xb, (long long)NN * DIN / 4);
    transpose_to_bf16<<<dim3(4, 32), 256, 0, stream>>>(W1, W1T, DIN, 128);
    transpose_to_bf16<<<dim3(16, 4), 256, 0, stream>>>(h1_lin, h1T, 128, 512);
    transpose_to_bf16<<<dim3(4, 4), 256, 0, stream>>>(h2_lin, h2T, 128, 128);
    transpose_to_bf16<<<dim3(32, 4), 256, 0, stream>>>(W2, W2T, 128, DIN);
    scan_two<<<2, 1024, 0, stream>>>(ecnt, eoff, ncnt, noff);
    fill_lists<<<(NNZC + 255) / 256, 256, 0, stream>>>(edge_idx, node_idx, eoff, noff,
                                                       ecur, ncur, elist, nlist);

    const int MB = (NN + 127) / 128;   // 235

    // h = leaky(xb @ W1 + b1)   [MFMA + BN1 stats fused]
    hipMemsetAsync(accum, 0, 256 * 4, stream);
    gemm_mfma<true, true, false, true, false><<<dim3(1, MB), 256, 0, stream>>>(
        xb, W1T, b1, nullptr, h, accum, NN, DIN, 128);
    bn_apply_f<true><<<1024, 256, 0, stream>>>(h, hb, (long long)NN * 128 / 4, accum,
                                               bn1_g, bn1_b, 1.0f / NN);

    // ---- hconv1 (heads=4) ----
    edge_feat<<<EE, 128, 0, stream>>>(elist, eoff, node_idx, h, he, heb);
    gemm_mfma<false, false, false, false, false><<<dim3(4, MB), 256, 0, stream>>>(
        hb, h1T, nullptr, nullptr, xh, nullptr, NN, 128, 512);
    gemm_mfma<false, false, false, false, false><<<dim3(4, 8), 256, 0, stream>>>(
        heb, h1T, nullptr, nullptr, eh, nullptr, EE, 128, 512);
    att_dots<4><<<(NN + 3) / 4, 256, 0, stream>>>(xh, h1_att, 0, ax, NN);
    att_dots<4><<<(EE + 3) / 4, 256, 0, stream>>>(eh, h1_att, 128, ae, EE);
    edge_softmax<4><<<EE, 256, 0, stream>>>(elist, eoff, node_idx, ax, ae, alpha);
    edge_aggregate<4><<<EE, 512, 0, stream>>>(elist, eoff, node_idx, alpha, xh, oute);
    node_aggregate<4><<<NN, 512, 0, stream>>>(nlist, noff, edge_idx, alpha, oute, h1_bias, h);

    // BN2
    hipMemsetAsync(accum, 0, 256 * 4, stream);
    bn_stats<<<512, 256, 0, stream>>>(h, (long long)NN * 128 / 4, accum);
    bn_apply_f<true><<<1024, 256, 0, stream>>>(h, hb, (long long)NN * 128 / 4, accum,
                                               bn2_g, bn2_b, 1.0f / NN);

    // ---- hconv2 (heads=1) ----
    edge_feat<<<EE, 128, 0, stream>>>(elist, eoff, node_idx, h, he, heb);
    gemm_mfma<false, false, false, false, false><<<dim3(1, MB), 256, 0, stream>>>(
        hb, h2T, nullptr, nullptr, xh, nullptr, NN, 128, 128);
    gemm_mfma<false, false, false, false, false><<<dim3(1, 8), 256, 0, stream>>>(
        heb, h2T, nullptr, nullptr, eh, nullptr, EE, 128, 128);
    att_dots<1><<<(NN + 3) / 4, 256, 0, stream>>>(xh, h2_att, 0, ax, NN);
    att_dots<1><<<(EE + 3) / 4, 256, 0, stream>>>(eh, h2_att, 128, ae, EE);
    edge_softmax<1><<<EE, 256, 0, stream>>>(elist, eoff, node_idx, ax, ae, alpha);
    edge_aggregate<1><<<EE, 128, 0, stream>>>(elist, eoff, node_idx, alpha, xh, oute);
    node_aggregate<1><<<NN, 128, 0, stream>>>(nlist, noff, edge_idx, alpha, oute, h2_bias, h);

    // BN3 (shadow feeds W2)
    hipMemsetAsync(accum, 0, 256 * 4, stream);
    bn_stats<<<512, 256, 0, stream>>>(h, (long long)NN * 128 / 4, accum);
    bn_apply_f<true><<<1024, 256, 0, stream>>>(h, hb, (long long)NN * 128 / 4, accum,
                                               bn3_g, bn3_b, 1.0f / NN);

    // out_pre = xb + leaky(hb @ W2 + b2) -> bf16 scratch [MFMA + BN4 stats fused]
    hipMemsetAsync(accum, 0, 256 * 4, stream);
    gemm_mfma<true, true, true, true, true><<<dim3(8, MB), 256, 0, stream>>>(
        hb, W2T, b2, xb, outb, accum, NN, 128, DIN);

    // BN4: bf16 -> f32 out (overwrites all of d_out incl. xb scratch)
    bn_apply_b2f<<<2048, 256, 0, stream>>>(outb, out, (long long)NN * DIN / 4, accum,
                                           bn4_g, bn4_b, 1.0f / (NN * PP));
}

// Round 12
// 865.832 us; speedup vs baseline: 1.0070x; 1.0070x over previous
//
#include <hip/hip_runtime.h>
#include <math.h>

#define NN 30000
#define PP 8
#define DM 128
#define EE 1000
#define NNZC 120000
#define DIN (PP*DM)   // 1024

typedef __attribute__((ext_vector_type(8))) short bf16x8;
typedef __attribute__((ext_vector_type(4))) float f32x4;

__device__ __forceinline__ short f2bf(float f) {
    union { float f; unsigned u; } v; v.f = f;
    unsigned r = v.u + 0x7fffu + ((v.u >> 16) & 1u);
    return (short)(r >> 16);
}
__device__ __forceinline__ float bf2f(short s) {
    union { unsigned u; float f; } v;
    v.u = ((unsigned)(unsigned short)s) << 16;
    return v.f;
}

// ---------------------------------------------------------------- CSR build
__global__ void count_kernel(const int* __restrict__ ei, const int* __restrict__ ni,
                             int* __restrict__ ecnt, int* __restrict__ ncnt) {
    int k = blockIdx.x * 256 + threadIdx.x;
    if (k >= NNZC) return;
    atomicAdd(&ecnt[ei[k]], 1);
    atomicAdd(&ncnt[ni[k]], 1);
}

__global__ __launch_bounds__(1024)
void scan_two(const int* __restrict__ ecnt, int* __restrict__ eoff,
              const int* __restrict__ ncnt, int* __restrict__ noff) {
    const int* cnt; int* off; int len;
    if (blockIdx.x == 0) { cnt = ecnt; off = eoff; len = EE; }
    else                 { cnt = ncnt; off = noff; len = NN; }
    __shared__ int wsum[16];
    __shared__ int carrysh;
    int t = threadIdx.x;
    int lane = t & 63, w = t >> 6;
    if (t == 0) carrysh = 0;
    __syncthreads();
    for (int base = 0; base < len; base += 1024) {
        int v = (base + t < len) ? cnt[base + t] : 0;
        int s = v;
        #pragma unroll
        for (int d = 1; d < 64; d <<= 1) {
            int u = __shfl_up(s, d);
            if (lane >= d) s += u;
        }
        if (lane == 63) wsum[w] = s;
        __syncthreads();
        if (t < 16) {
            int ws = wsum[t];
            #pragma unroll
            for (int d = 1; d < 16; d <<= 1) {
                int u = __shfl_up(ws, d);
                if (t >= d) ws += u;
            }
            wsum[t] = ws;
        }
        __syncthreads();
        int c = carrysh;
        int woff = (w > 0) ? wsum[w - 1] : 0;
        if (base + t < len) off[base + t] = c + woff + s - v;
        int total = wsum[15];
        __syncthreads();
        if (t == 0) carrysh = c + total;
    }
    __syncthreads();
    if (t == 0) off[len] = carrysh;
}

__global__ void fill_lists(const int* __restrict__ ei, const int* __restrict__ ni,
                           const int* __restrict__ eoff, const int* __restrict__ noff,
                           int* __restrict__ ecur, int* __restrict__ ncur,
                           int* __restrict__ elist, int* __restrict__ nlist) {
    int k = blockIdx.x * 256 + threadIdx.x;
    if (k >= NNZC) return;
    int e = ei[k];
    int p = atomicAdd(&ecur[e], 1);
    elist[eoff[e] + p] = k;
    int n = ni[k];
    int q = atomicAdd(&ncur[n], 1);
    nlist[noff[n] + q] = k;
}

// ---------------------------------------------------------------- weight transpose+convert
__global__ void transpose_to_bf16(const float* __restrict__ B, short* __restrict__ BT,
                                  int K, int N) {
    __shared__ float tile[32][33];
    int bn = blockIdx.x * 32, bk = blockIdx.y * 32;
    int tx = threadIdx.x & 31, ty = threadIdx.x >> 5;
    #pragma unroll
    for (int yy = ty; yy < 32; yy += 8) {
        int k = bk + yy, n = bn + tx;
        tile[yy][tx] = (k < K && n < N) ? B[(size_t)k * N + n] : 0.f;
    }
    __syncthreads();
    #pragma unroll
    for (int yy = ty; yy < 32; yy += 8) {
        int n = bn + yy, k = bk + tx;
        if (n < N && k < K) BT[(size_t)n * K + k] = f2bf(tile[tx][yy]);
    }
}

// ---------------------------------------------------------------- f32 -> bf16 bulk convert
__global__ void cvt_f2b(const float* __restrict__ in, short* __restrict__ outb, long long total4) {
    long long idx = (long long)blockIdx.x * 256 + threadIdx.x;
    long long stride = (long long)gridDim.x * 256;
    const float4* i4 = (const float4*)in;
    short4* o4 = (short4*)outb;
    for (; idx < total4; idx += stride) {
        float4 v = i4[idx];
        o4[idx] = make_short4(f2bf(v.x), f2bf(v.y), f2bf(v.z), f2bf(v.w));
    }
}

// ---------------------------------------------------------------- bf16 MFMA GEMM  (R10/R11 structure)
template<bool HASBIAS, bool LEAKY, bool ADDSRC, bool STATS, bool OUTBF16>
__global__ __launch_bounds__(256)
void gemm_mfma(const short* __restrict__ A, const short* __restrict__ BT,
               const float* __restrict__ bias, const short* __restrict__ srcb,
               void* __restrict__ Cout, float* __restrict__ accum, int M, int K, int Nc) {
    __shared__ short As[128 * 40];   // row stride 40 shorts (80B): bank-uniform
    __shared__ short Bs[128 * 40];
    const int tid = threadIdx.x;
    const int lane = tid & 63, wid = tid >> 6;
    const int wm = wid >> 1, wn = wid & 1;
    const int row0 = blockIdx.y * 128, col0 = blockIdx.x * 128;
    const int srow = tid >> 2, skq = tid & 3;

    f32x4 acc[4][4] = {};
    const int NT = K >> 5;

    struct Stage { bf16x8 a[2]; bf16x8 b[2]; };
    Stage s0, s1;

    auto loadT = [&](int t, Stage& s) {
        int k0 = t << 5;
        #pragma unroll
        for (int c = 0; c < 2; ++c) {
            int gr = row0 + srow + 64 * c;
            s.a[c] = bf16x8{0, 0, 0, 0, 0, 0, 0, 0};
            if (gr < M)
                s.a[c] = *(const bf16x8*)(A + (size_t)gr * K + k0 + skq * 8);
            int gc = col0 + srow + 64 * c;
            s.b[c] = *(const bf16x8*)(BT + (size_t)gc * K + k0 + skq * 8);
        }
    };
    auto writeT = [&](Stage& s) {
        #pragma unroll
        for (int c = 0; c < 2; ++c) {
            *(bf16x8*)&As[(srow + 64 * c) * 40 + skq * 8] = s.a[c];
            *(bf16x8*)&Bs[(srow + 64 * c) * 40 + skq * 8] = s.b[c];
        }
    };
    auto compute = [&]() {
        bf16x8 av[4], bv[4];
        #pragma unroll
        for (int i = 0; i < 4; ++i)
            av[i] = *(const bf16x8*)&As[(wm * 64 + i * 16 + (lane & 15)) * 40 + (lane >> 4) * 8];
        #pragma unroll
        for (int j = 0; j < 4; ++j)
            bv[j] = *(const bf16x8*)&Bs[(wn * 64 + j * 16 + (lane & 15)) * 40 + (lane >> 4) * 8];
        #pragma unroll
        for (int i = 0; i < 4; ++i)
            #pragma unroll
            for (int j = 0; j < 4; ++j)
                acc[i][j] = __builtin_amdgcn_mfma_f32_16x16x32_bf16(av[i], bv[j], acc[i][j], 0, 0, 0);
    };

    loadT(0, s0);
    for (int t = 0; t < NT; t += 2) {
        __syncthreads();
        loadT(t + 1, s1);
        writeT(s0);
        __syncthreads();
        compute();
        __syncthreads();
        if (t + 2 < NT) loadT(t + 2, s0);
        writeT(s1);
        __syncthreads();
        compute();
    }

    float* Cf = (float*)Cout;
    short* Cb = (short*)Cout;
    float lsum[4] = {0.f, 0.f, 0.f, 0.f}, lsq[4] = {0.f, 0.f, 0.f, 0.f};
    #pragma unroll
    for (int i = 0; i < 4; ++i) {
        #pragma unroll
        for (int q = 0; q < 4; ++q) {
            int row = row0 + wm * 64 + i * 16 + (lane >> 4) * 4 + q;
            if (row < M) {
                #pragma unroll
                for (int j = 0; j < 4; ++j) {
                    int col = col0 + wn * 64 + j * 16 + (lane & 15);
                    float val = acc[i][j][q];
                    if (HASBIAS) val += bias[col];
                    if (LEAKY)   val = val > 0.f ? val : 0.2f * val;
                    if (ADDSRC)  val += bf2f(srcb[(size_t)row * Nc + col]);
                    if (STATS) { lsum[j] += val; lsq[j] += val * val; }
                    if (OUTBF16) Cb[(size_t)row * Nc + col] = f2bf(val);
                    else         Cf[(size_t)row * Nc + col] = val;
                }
            }
        }
    }
    if (STATS) {
        __syncthreads();
        float* sred = (float*)As;
        sred[tid] = 0.f;
        __syncthreads();
        int ch = wn * 64 + (lane & 15);
        #pragma unroll
        for (int j = 0; j < 4; ++j) {
            atomicAdd(&sred[ch + j * 16], lsum[j]);
            atomicAdd(&sred[128 + ch + j * 16], lsq[j]);
        }
        __syncthreads();
        atomicAdd(&accum[tid], sred[tid]);
    }
}

// ---------------------------------------------------------------- BatchNorm stats (float4)
__global__ void bn_stats(const float* __restrict__ a, long long total4, float* __restrict__ accum) {
    int t = threadIdx.x;
    long long idx = (long long)blockIdx.x * 256 + t;
    long long stride = (long long)gridDim.x * 256;
    const float4* a4 = (const float4*)a;
    float s1[4] = {0.f,0.f,0.f,0.f}, s2[4] = {0.f,0.f,0.f,0.f};
    for (; idx < total4; idx += stride) {
        float4 v = a4[idx];
        s1[0] += v.x; s2[0] += v.x * v.x;
        s1[1] += v.y; s2[1] += v.y * v.y;
        s1[2] += v.z; s2[2] += v.z * v.z;
        s1[3] += v.w; s2[3] += v.w * v.w;
    }
    __shared__ float r1[256][4], r2[256][4];
    #pragma unroll
    for (int k = 0; k < 4; ++k) { r1[t][k] = s1[k]; r2[t][k] = s2[k]; }
    __syncthreads();
    if (t < 32) {
        #pragma unroll
        for (int k = 0; k < 4; ++k) {
            float a1 = 0.f, a2 = 0.f;
            #pragma unroll
            for (int u = 0; u < 8; ++u) { a1 += r1[t + u * 32][k]; a2 += r2[t + u * 32][k]; }
            atomicAdd(&accum[t * 4 + k], a1);
            atomicAdd(&accum[128 + t * 4 + k], a2);
        }
    }
}

// ---------------------------------------------------------------- BN finalize+apply (f32 in/out, optional bf16 shadow)
template<bool SHADOW>
__global__ void bn_apply_f(float* __restrict__ a, short* __restrict__ shadow, long long total4,
                           const float* __restrict__ accum, const float* __restrict__ g,
                           const float* __restrict__ b, float invM) {
    __shared__ float scs[256];
    int t = threadIdx.x;
    if (t < 128) {
        float mean = accum[t] * invM;
        float var = accum[128 + t] * invM - mean * mean;
        float s = g[t] * rsqrtf(var + 1e-5f);
        scs[t] = s;
        scs[128 + t] = b[t] - mean * s;
    }
    __syncthreads();
    long long idx = (long long)blockIdx.x * 256 + t;
    long long stride = (long long)gridDim.x * 256;
    float4* a4 = (float4*)a;
    short4* s4p = (short4*)shadow;
    for (; idx < total4; idx += stride) {
        int c = (int)((idx & 31) * 4);
        float4 v = a4[idx];
        v.x = v.x * scs[c + 0] + scs[128 + c + 0];
        v.y = v.y * scs[c + 1] + scs[128 + c + 1];
        v.z = v.z * scs[c + 2] + scs[128 + c + 2];
        v.w = v.w * scs[c + 3] + scs[128 + c + 3];
        a4[idx] = v;
        if (SHADOW)
            s4p[idx] = make_short4(f2bf(v.x), f2bf(v.y), f2bf(v.z), f2bf(v.w));
    }
}

// ---------------------------------------------------------------- BN apply bf16 -> f32
__global__ void bn_apply_b2f(const short* __restrict__ inb, float* __restrict__ outp,
                             long long total4, const float* __restrict__ accum,
                             const float* __restrict__ g, const float* __restrict__ b, float invM) {
    __shared__ float scs[256];
    int t = threadIdx.x;
    if (t < 128) {
        float mean = accum[t] * invM;
        float var = accum[128 + t] * invM - mean * mean;
        float s = g[t] * rsqrtf(var + 1e-5f);
        scs[t] = s;
        scs[128 + t] = b[t] - mean * s;
    }
    __syncthreads();
    long long idx = (long long)blockIdx.x * 256 + t;
    long long stride = (long long)gridDim.x * 256;
    const short4* in4 = (const short4*)inb;
    float4* o4 = (float4*)outp;
    for (; idx < total4; idx += stride) {
        int c = (int)((idx & 31) * 4);
        short4 sv = in4[idx];
        float4 v;
        v.x = bf2f(sv.x) * scs[c + 0] + scs[128 + c + 0];
        v.y = bf2f(sv.y) * scs[c + 1] + scs[128 + c + 1];
        v.z = bf2f(sv.z) * scs[c + 2] + scs[128 + c + 2];
        v.w = bf2f(sv.w) * scs[c + 3] + scs[128 + c + 3];
        o4[idx] = v;
    }
}

// ---------------------------------------------------------------- he_attr[e] = sum_{k in edge e} h[node_idx[k]]
__global__ void edge_feat(const int* __restrict__ elist, const int* __restrict__ eoff,
                          const int* __restrict__ nidx, const float* __restrict__ h,
                          float* __restrict__ he) {
    int e = blockIdx.x;
    int off = eoff[e], cnt = eoff[e + 1] - off;
    int d = threadIdx.x;  // 128
    float acc = 0.f;
    for (int p = 0; p < cnt; ++p) {
        int k = elist[off + p];
        int n = nidx[k];
        acc += h[(size_t)n * 128 + d];
    }
    he[(size_t)e * 128 + d] = acc;
}

// ---------------------------------------------------------------- w_att precompute:
// wx[h][d] = sum_j lin[d, h*128+j] * att[h, j]        (x-side)
// we[h][d] = sum_j lin[d, h*128+j] * att[h, 128+j]    (edge-side)
template<int H>
__global__ void watt_kernel(const float* __restrict__ lin, const float* __restrict__ att,
                            float* __restrict__ wx, float* __restrict__ we) {
    int t = threadIdx.x;            // H*128 threads
    int hh = t >> 7, d = t & 127;
    float sx = 0.f, se = 0.f;
    for (int j = 0; j < 128; ++j) {
        float l = lin[(size_t)d * (H * 128) + hh * 128 + j];
        sx += l * att[hh * 256 + j];
        se += l * att[hh * 256 + 128 + j];
    }
    wx[t] = sx;
    we[t] = se;
}

// ---------------------------------------------------------------- dots: out[row,h] = h_row . w[h]  (128-dim)
template<int H>
__global__ void dots128(const float* __restrict__ feat, const float* __restrict__ w,
                        float* __restrict__ out, int M) {
    int wv = threadIdx.x >> 6;
    int lane = threadIdx.x & 63;
    int row = blockIdx.x * 4 + wv;
    if (row >= M) return;
    const float* fr = feat + (size_t)row * 128;
    float f0 = fr[lane], f1 = fr[lane + 64];
    #pragma unroll
    for (int h = 0; h < H; ++h) {
        float v = f0 * w[h * 128 + lane] + f1 * w[h * 128 + lane + 64];
        #pragma unroll
        for (int s = 32; s > 0; s >>= 1) v += __shfl_xor(v, s);
        if (lane == 0) out[(size_t)row * H + h] = v;
    }
}

// ---------------------------------------------------------------- per-edge segment softmax
template<int H>
__global__ void edge_softmax(const int* __restrict__ elist, const int* __restrict__ eoff,
                             const int* __restrict__ nidx, const float* __restrict__ ax,
                             const float* __restrict__ ae, float* __restrict__ alpha) {
    constexpr int SLOTS = 256 / H;
    __shared__ float red[256];
    int e = blockIdx.x;
    int off = eoff[e], cnt = eoff[e + 1] - off;
    int t = threadIdx.x;
    int h = t % H, slot = t / H;
    float aeh = ae[(size_t)e * H + h];
    float lmax = -1e30f;
    for (int p = slot; p < cnt; p += SLOTS) {
        int k = elist[off + p];
        int n = nidx[k];
        float v = ax[(size_t)n * H + h] + aeh;
        v = v > 0.f ? v : 0.2f * v;
        alpha[(size_t)k * H + h] = v;
        lmax = fmaxf(lmax, v);
    }
    red[t] = lmax;
    __syncthreads();
    for (int s = SLOTS / 2; s > 0; s >>= 1) {
        if (slot < s) red[slot * H + h] = fmaxf(red[slot * H + h], red[(slot + s) * H + h]);
        __syncthreads();
    }
    float m = red[h];
    __syncthreads();
    float lsum = 0.f;
    for (int p = slot; p < cnt; p += SLOTS) {
        int k = elist[off + p];
        float ex = expf(alpha[(size_t)k * H + h] - m);
        alpha[(size_t)k * H + h] = ex;
        lsum += ex;
    }
    red[t] = lsum;
    __syncthreads();
    for (int s = SLOTS / 2; s > 0; s >>= 1) {
        if (slot < s) red[slot * H + h] += red[(slot + s) * H + h];
        __syncthreads();
    }
    float inv = 1.0f / (red[h] + 1e-16f);
    for (int p = slot; p < cnt; p += SLOTS) {
        int k = elist[off + p];
        alpha[(size_t)k * H + h] *= inv;
    }
}

// ---------------------------------------------------------------- agg_e[e,h,d] = Binv * sum_k alpha[k,h]*h[v_k,d]  (128-space)
template<int H>
__global__ void edge_agg128(const int* __restrict__ elist, const int* __restrict__ eoff,
                            const int* __restrict__ nidx, const float* __restrict__ alpha,
                            const float* __restrict__ h, float* __restrict__ agg) {
    int e = blockIdx.x;
    int off = eoff[e], cnt = eoff[e + 1] - off;
    int t = threadIdx.x;            // H*128 threads
    int hh = t >> 7, d = t & 127;
    float acc = 0.f;
    for (int p = 0; p < cnt; ++p) {
        int k = elist[off + p];
        int n = nidx[k];
        acc += alpha[(size_t)k * H + hh] * h[(size_t)n * 128 + d];
    }
    float binv = cnt > 0 ? 1.0f / (float)cnt : 0.0f;
    agg[(size_t)e * (H * 128) + t] = acc * binv;
}

// ---------------------------------------------------------------- oute[e,h,j] = sum_d agg[e,h,d] * lin[d, h*128+j]
template<int H>
__global__ void oute_lin(const float* __restrict__ agg, const float* __restrict__ lin,
                         float* __restrict__ oute) {
    __shared__ float ar[H * 128];
    int e = blockIdx.x;
    int t = threadIdx.x;            // H*128 threads
    ar[t] = agg[(size_t)e * (H * 128) + t];
    __syncthreads();
    int hh = t >> 7;
    float acc = 0.f;
    #pragma unroll 4
    for (int d = 0; d < 128; ++d)
        acc += ar[hh * 128 + d] * lin[(size_t)d * (H * 128) + t];
    oute[(size_t)e * (H * 128) + t] = acc;
}

// ---------------------------------------------------------------- node side (512-space, oute L2-resident)
template<int H>
__global__ void node_aggregate(const int* __restrict__ nlist, const int* __restrict__ noff,
                               const int* __restrict__ eidx, const float* __restrict__ alpha,
                               const float* __restrict__ out_e, const float* __restrict__ bias,
                               float* __restrict__ hout) {
    __shared__ float red[H * 128];
    int n = blockIdx.x;
    int off = noff[n], cnt = noff[n + 1] - off;
    int t = threadIdx.x;            // H*128 threads
    int h = t >> 7;
    float acc = 0.f;
    for (int p = 0; p < cnt; ++p) {
        int k = nlist[off + p];
        int e = eidx[k];
        acc += alpha[(size_t)k * H + h] * out_e[(size_t)e * (H * 128) + t];
    }
    float dinv = cnt > 0 ? 1.0f / (float)cnt : 0.0f;
    acc *= dinv;
    if (H == 1) {
        hout[(size_t)n * 128 + t] += acc + bias[t];
    } else {
        red[t] = acc;
        __syncthreads();
        if (t < 128) {
            float s = 0.f;
            #pragma unroll
            for (int hh = 0; hh < H; ++hh) s += red[hh * 128 + t];
            hout[(size_t)n * 128 + t] += s * (1.0f / H) + bias[t];
        }
    }
}

// ---------------------------------------------------------------- launch
extern "C" void kernel_launch(void* const* d_in, const int* in_sizes, int n_in,
                              void* d_out, int out_size, void* d_ws, size_t ws_size,
                              hipStream_t stream) {
    (void)in_sizes; (void)n_in; (void)out_size; (void)ws_size;
    const float* x        = (const float*)d_in[0];
    const int*   node_idx = (const int*)d_in[1];
    const int*   edge_idx = (const int*)d_in[2];
    const float* W1    = (const float*)d_in[4];
    const float* b1    = (const float*)d_in[5];
    const float* bn1_g = (const float*)d_in[6];
    const float* bn1_b = (const float*)d_in[7];
    const float* h1_lin  = (const float*)d_in[8];
    const float* h1_att  = (const float*)d_in[9];
    const float* h1_bias = (const float*)d_in[10];
    const float* bn2_g = (const float*)d_in[11];
    const float* bn2_b = (const float*)d_in[12];
    const float* h2_lin  = (const float*)d_in[13];
    const float* h2_att  = (const float*)d_in[14];
    const float* h2_bias = (const float*)d_in[15];
    const float* bn3_g = (const float*)d_in[16];
    const float* bn3_b = (const float*)d_in[17];
    const float* W2    = (const float*)d_in[18];
    const float* b2    = (const float*)d_in[19];
    const float* bn4_g = (const float*)d_in[20];
    const float* bn4_b = (const float*)d_in[21];
    float* out = (float*)d_out;

    char* ws = (char*)d_ws;
    size_t off = 0;
    auto alloc = [&](size_t bytes) -> void* {
        void* p = ws + off;
        off = (off + bytes + 255) & ~(size_t)255;
        return p;
    };
    float* h     = (float*)alloc((size_t)NN * 128 * 4);
    float* scratch = (float*)alloc((size_t)NN * 512 * 4);   // pre-BN4 bf16 home (+ spare)
    float* he    = (float*)alloc((size_t)EE * 128 * 4);
    float* agg   = (float*)alloc((size_t)EE * 512 * 4);
    float* oute  = (float*)alloc((size_t)EE * 512 * 4);
    float* ax    = (float*)alloc((size_t)NN * 4 * 4);
    float* ae    = (float*)alloc((size_t)EE * 4 * 4);
    float* alpha = (float*)alloc((size_t)NNZC * 4 * 4);
    float* accum = (float*)alloc(256 * 4);
    float* wax   = (float*)alloc(512 * 4);
    float* wae   = (float*)alloc(512 * 4);
    short* hb    = (short*)alloc((size_t)NN * 128 * 2);    // bf16 shadow of h (BN3 only)
    short* W1T   = (short*)alloc((size_t)128 * DIN * 2);
    short* W2T   = (short*)alloc((size_t)DIN * 128 * 2);
    int* ecnt  = (int*)alloc(EE * 4);
    int* eoff  = (int*)alloc((EE + 1) * 4);
    int* ecur  = (int*)alloc(EE * 4);
    int* elist = (int*)alloc(NNZC * 4);
    int* ncnt  = (int*)alloc(NN * 4);
    int* noff  = (int*)alloc((NN + 1) * 4);
    int* ncur  = (int*)alloc(NN * 4);
    int* nlist = (int*)alloc(NNZC * 4);

    short* xb   = (short*)d_out;       // bf16 copy of x in dead space of d_out
    short* outb = (short*)scratch;     // pre-BN4 bf16 scratch

    hipMemsetAsync(ecnt, 0, EE * 4, stream);
    hipMemsetAsync(ncnt, 0, NN * 4, stream);
    hipMemsetAsync(ecur, 0, EE * 4, stream);
    hipMemsetAsync(ncur, 0, NN * 4, stream);

    count_kernel<<<(NNZC + 255) / 256, 256, 0, stream>>>(edge_idx, node_idx, ecnt, ncnt);
    cvt_f2b<<<2048, 256, 0, stream>>>(x, xb, (long long)NN * DIN / 4);
    transpose_to_bf16<<<dim3(4, 32), 256, 0, stream>>>(W1, W1T, DIN, 128);
    transpose_to_bf16<<<dim3(32, 4), 256, 0, stream>>>(W2, W2T, 128, DIN);
    scan_two<<<2, 1024, 0, stream>>>(ecnt, eoff, ncnt, noff);
    fill_lists<<<(NNZC + 255) / 256, 256, 0, stream>>>(edge_idx, node_idx, eoff, noff,
                                                       ecur, ncur, elist, nlist);

    const int MB = (NN + 127) / 128;   // 235

    // h = leaky(xb @ W1 + b1)   [MFMA + BN1 stats fused]
    hipMemsetAsync(accum, 0, 256 * 4, stream);
    gemm_mfma<true, true, false, true, false><<<dim3(1, MB), 256, 0, stream>>>(
        xb, W1T, b1, nullptr, h, accum, NN, DIN, 128);
    bn_apply_f<false><<<1024, 256, 0, stream>>>(h, nullptr, (long long)NN * 128 / 4, accum,
                                                bn1_g, bn1_b, 1.0f / NN);

    // ---- hconv1 (heads=4), linearity-refactored ----
    edge_feat<<<EE, 128, 0, stream>>>(elist, eoff, node_idx, h, he);
    watt_kernel<4><<<1, 512, 0, stream>>>(h1_lin, h1_att, wax, wae);
    dots128<4><<<(NN + 3) / 4, 256, 0, stream>>>(h, wax, ax, NN);
    dots128<4><<<(EE + 3) / 4, 256, 0, stream>>>(he, wae, ae, EE);
    edge_softmax<4><<<EE, 256, 0, stream>>>(elist, eoff, node_idx, ax, ae, alpha);
    edge_agg128<4><<<EE, 512, 0, stream>>>(elist, eoff, node_idx, alpha, h, agg);
    oute_lin<4><<<EE, 512, 0, stream>>>(agg, h1_lin, oute);
    node_aggregate<4><<<NN, 512, 0, stream>>>(nlist, noff, edge_idx, alpha, oute, h1_bias, h);

    // BN2
    hipMemsetAsync(accum, 0, 256 * 4, stream);
    bn_stats<<<512, 256, 0, stream>>>(h, (long long)NN * 128 / 4, accum);
    bn_apply_f<false><<<1024, 256, 0, stream>>>(h, nullptr, (long long)NN * 128 / 4, accum,
                                                bn2_g, bn2_b, 1.0f / NN);

    // ---- hconv2 (heads=1), linearity-refactored ----
    edge_feat<<<EE, 128, 0, stream>>>(elist, eoff, node_idx, h, he);
    watt_kernel<1><<<1, 128, 0, stream>>>(h2_lin, h2_att, wax, wae);
    dots128<1><<<(NN + 3) / 4, 256, 0, stream>>>(h, wax, ax, NN);
    dots128<1><<<(EE + 3) / 4, 256, 0, stream>>>(he, wae, ae, EE);
    edge_softmax<1><<<EE, 256, 0, stream>>>(elist, eoff, node_idx, ax, ae, alpha);
    edge_agg128<1><<<EE, 128, 0, stream>>>(elist, eoff, node_idx, alpha, h, agg);
    oute_lin<1><<<EE, 128, 0, stream>>>(agg, h2_lin, oute);
    node_aggregate<1><<<NN, 128, 0, stream>>>(nlist, noff, edge_idx, alpha, oute, h2_bias, h);

    // BN3 (shadow feeds W2)
    hipMemsetAsync(accum, 0, 256 * 4, stream);
    bn_stats<<<512, 256, 0, stream>>>(h, (long long)NN * 128 / 4, accum);
    bn_apply_f<true><<<1024, 256, 0, stream>>>(h, hb, (long long)NN * 128 / 4, accum,
                                               bn3_g, bn3_b, 1.0f / NN);

    // out_pre = xb + leaky(hb @ W2 + b2) -> bf16 scratch [MFMA + BN4 stats fused]
    hipMemsetAsync(accum, 0, 256 * 4, stream);
    gemm_mfma<true, true, true, true, true><<<dim3(8, MB), 256, 0, stream>>>(
        hb, W2T, b2, xb, outb, accum, NN, 128, DIN);

    // BN4: bf16 -> f32 out (overwrites all of d_out incl. xb scratch)
    bn_apply_b2f<<<2048, 256, 0, stream>>>(outb, out, (long long)NN * DIN / 4, accum,
                                           bn4_g, bn4_b, 1.0f / (NN * PP));
}

// Round 13
// 855.451 us; speedup vs baseline: 1.0192x; 1.0121x over previous
//
#include <hip/hip_runtime.h>
#include <math.h>

#define NN 30000
#define PP 8
#define DM 128
#define EE 1000
#define NNZC 120000
#define DIN (PP*DM)   // 1024

typedef __attribute__((ext_vector_type(8))) short bf16x8;
typedef __attribute__((ext_vector_type(4))) float f32x4;

__device__ __forceinline__ short f2bf(float f) {
    union { float f; unsigned u; } v; v.f = f;
    unsigned r = v.u + 0x7fffu + ((v.u >> 16) & 1u);
    return (short)(r >> 16);
}
__device__ __forceinline__ float bf2f(short s) {
    union { unsigned u; float f; } v;
    v.u = ((unsigned)(unsigned short)s) << 16;
    return v.f;
}

// ---------------------------------------------------------------- CSR build
__global__ void count_kernel(const int* __restrict__ ei, const int* __restrict__ ni,
                             int* __restrict__ ecnt, int* __restrict__ ncnt) {
    int k = blockIdx.x * 256 + threadIdx.x;
    if (k >= NNZC) return;
    atomicAdd(&ecnt[ei[k]], 1);
    atomicAdd(&ncnt[ni[k]], 1);
}

__global__ __launch_bounds__(1024)
void scan_two(const int* __restrict__ ecnt, int* __restrict__ eoff,
              const int* __restrict__ ncnt, int* __restrict__ noff) {
    const int* cnt; int* off; int len;
    if (blockIdx.x == 0) { cnt = ecnt; off = eoff; len = EE; }
    else                 { cnt = ncnt; off = noff; len = NN; }
    __shared__ int wsum[16];
    __shared__ int carrysh;
    int t = threadIdx.x;
    int lane = t & 63, w = t >> 6;
    if (t == 0) carrysh = 0;
    __syncthreads();
    for (int base = 0; base < len; base += 1024) {
        int v = (base + t < len) ? cnt[base + t] : 0;
        int s = v;
        #pragma unroll
        for (int d = 1; d < 64; d <<= 1) {
            int u = __shfl_up(s, d);
            if (lane >= d) s += u;
        }
        if (lane == 63) wsum[w] = s;
        __syncthreads();
        if (t < 16) {
            int ws = wsum[t];
            #pragma unroll
            for (int d = 1; d < 16; d <<= 1) {
                int u = __shfl_up(ws, d);
                if (t >= d) ws += u;
            }
            wsum[t] = ws;
        }
        __syncthreads();
        int c = carrysh;
        int woff = (w > 0) ? wsum[w - 1] : 0;
        if (base + t < len) off[base + t] = c + woff + s - v;
        int total = wsum[15];
        __syncthreads();
        if (t == 0) carrysh = c + total;
    }
    __syncthreads();
    if (t == 0) off[len] = carrysh;
}

__global__ void fill_lists(const int* __restrict__ ei, const int* __restrict__ ni,
                           const int* __restrict__ eoff, const int* __restrict__ noff,
                           int* __restrict__ ecur, int* __restrict__ ncur,
                           int* __restrict__ elist, int* __restrict__ nlist) {
    int k = blockIdx.x * 256 + threadIdx.x;
    if (k >= NNZC) return;
    int e = ei[k];
    int p = atomicAdd(&ecur[e], 1);
    elist[eoff[e] + p] = k;
    int n = ni[k];
    int q = atomicAdd(&ncur[n], 1);
    nlist[noff[n] + q] = k;
}

// ---------------------------------------------------------------- weight transpose+convert
__global__ void transpose_to_bf16(const float* __restrict__ B, short* __restrict__ BT,
                                  int K, int N) {
    __shared__ float tile[32][33];
    int bn = blockIdx.x * 32, bk = blockIdx.y * 32;
    int tx = threadIdx.x & 31, ty = threadIdx.x >> 5;
    #pragma unroll
    for (int yy = ty; yy < 32; yy += 8) {
        int k = bk + yy, n = bn + tx;
        tile[yy][tx] = (k < K && n < N) ? B[(size_t)k * N + n] : 0.f;
    }
    __syncthreads();
    #pragma unroll
    for (int yy = ty; yy < 32; yy += 8) {
        int n = bn + yy, k = bk + tx;
        if (n < N && k < K) BT[(size_t)n * K + k] = f2bf(tile[tx][yy]);
    }
}

// ---------------------------------------------------------------- bf16 MFMA GEMM
// BM = 64*RG, BN = 128, BK = 32 double-buffered; 4 waves; 16x16x32 MFMA.
// AF32: A operand is f32, converted to bf16 during LDS staging (R10 path);
//       DUMPA additionally stores the bf16 tile to Adump (valid when colB==1).
// 1-D grid; SWZ: XCD-bijective remap (requires gridDim.x % 8 == 0), col-fastest
// decode so each XCD keeps a row-panel of A resident in its L2.
template<int RG, bool AF32, bool DUMPA, bool HASBIAS, bool LEAKY, bool ADDSRC,
         bool STATS, bool OUTBF16, bool SWZ>
__global__ __launch_bounds__(256)
void gemm_mfma(const void* __restrict__ Ain, const short* __restrict__ BT,
               const float* __restrict__ bias, const short* __restrict__ srcb,
               void* __restrict__ Cout, float* __restrict__ accum,
               short* __restrict__ Adump, int M, int K, int Nc, int colB) {
    constexpr int BM = 64 * RG;
    __shared__ short As[BM * 40];
    __shared__ short Bs[128 * 40];
    const int tid = threadIdx.x;
    const int lane = tid & 63, wid = tid >> 6;
    const int wm = wid >> 1, wn = wid & 1;

    int row0, col0;
    {
        int w = blockIdx.x;
        int l;
        if (SWZ) { int cpx = gridDim.x >> 3; l = (w & 7) * cpx + (w >> 3); }
        else     { l = w; }
        row0 = (l / colB) * BM;
        col0 = (l % colB) * 128;
    }
    const int srow = tid >> 2, skq = tid & 3;

    f32x4 acc[RG * 2][4] = {};
    const int NT = K >> 5;

    struct Stage { float4 fa[RG][2]; bf16x8 a[RG]; bf16x8 b[2]; };
    Stage s0, s1;

    auto loadT = [&](int t, Stage& s) {
        int k0 = t << 5;
        #pragma unroll
        for (int c = 0; c < RG; ++c) {
            int gr = row0 + srow + 64 * c;
            if (AF32) {
                float4 z = make_float4(0.f, 0.f, 0.f, 0.f);
                s.fa[c][0] = z; s.fa[c][1] = z;
                if (gr < M) {
                    const float4* p = (const float4*)((const float*)Ain + (size_t)gr * K + k0 + skq * 8);
                    s.fa[c][0] = p[0]; s.fa[c][1] = p[1];
                }
            } else {
                s.a[c] = bf16x8{0, 0, 0, 0, 0, 0, 0, 0};
                if (gr < M)
                    s.a[c] = *(const bf16x8*)((const short*)Ain + (size_t)gr * K + k0 + skq * 8);
            }
        }
        #pragma unroll
        for (int c = 0; c < 2; ++c) {
            int gc = col0 + srow + 64 * c;
            s.b[c] = *(const bf16x8*)(BT + (size_t)gc * K + k0 + skq * 8);
        }
    };
    auto writeT = [&](int t, Stage& s) {
        int k0 = t << 5;
        #pragma unroll
        for (int c = 0; c < RG; ++c) {
            bf16x8 t8;
            if (AF32) {
                t8[0] = f2bf(s.fa[c][0].x); t8[1] = f2bf(s.fa[c][0].y);
                t8[2] = f2bf(s.fa[c][0].z); t8[3] = f2bf(s.fa[c][0].w);
                t8[4] = f2bf(s.fa[c][1].x); t8[5] = f2bf(s.fa[c][1].y);
                t8[6] = f2bf(s.fa[c][1].z); t8[7] = f2bf(s.fa[c][1].w);
                if (DUMPA) {
                    int gr = row0 + srow + 64 * c;
                    if (gr < M)
                        *(bf16x8*)(Adump + (size_t)gr * K + k0 + skq * 8) = t8;
                }
            } else {
                t8 = s.a[c];
            }
            *(bf16x8*)&As[(srow + 64 * c) * 40 + skq * 8] = t8;
        }
        #pragma unroll
        for (int c = 0; c < 2; ++c)
            *(bf16x8*)&Bs[(srow + 64 * c) * 40 + skq * 8] = s.b[c];
    };
    auto compute = [&]() {
        bf16x8 av[RG * 2], bv[4];
        #pragma unroll
        for (int i = 0; i < RG * 2; ++i)
            av[i] = *(const bf16x8*)&As[(wm * (RG * 32) + i * 16 + (lane & 15)) * 40 + (lane >> 4) * 8];
        #pragma unroll
        for (int j = 0; j < 4; ++j)
            bv[j] = *(const bf16x8*)&Bs[(wn * 64 + j * 16 + (lane & 15)) * 40 + (lane >> 4) * 8];
        #pragma unroll
        for (int i = 0; i < RG * 2; ++i)
            #pragma unroll
            for (int j = 0; j < 4; ++j)
                acc[i][j] = __builtin_amdgcn_mfma_f32_16x16x32_bf16(av[i], bv[j], acc[i][j], 0, 0, 0);
    };

    loadT(0, s0);
    for (int t = 0; t < NT; t += 2) {
        __syncthreads();
        loadT(t + 1, s1);
        writeT(t, s0);
        __syncthreads();
        compute();
        __syncthreads();
        if (t + 2 < NT) loadT(t + 2, s0);
        writeT(t + 1, s1);
        __syncthreads();
        compute();
    }

    // epilogue: wave-coalesced register stores (col=lane&15 consecutive)
    float* Cf = (float*)Cout;
    short* Cb = (short*)Cout;
    float lsum[4] = {0.f, 0.f, 0.f, 0.f}, lsq[4] = {0.f, 0.f, 0.f, 0.f};
    #pragma unroll
    for (int i = 0; i < RG * 2; ++i) {
        #pragma unroll
        for (int q = 0; q < 4; ++q) {
            int row = row0 + wm * (RG * 32) + i * 16 + (lane >> 4) * 4 + q;
            if (row < M) {
                #pragma unroll
                for (int j = 0; j < 4; ++j) {
                    int col = col0 + wn * 64 + j * 16 + (lane & 15);
                    float val = acc[i][j][q];
                    if (HASBIAS) val += bias[col];
                    if (LEAKY)   val = val > 0.f ? val : 0.2f * val;
                    if (ADDSRC)  val += bf2f(srcb[(size_t)row * Nc + col]);
                    if (STATS) { lsum[j] += val; lsq[j] += val * val; }
                    if (OUTBF16) Cb[(size_t)row * Nc + col] = f2bf(val);
                    else         Cf[(size_t)row * Nc + col] = val;
                }
            }
        }
    }
    if (STATS) {
        __syncthreads();
        float* sred = (float*)As;
        sred[tid] = 0.f;
        __syncthreads();
        int ch = wn * 64 + (lane & 15);
        #pragma unroll
        for (int j = 0; j < 4; ++j) {
            atomicAdd(&sred[ch + j * 16], lsum[j]);
            atomicAdd(&sred[128 + ch + j * 16], lsq[j]);
        }
        __syncthreads();
        atomicAdd(&accum[tid], sred[tid]);
    }
}

// ---------------------------------------------------------------- BatchNorm stats (float4)
__global__ void bn_stats(const float* __restrict__ a, long long total4, float* __restrict__ accum) {
    int t = threadIdx.x;
    long long idx = (long long)blockIdx.x * 256 + t;
    long long stride = (long long)gridDim.x * 256;
    const float4* a4 = (const float4*)a;
    float s1[4] = {0.f,0.f,0.f,0.f}, s2[4] = {0.f,0.f,0.f,0.f};
    for (; idx < total4; idx += stride) {
        float4 v = a4[idx];
        s1[0] += v.x; s2[0] += v.x * v.x;
        s1[1] += v.y; s2[1] += v.y * v.y;
        s1[2] += v.z; s2[2] += v.z * v.z;
        s1[3] += v.w; s2[3] += v.w * v.w;
    }
    __shared__ float r1[256][4], r2[256][4];
    #pragma unroll
    for (int k = 0; k < 4; ++k) { r1[t][k] = s1[k]; r2[t][k] = s2[k]; }
    __syncthreads();
    if (t < 32) {
        #pragma unroll
        for (int k = 0; k < 4; ++k) {
            float a1 = 0.f, a2 = 0.f;
            #pragma unroll
            for (int u = 0; u < 8; ++u) { a1 += r1[t + u * 32][k]; a2 += r2[t + u * 32][k]; }
            atomicAdd(&accum[t * 4 + k], a1);
            atomicAdd(&accum[128 + t * 4 + k], a2);
        }
    }
}

// ---------------------------------------------------------------- BN finalize+apply (f32 in/out, optional bf16 shadow)
template<bool SHADOW>
__global__ void bn_apply_f(float* __restrict__ a, short* __restrict__ shadow, long long total4,
                           const float* __restrict__ accum, const float* __restrict__ g,
                           const float* __restrict__ b, float invM) {
    __shared__ float scs[256];
    int t = threadIdx.x;
    if (t < 128) {
        float mean = accum[t] * invM;
        float var = accum[128 + t] * invM - mean * mean;
        float s = g[t] * rsqrtf(var + 1e-5f);
        scs[t] = s;
        scs[128 + t] = b[t] - mean * s;
    }
    __syncthreads();
    long long idx = (long long)blockIdx.x * 256 + t;
    long long stride = (long long)gridDim.x * 256;
    float4* a4 = (float4*)a;
    short4* s4p = (short4*)shadow;
    for (; idx < total4; idx += stride) {
        int c = (int)((idx & 31) * 4);
        float4 v = a4[idx];
        v.x = v.x * scs[c + 0] + scs[128 + c + 0];
        v.y = v.y * scs[c + 1] + scs[128 + c + 1];
        v.z = v.z * scs[c + 2] + scs[128 + c + 2];
        v.w = v.w * scs[c + 3] + scs[128 + c + 3];
        a4[idx] = v;
        if (SHADOW)
            s4p[idx] = make_short4(f2bf(v.x), f2bf(v.y), f2bf(v.z), f2bf(v.w));
    }
}

// ---------------------------------------------------------------- BN apply bf16 -> f32
__global__ void bn_apply_b2f(const short* __restrict__ inb, float* __restrict__ outp,
                             long long total4, const float* __restrict__ accum,
                             const float* __restrict__ g, const float* __restrict__ b, float invM) {
    __shared__ float scs[256];
    int t = threadIdx.x;
    if (t < 128) {
        float mean = accum[t] * invM;
        float var = accum[128 + t] * invM - mean * mean;
        float s = g[t] * rsqrtf(var + 1e-5f);
        scs[t] = s;
        scs[128 + t] = b[t] - mean * s;
    }
    __syncthreads();
    long long idx = (long long)blockIdx.x * 256 + t;
    long long stride = (long long)gridDim.x * 256;
    const short4* in4 = (const short4*)inb;
    float4* o4 = (float4*)outp;
    for (; idx < total4; idx += stride) {
        int c = (int)((idx & 31) * 4);
        short4 sv = in4[idx];
        float4 v;
        v.x = bf2f(sv.x) * scs[c + 0] + scs[128 + c + 0];
        v.y = bf2f(sv.y) * scs[c + 1] + scs[128 + c + 1];
        v.z = bf2f(sv.z) * scs[c + 2] + scs[128 + c + 2];
        v.w = bf2f(sv.w) * scs[c + 3] + scs[128 + c + 3];
        o4[idx] = v;
    }
}

// ---------------------------------------------------------------- he_attr[e] = sum_{k in edge e} h[node_idx[k]]
__global__ void edge_feat(const int* __restrict__ elist, const int* __restrict__ eoff,
                          const int* __restrict__ nidx, const float* __restrict__ h,
                          float* __restrict__ he) {
    int e = blockIdx.x;
    int off = eoff[e], cnt = eoff[e + 1] - off;
    int d = threadIdx.x;  // 128
    float acc = 0.f;
    for (int p = 0; p < cnt; ++p) {
        int k = elist[off + p];
        int n = nidx[k];
        acc += h[(size_t)n * 128 + d];
    }
    he[(size_t)e * 128 + d] = acc;
}

// ---------------------------------------------------------------- w_att precompute
template<int H>
__global__ void watt_kernel(const float* __restrict__ lin, const float* __restrict__ att,
                            float* __restrict__ wx, float* __restrict__ we) {
    int t = threadIdx.x;            // H*128 threads
    int hh = t >> 7, d = t & 127;
    float sx = 0.f, se = 0.f;
    for (int j = 0; j < 128; ++j) {
        float l = lin[(size_t)d * (H * 128) + hh * 128 + j];
        sx += l * att[hh * 256 + j];
        se += l * att[hh * 256 + 128 + j];
    }
    wx[t] = sx;
    we[t] = se;
}

// ---------------------------------------------------------------- dots: out[row,h] = h_row . w[h]
template<int H>
__global__ void dots128(const float* __restrict__ feat, const float* __restrict__ w,
                        float* __restrict__ out, int M) {
    int wv = threadIdx.x >> 6;
    int lane = threadIdx.x & 63;
    int row = blockIdx.x * 4 + wv;
    if (row >= M) return;
    const float* fr = feat + (size_t)row * 128;
    float f0 = fr[lane], f1 = fr[lane + 64];
    #pragma unroll
    for (int h = 0; h < H; ++h) {
        float v = f0 * w[h * 128 + lane] + f1 * w[h * 128 + lane + 64];
        #pragma unroll
        for (int s = 32; s > 0; s >>= 1) v += __shfl_xor(v, s);
        if (lane == 0) out[(size_t)row * H + h] = v;
    }
}

// ---------------------------------------------------------------- per-edge segment softmax
template<int H>
__global__ void edge_softmax(const int* __restrict__ elist, const int* __restrict__ eoff,
                             const int* __restrict__ nidx, const float* __restrict__ ax,
                             const float* __restrict__ ae, float* __restrict__ alpha) {
    constexpr int SLOTS = 256 / H;
    __shared__ float red[256];
    int e = blockIdx.x;
    int off = eoff[e], cnt = eoff[e + 1] - off;
    int t = threadIdx.x;
    int h = t % H, slot = t / H;
    float aeh = ae[(size_t)e * H + h];
    float lmax = -1e30f;
    for (int p = slot; p < cnt; p += SLOTS) {
        int k = elist[off + p];
        int n = nidx[k];
        float v = ax[(size_t)n * H + h] + aeh;
        v = v > 0.f ? v : 0.2f * v;
        alpha[(size_t)k * H + h] = v;
        lmax = fmaxf(lmax, v);
    }
    red[t] = lmax;
    __syncthreads();
    for (int s = SLOTS / 2; s > 0; s >>= 1) {
        if (slot < s) red[slot * H + h] = fmaxf(red[slot * H + h], red[(slot + s) * H + h]);
        __syncthreads();
    }
    float m = red[h];
    __syncthreads();
    float lsum = 0.f;
    for (int p = slot; p < cnt; p += SLOTS) {
        int k = elist[off + p];
        float ex = expf(alpha[(size_t)k * H + h] - m);
        alpha[(size_t)k * H + h] = ex;
        lsum += ex;
    }
    red[t] = lsum;
    __syncthreads();
    for (int s = SLOTS / 2; s > 0; s >>= 1) {
        if (slot < s) red[slot * H + h] += red[(slot + s) * H + h];
        __syncthreads();
    }
    float inv = 1.0f / (red[h] + 1e-16f);
    for (int p = slot; p < cnt; p += SLOTS) {
        int k = elist[off + p];
        alpha[(size_t)k * H + h] *= inv;
    }
}

// ---------------------------------------------------------------- agg_e (128-space)
template<int H>
__global__ void edge_agg128(const int* __restrict__ elist, const int* __restrict__ eoff,
                            const int* __restrict__ nidx, const float* __restrict__ alpha,
                            const float* __restrict__ h, float* __restrict__ agg) {
    int e = blockIdx.x;
    int off = eoff[e], cnt = eoff[e + 1] - off;
    int t = threadIdx.x;            // H*128 threads
    int hh = t >> 7, d = t & 127;
    float acc = 0.f;
    for (int p = 0; p < cnt; ++p) {
        int k = elist[off + p];
        int n = nidx[k];
        acc += alpha[(size_t)k * H + hh] * h[(size_t)n * 128 + d];
    }
    float binv = cnt > 0 ? 1.0f / (float)cnt : 0.0f;
    agg[(size_t)e * (H * 128) + t] = acc * binv;
}

// ---------------------------------------------------------------- oute[e,h,j] = sum_d agg[e,h,d] * lin[d, h*128+j]
template<int H>
__global__ void oute_lin(const float* __restrict__ agg, const float* __restrict__ lin,
                         float* __restrict__ oute) {
    __shared__ float ar[H * 128];
    int e = blockIdx.x;
    int t = threadIdx.x;            // H*128 threads
    ar[t] = agg[(size_t)e * (H * 128) + t];
    __syncthreads();
    int hh = t >> 7;
    float acc = 0.f;
    #pragma unroll 4
    for (int d = 0; d < 128; ++d)
        acc += ar[hh * 128 + d] * lin[(size_t)d * (H * 128) + t];
    oute[(size_t)e * (H * 128) + t] = acc;
}

// ---------------------------------------------------------------- node side
template<int H>
__global__ void node_aggregate(const int* __restrict__ nlist, const int* __restrict__ noff,
                               const int* __restrict__ eidx, const float* __restrict__ alpha,
                               const float* __restrict__ out_e, const float* __restrict__ bias,
                               float* __restrict__ hout) {
    __shared__ float red[H * 128];
    int n = blockIdx.x;
    int off = noff[n], cnt = noff[n + 1] - off;
    int t = threadIdx.x;            // H*128 threads
    int h = t >> 7;
    float acc = 0.f;
    for (int p = 0; p < cnt; ++p) {
        int k = nlist[off + p];
        int e = eidx[k];
        acc += alpha[(size_t)k * H + h] * out_e[(size_t)e * (H * 128) + t];
    }
    float dinv = cnt > 0 ? 1.0f / (float)cnt : 0.0f;
    acc *= dinv;
    if (H == 1) {
        hout[(size_t)n * 128 + t] += acc + bias[t];
    } else {
        red[t] = acc;
        __syncthreads();
        if (t < 128) {
            float s = 0.f;
            #pragma unroll
            for (int hh = 0; hh < H; ++hh) s += red[hh * 128 + t];
            hout[(size_t)n * 128 + t] += s * (1.0f / H) + bias[t];
        }
    }
}

// ---------------------------------------------------------------- launch
extern "C" void kernel_launch(void* const* d_in, const int* in_sizes, int n_in,
                              void* d_out, int out_size, void* d_ws, size_t ws_size,
                              hipStream_t stream) {
    (void)in_sizes; (void)n_in; (void)out_size; (void)ws_size;
    const float* x        = (const float*)d_in[0];
    const int*   node_idx = (const int*)d_in[1];
    const int*   edge_idx = (const int*)d_in[2];
    const float* W1    = (const float*)d_in[4];
    const float* b1    = (const float*)d_in[5];
    const float* bn1_g = (const float*)d_in[6];
    const float* bn1_b = (const float*)d_in[7];
    const float* h1_lin  = (const float*)d_in[8];
    const float* h1_att  = (const float*)d_in[9];
    const float* h1_bias = (const float*)d_in[10];
    const float* bn2_g = (const float*)d_in[11];
    const float* bn2_b = (const float*)d_in[12];
    const float* h2_lin  = (const float*)d_in[13];
    const float* h2_att  = (const float*)d_in[14];
    const float* h2_bias = (const float*)d_in[15];
    const float* bn3_g = (const float*)d_in[16];
    const float* bn3_b = (const float*)d_in[17];
    const float* W2    = (const float*)d_in[18];
    const float* b2    = (const float*)d_in[19];
    const float* bn4_g = (const float*)d_in[20];
    const float* bn4_b = (const float*)d_in[21];
    float* out = (float*)d_out;

    char* ws = (char*)d_ws;
    size_t off = 0;
    auto alloc = [&](size_t bytes) -> void* {
        void* p = ws + off;
        off = (off + bytes + 255) & ~(size_t)255;
        return p;
    };
    float* h     = (float*)alloc((size_t)NN * 128 * 4);
    float* scratch = (float*)alloc((size_t)NN * 512 * 4);   // pre-BN4 bf16 home
    float* he    = (float*)alloc((size_t)EE * 128 * 4);
    float* agg   = (float*)alloc((size_t)EE * 512 * 4);
    float* oute  = (float*)alloc((size_t)EE * 512 * 4);
    float* ax    = (float*)alloc((size_t)NN * 4 * 4);
    float* ae    = (float*)alloc((size_t)EE * 4 * 4);
    float* alpha = (float*)alloc((size_t)NNZC * 4 * 4);
    float* accum = (float*)alloc(256 * 4);
    float* wax   = (float*)alloc(512 * 4);
    float* wae   = (float*)alloc(512 * 4);
    short* hb    = (short*)alloc((size_t)NN * 128 * 2);    // bf16 shadow of h (BN3)
    short* W1T   = (short*)alloc((size_t)128 * DIN * 2);
    short* W2T   = (short*)alloc((size_t)DIN * 128 * 2);
    int* ecnt  = (int*)alloc(EE * 4);
    int* eoff  = (int*)alloc((EE + 1) * 4);
    int* ecur  = (int*)alloc(EE * 4);
    int* elist = (int*)alloc(NNZC * 4);
    int* ncnt  = (int*)alloc(NN * 4);
    int* noff  = (int*)alloc((NN + 1) * 4);
    int* ncur  = (int*)alloc(NN * 4);
    int* nlist = (int*)alloc(NNZC * 4);

    short* xb   = (short*)d_out;       // bf16 copy of x in dead space of d_out
    short* outb = (short*)scratch;     // pre-BN4 bf16 scratch

    hipMemsetAsync(ecnt, 0, EE * 4, stream);
    hipMemsetAsync(ncnt, 0, NN * 4, stream);
    hipMemsetAsync(ecur, 0, EE * 4, stream);
    hipMemsetAsync(ncur, 0, NN * 4, stream);

    count_kernel<<<(NNZC + 255) / 256, 256, 0, stream>>>(edge_idx, node_idx, ecnt, ncnt);
    transpose_to_bf16<<<dim3(4, 32), 256, 0, stream>>>(W1, W1T, DIN, 128);
    transpose_to_bf16<<<dim3(32, 4), 256, 0, stream>>>(W2, W2T, 128, DIN);
    scan_two<<<2, 1024, 0, stream>>>(ecnt, eoff, ncnt, noff);
    fill_lists<<<(NNZC + 255) / 256, 256, 0, stream>>>(edge_idx, node_idx, eoff, noff,
                                                       ecur, ncur, elist, nlist);

    const int MB64  = (NN + 63) / 64;     // 469
    const int MB128 = (NN + 127) / 128;   // 235

    // h = leaky(x @ W1 + b1)   [MFMA, BM=64, f32-A cvt-on-stage + xb dump, BN1 stats]
    hipMemsetAsync(accum, 0, 256 * 4, stream);
    gemm_mfma<1, true, true, true, true, false, true, false, false>
        <<<MB64, 256, 0, stream>>>(x, W1T, b1, nullptr, h, accum, xb, NN, DIN, 128, 1);
    bn_apply_f<false><<<1024, 256, 0, stream>>>(h, nullptr, (long long)NN * 128 / 4, accum,
                                                bn1_g, bn1_b, 1.0f / NN);

    // ---- hconv1 (heads=4), linearity-refactored ----
    edge_feat<<<EE, 128, 0, stream>>>(elist, eoff, node_idx, h, he);
    watt_kernel<4><<<1, 512, 0, stream>>>(h1_lin, h1_att, wax, wae);
    dots128<4><<<(NN + 3) / 4, 256, 0, stream>>>(h, wax, ax, NN);
    dots128<4><<<(EE + 3) / 4, 256, 0, stream>>>(he, wae, ae, EE);
    edge_softmax<4><<<EE, 256, 0, stream>>>(elist, eoff, node_idx, ax, ae, alpha);
    edge_agg128<4><<<EE, 512, 0, stream>>>(elist, eoff, node_idx, alpha, h, agg);
    oute_lin<4><<<EE, 512, 0, stream>>>(agg, h1_lin, oute);
    node_aggregate<4><<<NN, 512, 0, stream>>>(nlist, noff, edge_idx, alpha, oute, h1_bias, h);

    // BN2
    hipMemsetAsync(accum, 0, 256 * 4, stream);
    bn_stats<<<512, 256, 0, stream>>>(h, (long long)NN * 128 / 4, accum);
    bn_apply_f<false><<<1024, 256, 0, stream>>>(h, nullptr, (long long)NN * 128 / 4, accum,
                                                bn2_g, bn2_b, 1.0f / NN);

    // ---- hconv2 (heads=1), linearity-refactored ----
    edge_feat<<<EE, 128, 0, stream>>>(elist, eoff, node_idx, h, he);
    watt_kernel<1><<<1, 128, 0, stream>>>(h2_lin, h2_att, wax, wae);
    dots128<1><<<(NN + 3) / 4, 256, 0, stream>>>(h, wax, ax, NN);
    dots128<1><<<(EE + 3) / 4, 256, 0, stream>>>(he, wae, ae, EE);
    edge_softmax<1><<<EE, 256, 0, stream>>>(elist, eoff, node_idx, ax, ae, alpha);
    edge_agg128<1><<<EE, 128, 0, stream>>>(elist, eoff, node_idx, alpha, h, agg);
    oute_lin<1><<<EE, 128, 0, stream>>>(agg, h2_lin, oute);
    node_aggregate<1><<<NN, 128, 0, stream>>>(nlist, noff, edge_idx, alpha, oute, h2_bias, h);

    // BN3 (shadow feeds W2)
    hipMemsetAsync(accum, 0, 256 * 4, stream);
    bn_stats<<<512, 256, 0, stream>>>(h, (long long)NN * 128 / 4, accum);
    bn_apply_f<true><<<1024, 256, 0, stream>>>(h, hb, (long long)NN * 128 / 4, accum,
                                               bn3_g, bn3_b, 1.0f / NN);

    // out_pre = xb + leaky(hb @ W2 + b2) -> bf16 scratch
    // [MFMA + BN4 stats fused + XCD-bijective swizzle: grid 1880 = 8 XCD chunks x 235]
    hipMemsetAsync(accum, 0, 256 * 4, stream);
    gemm_mfma<2, false, false, true, true, true, true, true, true>
        <<<8 * MB128, 256, 0, stream>>>(hb, W2T, b2, xb, outb, accum, nullptr, NN, 128, DIN, 8);

    // BN4: bf16 -> f32 out (overwrites all of d_out incl. xb scratch)
    bn_apply_b2f<<<2048, 256, 0, stream>>>(outb, out, (long long)NN * DIN / 4, accum,
                                           bn4_g, bn4_b, 1.0f / (NN * PP));
}

// Round 14
// 842.571 us; speedup vs baseline: 1.0348x; 1.0153x over previous
//
#include <hip/hip_runtime.h>
#include <math.h>

#define NN 30000
#define PP 8
#define DM 128
#define EE 1000
#define NNZC 120000
#define DIN (PP*DM)   // 1024

typedef __attribute__((ext_vector_type(8))) short bf16x8;
typedef __attribute__((ext_vector_type(4))) float f32x4;

__device__ __forceinline__ short f2bf(float f) {
    union { float f; unsigned u; } v; v.f = f;
    unsigned r = v.u + 0x7fffu + ((v.u >> 16) & 1u);
    return (short)(r >> 16);
}
__device__ __forceinline__ float bf2f(short s) {
    union { unsigned u; float f; } v;
    v.u = ((unsigned)(unsigned short)s) << 16;
    return v.f;
}

// ---------------------------------------------------------------- CSR build
__global__ void count_kernel(const int* __restrict__ ei, const int* __restrict__ ni,
                             int* __restrict__ ecnt, int* __restrict__ ncnt) {
    int k = blockIdx.x * 256 + threadIdx.x;
    if (k >= NNZC) return;
    atomicAdd(&ecnt[ei[k]], 1);
    atomicAdd(&ncnt[ni[k]], 1);
}

__global__ __launch_bounds__(1024)
void scan_two(const int* __restrict__ ecnt, int* __restrict__ eoff,
              const int* __restrict__ ncnt, int* __restrict__ noff) {
    const int* cnt; int* off; int len;
    if (blockIdx.x == 0) { cnt = ecnt; off = eoff; len = EE; }
    else                 { cnt = ncnt; off = noff; len = NN; }
    __shared__ int wsum[16];
    __shared__ int carrysh;
    int t = threadIdx.x;
    int lane = t & 63, w = t >> 6;
    if (t == 0) carrysh = 0;
    __syncthreads();
    for (int base = 0; base < len; base += 1024) {
        int v = (base + t < len) ? cnt[base + t] : 0;
        int s = v;
        #pragma unroll
        for (int d = 1; d < 64; d <<= 1) {
            int u = __shfl_up(s, d);
            if (lane >= d) s += u;
        }
        if (lane == 63) wsum[w] = s;
        __syncthreads();
        if (t < 16) {
            int ws = wsum[t];
            #pragma unroll
            for (int d = 1; d < 16; d <<= 1) {
                int u = __shfl_up(ws, d);
                if (t >= d) ws += u;
            }
            wsum[t] = ws;
        }
        __syncthreads();
        int c = carrysh;
        int woff = (w > 0) ? wsum[w - 1] : 0;
        if (base + t < len) off[base + t] = c + woff + s - v;
        int total = wsum[15];
        __syncthreads();
        if (t == 0) carrysh = c + total;
    }
    __syncthreads();
    if (t == 0) off[len] = carrysh;
}

__global__ void fill_lists(const int* __restrict__ ei, const int* __restrict__ ni,
                           const int* __restrict__ eoff, const int* __restrict__ noff,
                           int* __restrict__ ecur, int* __restrict__ ncur,
                           int* __restrict__ elist, int* __restrict__ nlist) {
    int k = blockIdx.x * 256 + threadIdx.x;
    if (k >= NNZC) return;
    int e = ei[k];
    int p = atomicAdd(&ecur[e], 1);
    elist[eoff[e] + p] = k;
    int n = ni[k];
    int q = atomicAdd(&ncur[n], 1);
    nlist[noff[n] + q] = k;
}

// ---------------------------------------------------------------- weight transpose+convert
__global__ void transpose_to_bf16(const float* __restrict__ B, short* __restrict__ BT,
                                  int K, int N) {
    __shared__ float tile[32][33];
    int bn = blockIdx.x * 32, bk = blockIdx.y * 32;
    int tx = threadIdx.x & 31, ty = threadIdx.x >> 5;
    #pragma unroll
    for (int yy = ty; yy < 32; yy += 8) {
        int k = bk + yy, n = bn + tx;
        tile[yy][tx] = (k < K && n < N) ? B[(size_t)k * N + n] : 0.f;
    }
    __syncthreads();
    #pragma unroll
    for (int yy = ty; yy < 32; yy += 8) {
        int n = bn + yy, k = bk + tx;
        if (n < N && k < K) BT[(size_t)n * K + k] = f2bf(tile[tx][yy]);
    }
}

// ---------------------------------------------------------------- bf16 MFMA GEMM
// STATS now writes per-block partials to spart (no same-address global atomics).
template<int RG, bool AF32, bool DUMPA, bool HASBIAS, bool LEAKY, bool ADDSRC,
         bool STATS, bool OUTBF16, bool SWZ>
__global__ __launch_bounds__(256)
void gemm_mfma(const void* __restrict__ Ain, const short* __restrict__ BT,
               const float* __restrict__ bias, const short* __restrict__ srcb,
               void* __restrict__ Cout, float* __restrict__ spart,
               short* __restrict__ Adump, int M, int K, int Nc, int colB) {
    constexpr int BM = 64 * RG;
    __shared__ short As[BM * 40];
    __shared__ short Bs[128 * 40];
    const int tid = threadIdx.x;
    const int lane = tid & 63, wid = tid >> 6;
    const int wm = wid >> 1, wn = wid & 1;

    int row0, col0;
    {
        int w = blockIdx.x;
        int l;
        if (SWZ) { int cpx = gridDim.x >> 3; l = (w & 7) * cpx + (w >> 3); }
        else     { l = w; }
        row0 = (l / colB) * BM;
        col0 = (l % colB) * 128;
    }
    const int srow = tid >> 2, skq = tid & 3;

    f32x4 acc[RG * 2][4] = {};
    const int NT = K >> 5;

    struct Stage { float4 fa[RG][2]; bf16x8 a[RG]; bf16x8 b[2]; };
    Stage s0, s1;

    auto loadT = [&](int t, Stage& s) {
        int k0 = t << 5;
        #pragma unroll
        for (int c = 0; c < RG; ++c) {
            int gr = row0 + srow + 64 * c;
            if (AF32) {
                float4 z = make_float4(0.f, 0.f, 0.f, 0.f);
                s.fa[c][0] = z; s.fa[c][1] = z;
                if (gr < M) {
                    const float4* p = (const float4*)((const float*)Ain + (size_t)gr * K + k0 + skq * 8);
                    s.fa[c][0] = p[0]; s.fa[c][1] = p[1];
                }
            } else {
                s.a[c] = bf16x8{0, 0, 0, 0, 0, 0, 0, 0};
                if (gr < M)
                    s.a[c] = *(const bf16x8*)((const short*)Ain + (size_t)gr * K + k0 + skq * 8);
            }
        }
        #pragma unroll
        for (int c = 0; c < 2; ++c) {
            int gc = col0 + srow + 64 * c;
            s.b[c] = *(const bf16x8*)(BT + (size_t)gc * K + k0 + skq * 8);
        }
    };
    auto writeT = [&](int t, Stage& s) {
        int k0 = t << 5;
        #pragma unroll
        for (int c = 0; c < RG; ++c) {
            bf16x8 t8;
            if (AF32) {
                t8[0] = f2bf(s.fa[c][0].x); t8[1] = f2bf(s.fa[c][0].y);
                t8[2] = f2bf(s.fa[c][0].z); t8[3] = f2bf(s.fa[c][0].w);
                t8[4] = f2bf(s.fa[c][1].x); t8[5] = f2bf(s.fa[c][1].y);
                t8[6] = f2bf(s.fa[c][1].z); t8[7] = f2bf(s.fa[c][1].w);
                if (DUMPA) {
                    int gr = row0 + srow + 64 * c;
                    if (gr < M)
                        *(bf16x8*)(Adump + (size_t)gr * K + k0 + skq * 8) = t8;
                }
            } else {
                t8 = s.a[c];
            }
            *(bf16x8*)&As[(srow + 64 * c) * 40 + skq * 8] = t8;
        }
        #pragma unroll
        for (int c = 0; c < 2; ++c)
            *(bf16x8*)&Bs[(srow + 64 * c) * 40 + skq * 8] = s.b[c];
    };
    auto compute = [&]() {
        bf16x8 av[RG * 2], bv[4];
        #pragma unroll
        for (int i = 0; i < RG * 2; ++i)
            av[i] = *(const bf16x8*)&As[(wm * (RG * 32) + i * 16 + (lane & 15)) * 40 + (lane >> 4) * 8];
        #pragma unroll
        for (int j = 0; j < 4; ++j)
            bv[j] = *(const bf16x8*)&Bs[(wn * 64 + j * 16 + (lane & 15)) * 40 + (lane >> 4) * 8];
        #pragma unroll
        for (int i = 0; i < RG * 2; ++i)
            #pragma unroll
            for (int j = 0; j < 4; ++j)
                acc[i][j] = __builtin_amdgcn_mfma_f32_16x16x32_bf16(av[i], bv[j], acc[i][j], 0, 0, 0);
    };

    loadT(0, s0);
    for (int t = 0; t < NT; t += 2) {
        __syncthreads();
        loadT(t + 1, s1);
        writeT(t, s0);
        __syncthreads();
        compute();
        __syncthreads();
        if (t + 2 < NT) loadT(t + 2, s0);
        writeT(t + 1, s1);
        __syncthreads();
        compute();
    }

    // epilogue: wave-coalesced register stores (col=lane&15 consecutive)
    float* Cf = (float*)Cout;
    short* Cb = (short*)Cout;
    float lsum[4] = {0.f, 0.f, 0.f, 0.f}, lsq[4] = {0.f, 0.f, 0.f, 0.f};
    #pragma unroll
    for (int i = 0; i < RG * 2; ++i) {
        #pragma unroll
        for (int q = 0; q < 4; ++q) {
            int row = row0 + wm * (RG * 32) + i * 16 + (lane >> 4) * 4 + q;
            if (row < M) {
                #pragma unroll
                for (int j = 0; j < 4; ++j) {
                    int col = col0 + wn * 64 + j * 16 + (lane & 15);
                    float val = acc[i][j][q];
                    if (HASBIAS) val += bias[col];
                    if (LEAKY)   val = val > 0.f ? val : 0.2f * val;
                    if (ADDSRC)  val += bf2f(srcb[(size_t)row * Nc + col]);
                    if (STATS) { lsum[j] += val; lsq[j] += val * val; }
                    if (OUTBF16) Cb[(size_t)row * Nc + col] = f2bf(val);
                    else         Cf[(size_t)row * Nc + col] = val;
                }
            }
        }
    }
    if (STATS) {
        __syncthreads();
        float* sred = (float*)As;
        sred[tid] = 0.f;
        __syncthreads();
        int ch = wn * 64 + (lane & 15);
        #pragma unroll
        for (int j = 0; j < 4; ++j) {
            atomicAdd(&sred[ch + j * 16], lsum[j]);
            atomicAdd(&sred[128 + ch + j * 16], lsq[j]);
        }
        __syncthreads();
        // per-block partial: plain coalesced store, NO same-address global atomics
        spart[(size_t)blockIdx.x * 256 + tid] = sred[tid];
    }
}

// ---------------------------------------------------------------- fold per-block partials into accum[256]
__global__ void reduce_stats(const float* __restrict__ part, int nblk, float* __restrict__ accum) {
    int t = threadIdx.x;
    float s = 0.f;
    for (int b = blockIdx.x; b < nblk; b += gridDim.x)
        s += part[(size_t)b * 256 + t];
    atomicAdd(&accum[t], s);   // 32 atomics/address max
}

// ---------------------------------------------------------------- BatchNorm stats (float4)
__global__ void bn_stats(const float* __restrict__ a, long long total4, float* __restrict__ accum) {
    int t = threadIdx.x;
    long long idx = (long long)blockIdx.x * 256 + t;
    long long stride = (long long)gridDim.x * 256;
    const float4* a4 = (const float4*)a;
    float s1[4] = {0.f,0.f,0.f,0.f}, s2[4] = {0.f,0.f,0.f,0.f};
    for (; idx < total4; idx += stride) {
        float4 v = a4[idx];
        s1[0] += v.x; s2[0] += v.x * v.x;
        s1[1] += v.y; s2[1] += v.y * v.y;
        s1[2] += v.z; s2[2] += v.z * v.z;
        s1[3] += v.w; s2[3] += v.w * v.w;
    }
    __shared__ float r1[256][4], r2[256][4];
    #pragma unroll
    for (int k = 0; k < 4; ++k) { r1[t][k] = s1[k]; r2[t][k] = s2[k]; }
    __syncthreads();
    if (t < 32) {
        #pragma unroll
        for (int k = 0; k < 4; ++k) {
            float a1 = 0.f, a2 = 0.f;
            #pragma unroll
            for (int u = 0; u < 8; ++u) { a1 += r1[t + u * 32][k]; a2 += r2[t + u * 32][k]; }
            atomicAdd(&accum[t * 4 + k], a1);
            atomicAdd(&accum[128 + t * 4 + k], a2);
        }
    }
}

// ---------------------------------------------------------------- BN finalize+apply (f32 in/out, optional bf16 shadow)
template<bool SHADOW>
__global__ void bn_apply_f(float* __restrict__ a, short* __restrict__ shadow, long long total4,
                           const float* __restrict__ accum, const float* __restrict__ g,
                           const float* __restrict__ b, float invM) {
    __shared__ float scs[256];
    int t = threadIdx.x;
    if (t < 128) {
        float mean = accum[t] * invM;
        float var = accum[128 + t] * invM - mean * mean;
        float s = g[t] * rsqrtf(var + 1e-5f);
        scs[t] = s;
        scs[128 + t] = b[t] - mean * s;
    }
    __syncthreads();
    long long idx = (long long)blockIdx.x * 256 + t;
    long long stride = (long long)gridDim.x * 256;
    float4* a4 = (float4*)a;
    short4* s4p = (short4*)shadow;
    for (; idx < total4; idx += stride) {
        int c = (int)((idx & 31) * 4);
        float4 v = a4[idx];
        v.x = v.x * scs[c + 0] + scs[128 + c + 0];
        v.y = v.y * scs[c + 1] + scs[128 + c + 1];
        v.z = v.z * scs[c + 2] + scs[128 + c + 2];
        v.w = v.w * scs[c + 3] + scs[128 + c + 3];
        a4[idx] = v;
        if (SHADOW)
            s4p[idx] = make_short4(f2bf(v.x), f2bf(v.y), f2bf(v.z), f2bf(v.w));
    }
}

// ---------------------------------------------------------------- BN apply bf16 -> f32
__global__ void bn_apply_b2f(const short* __restrict__ inb, float* __restrict__ outp,
                             long long total4, const float* __restrict__ accum,
                             const float* __restrict__ g, const float* __restrict__ b, float invM) {
    __shared__ float scs[256];
    int t = threadIdx.x;
    if (t < 128) {
        float mean = accum[t] * invM;
        float var = accum[128 + t] * invM - mean * mean;
        float s = g[t] * rsqrtf(var + 1e-5f);
        scs[t] = s;
        scs[128 + t] = b[t] - mean * s;
    }
    __syncthreads();
    long long idx = (long long)blockIdx.x * 256 + t;
    long long stride = (long long)gridDim.x * 256;
    const short4* in4 = (const short4*)inb;
    float4* o4 = (float4*)outp;
    for (; idx < total4; idx += stride) {
        int c = (int)((idx & 31) * 4);
        short4 sv = in4[idx];
        float4 v;
        v.x = bf2f(sv.x) * scs[c + 0] + scs[128 + c + 0];
        v.y = bf2f(sv.y) * scs[c + 1] + scs[128 + c + 1];
        v.z = bf2f(sv.z) * scs[c + 2] + scs[128 + c + 2];
        v.w = bf2f(sv.w) * scs[c + 3] + scs[128 + c + 3];
        o4[idx] = v;
    }
}

// ---------------------------------------------------------------- he_attr: 256 thr, 2-way member split
__global__ void edge_feat(const int* __restrict__ elist, const int* __restrict__ eoff,
                          const int* __restrict__ nidx, const float* __restrict__ h,
                          float* __restrict__ he) {
    __shared__ float red[128];
    int e = blockIdx.x;
    int off = eoff[e], cnt = eoff[e + 1] - off;
    int d = threadIdx.x & 127, half = threadIdx.x >> 7;
    float acc = 0.f;
    for (int p = half; p < cnt; p += 2) {
        int k = elist[off + p];
        int n = nidx[k];
        acc += h[(size_t)n * 128 + d];
    }
    if (half == 1) red[d] = acc;
    __syncthreads();
    if (half == 0) he[(size_t)e * 128 + d] = acc + red[d];
}

// ---------------------------------------------------------------- w_att precompute
template<int H>
__global__ void watt_kernel(const float* __restrict__ lin, const float* __restrict__ att,
                            float* __restrict__ wx, float* __restrict__ we) {
    int t = threadIdx.x;            // H*128 threads
    int hh = t >> 7, d = t & 127;
    float sx = 0.f, se = 0.f;
    for (int j = 0; j < 128; ++j) {
        float l = lin[(size_t)d * (H * 128) + hh * 128 + j];
        sx += l * att[hh * 256 + j];
        se += l * att[hh * 256 + 128 + j];
    }
    wx[t] = sx;
    we[t] = se;
}

// ---------------------------------------------------------------- dots: out[row,h] = h_row . w[h]
template<int H>
__global__ void dots128(const float* __restrict__ feat, const float* __restrict__ w,
                        float* __restrict__ out, int M) {
    int wv = threadIdx.x >> 6;
    int lane = threadIdx.x & 63;
    int row = blockIdx.x * 4 + wv;
    if (row >= M) return;
    const float* fr = feat + (size_t)row * 128;
    float f0 = fr[lane], f1 = fr[lane + 64];
    #pragma unroll
    for (int h = 0; h < H; ++h) {
        float v = f0 * w[h * 128 + lane] + f1 * w[h * 128 + lane + 64];
        #pragma unroll
        for (int s = 32; s > 0; s >>= 1) v += __shfl_xor(v, s);
        if (lane == 0) out[(size_t)row * H + h] = v;
    }
}

// ---------------------------------------------------------------- per-edge segment softmax
template<int H>
__global__ void edge_softmax(const int* __restrict__ elist, const int* __restrict__ eoff,
                             const int* __restrict__ nidx, const float* __restrict__ ax,
                             const float* __restrict__ ae, float* __restrict__ alpha) {
    constexpr int SLOTS = 256 / H;
    __shared__ float red[256];
    int e = blockIdx.x;
    int off = eoff[e], cnt = eoff[e + 1] - off;
    int t = threadIdx.x;
    int h = t % H, slot = t / H;
    float aeh = ae[(size_t)e * H + h];
    float lmax = -1e30f;
    for (int p = slot; p < cnt; p += SLOTS) {
        int k = elist[off + p];
        int n = nidx[k];
        float v = ax[(size_t)n * H + h] + aeh;
        v = v > 0.f ? v : 0.2f * v;
        alpha[(size_t)k * H + h] = v;
        lmax = fmaxf(lmax, v);
    }
    red[t] = lmax;
    __syncthreads();
    for (int s = SLOTS / 2; s > 0; s >>= 1) {
        if (slot < s) red[slot * H + h] = fmaxf(red[slot * H + h], red[(slot + s) * H + h]);
        __syncthreads();
    }
    float m = red[h];
    __syncthreads();
    float lsum = 0.f;
    for (int p = slot; p < cnt; p += SLOTS) {
        int k = elist[off + p];
        float ex = expf(alpha[(size_t)k * H + h] - m);
        alpha[(size_t)k * H + h] = ex;
        lsum += ex;
    }
    red[t] = lsum;
    __syncthreads();
    for (int s = SLOTS / 2; s > 0; s >>= 1) {
        if (slot < s) red[slot * H + h] += red[(slot + s) * H + h];
        __syncthreads();
    }
    float inv = 1.0f / (red[h] + 1e-16f);
    for (int p = slot; p < cnt; p += SLOTS) {
        int k = elist[off + p];
        alpha[(size_t)k * H + h] *= inv;
    }
}

// ---------------------------------------------------------------- agg_e (128-space)
template<int H>
__global__ void edge_agg128(const int* __restrict__ elist, const int* __restrict__ eoff,
                            const int* __restrict__ nidx, const float* __restrict__ alpha,
                            const float* __restrict__ h, float* __restrict__ agg) {
    int e = blockIdx.x;
    int off = eoff[e], cnt = eoff[e + 1] - off;
    int t = threadIdx.x;            // H*128 threads
    int hh = t >> 7, d = t & 127;
    float acc = 0.f;
    for (int p = 0; p < cnt; ++p) {
        int k = elist[off + p];
        int n = nidx[k];
        acc += alpha[(size_t)k * H + hh] * h[(size_t)n * 128 + d];
    }
    float binv = cnt > 0 ? 1.0f / (float)cnt : 0.0f;
    agg[(size_t)e * (H * 128) + t] = acc * binv;
}

// ---------------------------------------------------------------- oute[e,h,j] = sum_d agg[e,h,d] * lin[d, h*128+j]
template<int H>
__global__ void oute_lin(const float* __restrict__ agg, const float* __restrict__ lin,
                         float* __restrict__ oute) {
    __shared__ float ar[H * 128];
    int e = blockIdx.x;
    int t = threadIdx.x;            // H*128 threads
    ar[t] = agg[(size_t)e * (H * 128) + t];
    __syncthreads();
    int hh = t >> 7;
    float acc = 0.f;
    #pragma unroll 4
    for (int d = 0; d < 128; ++d)
        acc += ar[hh * 128 + d] * lin[(size_t)d * (H * 128) + t];
    oute[(size_t)e * (H * 128) + t] = acc;
}

// ---------------------------------------------------------------- node side
template<int H>
__global__ void node_aggregate(const int* __restrict__ nlist, const int* __restrict__ noff,
                               const int* __restrict__ eidx, const float* __restrict__ alpha,
                               const float* __restrict__ out_e, const float* __restrict__ bias,
                               float* __restrict__ hout) {
    __shared__ float red[H * 128];
    int n = blockIdx.x;
    int off = noff[n], cnt = noff[n + 1] - off;
    int t = threadIdx.x;            // H*128 threads
    int h = t >> 7;
    float acc = 0.f;
    for (int p = 0; p < cnt; ++p) {
        int k = nlist[off + p];
        int e = eidx[k];
        acc += alpha[(size_t)k * H + h] * out_e[(size_t)e * (H * 128) + t];
    }
    float dinv = cnt > 0 ? 1.0f / (float)cnt : 0.0f;
    acc *= dinv;
    if (H == 1) {
        hout[(size_t)n * 128 + t] += acc + bias[t];
    } else {
        red[t] = acc;
        __syncthreads();
        if (t < 128) {
            float s = 0.f;
            #pragma unroll
            for (int hh = 0; hh < H; ++hh) s += red[hh * 128 + t];
            hout[(size_t)n * 128 + t] += s * (1.0f / H) + bias[t];
        }
    }
}

// ---------------------------------------------------------------- launch
extern "C" void kernel_launch(void* const* d_in, const int* in_sizes, int n_in,
                              void* d_out, int out_size, void* d_ws, size_t ws_size,
                              hipStream_t stream) {
    (void)in_sizes; (void)n_in; (void)out_size; (void)ws_size;
    const float* x        = (const float*)d_in[0];
    const int*   node_idx = (const int*)d_in[1];
    const int*   edge_idx = (const int*)d_in[2];
    const float* W1    = (const float*)d_in[4];
    const float* b1    = (const float*)d_in[5];
    const float* bn1_g = (const float*)d_in[6];
    const float* bn1_b = (const float*)d_in[7];
    const float* h1_lin  = (const float*)d_in[8];
    const float* h1_att  = (const float*)d_in[9];
    const float* h1_bias = (const float*)d_in[10];
    const float* bn2_g = (const float*)d_in[11];
    const float* bn2_b = (const float*)d_in[12];
    const float* h2_lin  = (const float*)d_in[13];
    const float* h2_att  = (const float*)d_in[14];
    const float* h2_bias = (const float*)d_in[15];
    const float* bn3_g = (const float*)d_in[16];
    const float* bn3_b = (const float*)d_in[17];
    const float* W2    = (const float*)d_in[18];
    const float* b2    = (const float*)d_in[19];
    const float* bn4_g = (const float*)d_in[20];
    const float* bn4_b = (const float*)d_in[21];
    float* out = (float*)d_out;

    char* ws = (char*)d_ws;
    size_t off = 0;
    auto alloc = [&](size_t bytes) -> void* {
        void* p = ws + off;
        off = (off + bytes + 255) & ~(size_t)255;
        return p;
    };
    float* h     = (float*)alloc((size_t)NN * 128 * 4);
    float* scratch = (float*)alloc((size_t)NN * 512 * 4);   // pre-BN4 bf16 home
    float* he    = (float*)alloc((size_t)EE * 128 * 4);
    float* agg   = (float*)alloc((size_t)EE * 512 * 4);
    float* oute  = (float*)alloc((size_t)EE * 512 * 4);
    float* ax    = (float*)alloc((size_t)NN * 4 * 4);
    float* ae    = (float*)alloc((size_t)EE * 4 * 4);
    float* alpha = (float*)alloc((size_t)NNZC * 4 * 4);
    float* accum = (float*)alloc(256 * 4);
    float* spart = (float*)alloc((size_t)1880 * 256 * 4);
    float* wax   = (float*)alloc(512 * 4);
    float* wae   = (float*)alloc(512 * 4);
    short* hb    = (short*)alloc((size_t)NN * 128 * 2);    // bf16 shadow of h (BN3)
    short* W1T   = (short*)alloc((size_t)128 * DIN * 2);
    short* W2T   = (short*)alloc((size_t)DIN * 128 * 2);
    int* ecnt  = (int*)alloc(EE * 4);
    int* eoff  = (int*)alloc((EE + 1) * 4);
    int* ecur  = (int*)alloc(EE * 4);
    int* elist = (int*)alloc(NNZC * 4);
    int* ncnt  = (int*)alloc(NN * 4);
    int* noff  = (int*)alloc((NN + 1) * 4);
    int* ncur  = (int*)alloc(NN * 4);
    int* nlist = (int*)alloc(NNZC * 4);

    short* xb   = (short*)d_out;       // bf16 copy of x in dead space of d_out
    short* outb = (short*)scratch;     // pre-BN4 bf16 scratch

    hipMemsetAsync(ecnt, 0, EE * 4, stream);
    hipMemsetAsync(ncnt, 0, NN * 4, stream);
    hipMemsetAsync(ecur, 0, EE * 4, stream);
    hipMemsetAsync(ncur, 0, NN * 4, stream);

    count_kernel<<<(NNZC + 255) / 256, 256, 0, stream>>>(edge_idx, node_idx, ecnt, ncnt);
    transpose_to_bf16<<<dim3(4, 32), 256, 0, stream>>>(W1, W1T, DIN, 128);
    transpose_to_bf16<<<dim3(32, 4), 256, 0, stream>>>(W2, W2T, 128, DIN);
    scan_two<<<2, 1024, 0, stream>>>(ecnt, eoff, ncnt, noff);
    fill_lists<<<(NNZC + 255) / 256, 256, 0, stream>>>(edge_idx, node_idx, eoff, noff,
                                                       ecur, ncur, elist, nlist);

    const int MB64  = (NN + 63) / 64;     // 469
    const int MB128 = (NN + 127) / 128;   // 235

    // h = leaky(x @ W1 + b1)   [MFMA, BM=64, f32-A cvt-on-stage + xb dump, BN1 partial stats]
    hipMemsetAsync(accum, 0, 256 * 4, stream);
    gemm_mfma<1, true, true, true, true, false, true, false, false>
        <<<MB64, 256, 0, stream>>>(x, W1T, b1, nullptr, h, spart, xb, NN, DIN, 128, 1);
    reduce_stats<<<32, 256, 0, stream>>>(spart, MB64, accum);
    bn_apply_f<false><<<1024, 256, 0, stream>>>(h, nullptr, (long long)NN * 128 / 4, accum,
                                                bn1_g, bn1_b, 1.0f / NN);

    // ---- hconv1 (heads=4), linearity-refactored ----
    edge_feat<<<EE, 256, 0, stream>>>(elist, eoff, node_idx, h, he);
    watt_kernel<4><<<1, 512, 0, stream>>>(h1_lin, h1_att, wax, wae);
    dots128<4><<<(NN + 3) / 4, 256, 0, stream>>>(h, wax, ax, NN);
    dots128<4><<<(EE + 3) / 4, 256, 0, stream>>>(he, wae, ae, EE);
    edge_softmax<4><<<EE, 256, 0, stream>>>(elist, eoff, node_idx, ax, ae, alpha);
    edge_agg128<4><<<EE, 512, 0, stream>>>(elist, eoff, node_idx, alpha, h, agg);
    oute_lin<4><<<EE, 512, 0, stream>>>(agg, h1_lin, oute);
    node_aggregate<4><<<NN, 512, 0, stream>>>(nlist, noff, edge_idx, alpha, oute, h1_bias, h);

    // BN2
    hipMemsetAsync(accum, 0, 256 * 4, stream);
    bn_stats<<<512, 256, 0, stream>>>(h, (long long)NN * 128 / 4, accum);
    bn_apply_f<false><<<1024, 256, 0, stream>>>(h, nullptr, (long long)NN * 128 / 4, accum,
                                                bn2_g, bn2_b, 1.0f / NN);

    // ---- hconv2 (heads=1), linearity-refactored ----
    edge_feat<<<EE, 256, 0, stream>>>(elist, eoff, node_idx, h, he);
    watt_kernel<1><<<1, 128, 0, stream>>>(h2_lin, h2_att, wax, wae);
    dots128<1><<<(NN + 3) / 4, 256, 0, stream>>>(h, wax, ax, NN);
    dots128<1><<<(EE + 3) / 4, 256, 0, stream>>>(he, wae, ae, EE);
    edge_softmax<1><<<EE, 256, 0, stream>>>(elist, eoff, node_idx, ax, ae, alpha);
    edge_agg128<1><<<EE, 128, 0, stream>>>(elist, eoff, node_idx, alpha, h, agg);
    oute_lin<1><<<EE, 128, 0, stream>>>(agg, h2_lin, oute);
    node_aggregate<1><<<NN, 128, 0, stream>>>(nlist, noff, edge_idx, alpha, oute, h2_bias, h);

    // BN3 (shadow feeds W2)
    hipMemsetAsync(accum, 0, 256 * 4, stream);
    bn_stats<<<512, 256, 0, stream>>>(h, (long long)NN * 128 / 4, accum);
    bn_apply_f<true><<<1024, 256, 0, stream>>>(h, hb, (long long)NN * 128 / 4, accum,
                                               bn3_g, bn3_b, 1.0f / NN);

    // out_pre = xb + leaky(hb @ W2 + b2) -> bf16 scratch
    // [MFMA + BN4 partial stats + XCD-bijective swizzle: grid 1880]
    hipMemsetAsync(accum, 0, 256 * 4, stream);
    gemm_mfma<2, false, false, true, true, true, true, true, true>
        <<<8 * MB128, 256, 0, stream>>>(hb, W2T, b2, xb, outb, spart, nullptr, NN, 128, DIN, 8);
    reduce_stats<<<32, 256, 0, stream>>>(spart, 8 * MB128, accum);

    // BN4: bf16 -> f32 out (overwrites all of d_out incl. xb scratch)
    bn_apply_b2f<<<2048, 256, 0, stream>>>(outb, out, (long long)NN * DIN / 4, accum,
                                           bn4_g, bn4_b, 1.0f / (NN * PP));
}

// Round 15
// 727.076 us; speedup vs baseline: 1.1992x; 1.1588x over previous
//
#include <hip/hip_runtime.h>
#include <math.h>

#define NN 30000
#define PP 8
#define DM 128
#define EE 1000
#define NNZC 120000
#define DIN (PP*DM)   // 1024

typedef __attribute__((ext_vector_type(8))) short bf16x8;
typedef __attribute__((ext_vector_type(4))) float f32x4;

__device__ __forceinline__ short f2bf(float f) {
    union { float f; unsigned u; } v; v.f = f;
    unsigned r = v.u + 0x7fffu + ((v.u >> 16) & 1u);
    return (short)(r >> 16);
}
__device__ __forceinline__ float bf2f(short s) {
    union { unsigned u; float f; } v;
    v.u = ((unsigned)(unsigned short)s) << 16;
    return v.f;
}

// ---------------------------------------------------------------- CSR build
__global__ void count_kernel(const int* __restrict__ ei, const int* __restrict__ ni,
                             int* __restrict__ ecnt, int* __restrict__ ncnt) {
    int k = blockIdx.x * 256 + threadIdx.x;
    if (k >= NNZC) return;
    atomicAdd(&ecnt[ei[k]], 1);
    atomicAdd(&ncnt[ni[k]], 1);
}

__global__ __launch_bounds__(1024)
void scan_two(const int* __restrict__ ecnt, int* __restrict__ eoff,
              const int* __restrict__ ncnt, int* __restrict__ noff) {
    const int* cnt; int* off; int len;
    if (blockIdx.x == 0) { cnt = ecnt; off = eoff; len = EE; }
    else                 { cnt = ncnt; off = noff; len = NN; }
    __shared__ int wsum[16];
    __shared__ int carrysh;
    int t = threadIdx.x;
    int lane = t & 63, w = t >> 6;
    if (t == 0) carrysh = 0;
    __syncthreads();
    for (int base = 0; base < len; base += 1024) {
        int v = (base + t < len) ? cnt[base + t] : 0;
        int s = v;
        #pragma unroll
        for (int d = 1; d < 64; d <<= 1) {
            int u = __shfl_up(s, d);
            if (lane >= d) s += u;
        }
        if (lane == 63) wsum[w] = s;
        __syncthreads();
        if (t < 16) {
            int ws = wsum[t];
            #pragma unroll
            for (int d = 1; d < 16; d <<= 1) {
                int u = __shfl_up(ws, d);
                if (t >= d) ws += u;
            }
            wsum[t] = ws;
        }
        __syncthreads();
        int c = carrysh;
        int woff = (w > 0) ? wsum[w - 1] : 0;
        if (base + t < len) off[base + t] = c + woff + s - v;
        int total = wsum[15];
        __syncthreads();
        if (t == 0) carrysh = c + total;
    }
    __syncthreads();
    if (t == 0) off[len] = carrysh;
}

__global__ void fill_lists(const int* __restrict__ ei, const int* __restrict__ ni,
                           const int* __restrict__ eoff, const int* __restrict__ noff,
                           int* __restrict__ ecur, int* __restrict__ ncur,
                           int* __restrict__ elist, int* __restrict__ nlist) {
    int k = blockIdx.x * 256 + threadIdx.x;
    if (k >= NNZC) return;
    int e = ei[k];
    int p = atomicAdd(&ecur[e], 1);
    elist[eoff[e] + p] = k;
    int n = ni[k];
    int q = atomicAdd(&ncur[n], 1);
    nlist[noff[n] + q] = k;
}

// ---------------------------------------------------------------- weight transpose+convert
__global__ void transpose_to_bf16(const float* __restrict__ B, short* __restrict__ BT,
                                  int K, int N) {
    __shared__ float tile[32][33];
    int bn = blockIdx.x * 32, bk = blockIdx.y * 32;
    int tx = threadIdx.x & 31, ty = threadIdx.x >> 5;
    #pragma unroll
    for (int yy = ty; yy < 32; yy += 8) {
        int k = bk + yy, n = bn + tx;
        tile[yy][tx] = (k < K && n < N) ? B[(size_t)k * N + n] : 0.f;
    }
    __syncthreads();
    #pragma unroll
    for (int yy = ty; yy < 32; yy += 8) {
        int n = bn + yy, k = bk + tx;
        if (n < N && k < K) BT[(size_t)n * K + k] = f2bf(tile[tx][yy]);
    }
}

// ---------------------------------------------------------------- bf16 MFMA GEMM  (R14: spart stats)
template<int RG, bool AF32, bool DUMPA, bool HASBIAS, bool LEAKY, bool ADDSRC,
         bool STATS, bool OUTBF16, bool SWZ>
__global__ __launch_bounds__(256)
void gemm_mfma(const void* __restrict__ Ain, const short* __restrict__ BT,
               const float* __restrict__ bias, const short* __restrict__ srcb,
               void* __restrict__ Cout, float* __restrict__ spart,
               short* __restrict__ Adump, int M, int K, int Nc, int colB) {
    constexpr int BM = 64 * RG;
    __shared__ short As[BM * 40];
    __shared__ short Bs[128 * 40];
    const int tid = threadIdx.x;
    const int lane = tid & 63, wid = tid >> 6;
    const int wm = wid >> 1, wn = wid & 1;

    int row0, col0;
    {
        int w = blockIdx.x;
        int l;
        if (SWZ) { int cpx = gridDim.x >> 3; l = (w & 7) * cpx + (w >> 3); }
        else     { l = w; }
        row0 = (l / colB) * BM;
        col0 = (l % colB) * 128;
    }
    const int srow = tid >> 2, skq = tid & 3;

    f32x4 acc[RG * 2][4] = {};
    const int NT = K >> 5;

    struct Stage { float4 fa[RG][2]; bf16x8 a[RG]; bf16x8 b[2]; };
    Stage s0, s1;

    auto loadT = [&](int t, Stage& s) {
        int k0 = t << 5;
        #pragma unroll
        for (int c = 0; c < RG; ++c) {
            int gr = row0 + srow + 64 * c;
            if (AF32) {
                float4 z = make_float4(0.f, 0.f, 0.f, 0.f);
                s.fa[c][0] = z; s.fa[c][1] = z;
                if (gr < M) {
                    const float4* p = (const float4*)((const float*)Ain + (size_t)gr * K + k0 + skq * 8);
                    s.fa[c][0] = p[0]; s.fa[c][1] = p[1];
                }
            } else {
                s.a[c] = bf16x8{0, 0, 0, 0, 0, 0, 0, 0};
                if (gr < M)
                    s.a[c] = *(const bf16x8*)((const short*)Ain + (size_t)gr * K + k0 + skq * 8);
            }
        }
        #pragma unroll
        for (int c = 0; c < 2; ++c) {
            int gc = col0 + srow + 64 * c;
            s.b[c] = *(const bf16x8*)(BT + (size_t)gc * K + k0 + skq * 8);
        }
    };
    auto writeT = [&](int t, Stage& s) {
        int k0 = t << 5;
        #pragma unroll
        for (int c = 0; c < RG; ++c) {
            bf16x8 t8;
            if (AF32) {
                t8[0] = f2bf(s.fa[c][0].x); t8[1] = f2bf(s.fa[c][0].y);
                t8[2] = f2bf(s.fa[c][0].z); t8[3] = f2bf(s.fa[c][0].w);
                t8[4] = f2bf(s.fa[c][1].x); t8[5] = f2bf(s.fa[c][1].y);
                t8[6] = f2bf(s.fa[c][1].z); t8[7] = f2bf(s.fa[c][1].w);
                if (DUMPA) {
                    int gr = row0 + srow + 64 * c;
                    if (gr < M)
                        *(bf16x8*)(Adump + (size_t)gr * K + k0 + skq * 8) = t8;
                }
            } else {
                t8 = s.a[c];
            }
            *(bf16x8*)&As[(srow + 64 * c) * 40 + skq * 8] = t8;
        }
        #pragma unroll
        for (int c = 0; c < 2; ++c)
            *(bf16x8*)&Bs[(srow + 64 * c) * 40 + skq * 8] = s.b[c];
    };
    auto compute = [&]() {
        bf16x8 av[RG * 2], bv[4];
        #pragma unroll
        for (int i = 0; i < RG * 2; ++i)
            av[i] = *(const bf16x8*)&As[(wm * (RG * 32) + i * 16 + (lane & 15)) * 40 + (lane >> 4) * 8];
        #pragma unroll
        for (int j = 0; j < 4; ++j)
            bv[j] = *(const bf16x8*)&Bs[(wn * 64 + j * 16 + (lane & 15)) * 40 + (lane >> 4) * 8];
        #pragma unroll
        for (int i = 0; i < RG * 2; ++i)
            #pragma unroll
            for (int j = 0; j < 4; ++j)
                acc[i][j] = __builtin_amdgcn_mfma_f32_16x16x32_bf16(av[i], bv[j], acc[i][j], 0, 0, 0);
    };

    loadT(0, s0);
    for (int t = 0; t < NT; t += 2) {
        __syncthreads();
        loadT(t + 1, s1);
        writeT(t, s0);
        __syncthreads();
        compute();
        __syncthreads();
        if (t + 2 < NT) loadT(t + 2, s0);
        writeT(t + 1, s1);
        __syncthreads();
        compute();
    }

    float* Cf = (float*)Cout;
    short* Cb = (short*)Cout;
    float lsum[4] = {0.f, 0.f, 0.f, 0.f}, lsq[4] = {0.f, 0.f, 0.f, 0.f};
    #pragma unroll
    for (int i = 0; i < RG * 2; ++i) {
        #pragma unroll
        for (int q = 0; q < 4; ++q) {
            int row = row0 + wm * (RG * 32) + i * 16 + (lane >> 4) * 4 + q;
            if (row < M) {
                #pragma unroll
                for (int j = 0; j < 4; ++j) {
                    int col = col0 + wn * 64 + j * 16 + (lane & 15);
                    float val = acc[i][j][q];
                    if (HASBIAS) val += bias[col];
                    if (LEAKY)   val = val > 0.f ? val : 0.2f * val;
                    if (ADDSRC)  val += bf2f(srcb[(size_t)row * Nc + col]);
                    if (STATS) { lsum[j] += val; lsq[j] += val * val; }
                    if (OUTBF16) Cb[(size_t)row * Nc + col] = f2bf(val);
                    else         Cf[(size_t)row * Nc + col] = val;
                }
            }
        }
    }
    if (STATS) {
        __syncthreads();
        float* sred = (float*)As;
        sred[tid] = 0.f;
        __syncthreads();
        int ch = wn * 64 + (lane & 15);
        #pragma unroll
        for (int j = 0; j < 4; ++j) {
            atomicAdd(&sred[ch + j * 16], lsum[j]);
            atomicAdd(&sred[128 + ch + j * 16], lsq[j]);
        }
        __syncthreads();
        spart[(size_t)blockIdx.x * 256 + tid] = sred[tid];
    }
}

// ---------------------------------------------------------------- fold per-block partials into accum[256]
__global__ void reduce_stats(const float* __restrict__ part, int nblk, float* __restrict__ accum) {
    int t = threadIdx.x;
    float s = 0.f;
    for (int b = blockIdx.x; b < nblk; b += gridDim.x)
        s += part[(size_t)b * 256 + t];
    atomicAdd(&accum[t], s);
}

// ---------------------------------------------------------------- BN finalize+apply (f32 in/out, optional bf16 shadow)
template<bool SHADOW>
__global__ void bn_apply_f(float* __restrict__ a, short* __restrict__ shadow, long long total4,
                           const float* __restrict__ accum, const float* __restrict__ g,
                           const float* __restrict__ b, float invM) {
    __shared__ float scs[256];
    int t = threadIdx.x;
    if (t < 128) {
        float mean = accum[t] * invM;
        float var = accum[128 + t] * invM - mean * mean;
        float s = g[t] * rsqrtf(var + 1e-5f);
        scs[t] = s;
        scs[128 + t] = b[t] - mean * s;
    }
    __syncthreads();
    long long idx = (long long)blockIdx.x * 256 + t;
    long long stride = (long long)gridDim.x * 256;
    float4* a4 = (float4*)a;
    short4* s4p = (short4*)shadow;
    for (; idx < total4; idx += stride) {
        int c = (int)((idx & 31) * 4);
        float4 v = a4[idx];
        v.x = v.x * scs[c + 0] + scs[128 + c + 0];
        v.y = v.y * scs[c + 1] + scs[128 + c + 1];
        v.z = v.z * scs[c + 2] + scs[128 + c + 2];
        v.w = v.w * scs[c + 3] + scs[128 + c + 3];
        a4[idx] = v;
        if (SHADOW)
            s4p[idx] = make_short4(f2bf(v.x), f2bf(v.y), f2bf(v.z), f2bf(v.w));
    }
}

// ---------------------------------------------------------------- BN apply bf16 -> f32
__global__ void bn_apply_b2f(const short* __restrict__ inb, float* __restrict__ outp,
                             long long total4, const float* __restrict__ accum,
                             const float* __restrict__ g, const float* __restrict__ b, float invM) {
    __shared__ float scs[256];
    int t = threadIdx.x;
    if (t < 128) {
        float mean = accum[t] * invM;
        float var = accum[128 + t] * invM - mean * mean;
        float s = g[t] * rsqrtf(var + 1e-5f);
        scs[t] = s;
        scs[128 + t] = b[t] - mean * s;
    }
    __syncthreads();
    long long idx = (long long)blockIdx.x * 256 + t;
    long long stride = (long long)gridDim.x * 256;
    const short4* in4 = (const short4*)inb;
    float4* o4 = (float4*)outp;
    for (; idx < total4; idx += stride) {
        int c = (int)((idx & 31) * 4);
        short4 sv = in4[idx];
        float4 v;
        v.x = bf2f(sv.x) * scs[c + 0] + scs[128 + c + 0];
        v.y = bf2f(sv.y) * scs[c + 1] + scs[128 + c + 1];
        v.z = bf2f(sv.z) * scs[c + 2] + scs[128 + c + 2];
        v.w = bf2f(sv.w) * scs[c + 3] + scs[128 + c + 3];
        o4[idx] = v;
    }
}

// ---------------------------------------------------------------- he_attr: 256 thr, 2-way member split
__global__ void edge_feat(const int* __restrict__ elist, const int* __restrict__ eoff,
                          const int* __restrict__ nidx, const float* __restrict__ h,
                          float* __restrict__ he) {
    __shared__ float red[128];
    int e = blockIdx.x;
    int off = eoff[e], cnt = eoff[e + 1] - off;
    int d = threadIdx.x & 127, half = threadIdx.x >> 7;
    float acc = 0.f;
    for (int p = half; p < cnt; p += 2) {
        int k = elist[off + p];
        int n = nidx[k];
        acc += h[(size_t)n * 128 + d];
    }
    if (half == 1) red[d] = acc;
    __syncthreads();
    if (half == 0) he[(size_t)e * 128 + d] = acc + red[d];
}

// ---------------------------------------------------------------- w_att precompute
template<int H>
__global__ void watt_kernel(const float* __restrict__ lin, const float* __restrict__ att,
                            float* __restrict__ wx, float* __restrict__ we) {
    int t = threadIdx.x;            // H*128 threads
    int hh = t >> 7, d = t & 127;
    float sx = 0.f, se = 0.f;
    for (int j = 0; j < 128; ++j) {
        float l = lin[(size_t)d * (H * 128) + hh * 128 + j];
        sx += l * att[hh * 256 + j];
        se += l * att[hh * 256 + 128 + j];
    }
    wx[t] = sx;
    we[t] = se;
}

// ---------------------------------------------------------------- dots: out[row,h] = h_row . w[h]
template<int H>
__global__ void dots128(const float* __restrict__ feat, const float* __restrict__ w,
                        float* __restrict__ out, int M) {
    int wv = threadIdx.x >> 6;
    int lane = threadIdx.x & 63;
    int row = blockIdx.x * 4 + wv;
    if (row >= M) return;
    const float* fr = feat + (size_t)row * 128;
    float f0 = fr[lane], f1 = fr[lane + 64];
    #pragma unroll
    for (int h = 0; h < H; ++h) {
        float v = f0 * w[h * 128 + lane] + f1 * w[h * 128 + lane + 64];
        #pragma unroll
        for (int s = 32; s > 0; s >>= 1) v += __shfl_xor(v, s);
        if (lane == 0) out[(size_t)row * H + h] = v;
    }
}

// ---------------------------------------------------------------- per-edge segment softmax
template<int H>
__global__ void edge_softmax(const int* __restrict__ elist, const int* __restrict__ eoff,
                             const int* __restrict__ nidx, const float* __restrict__ ax,
                             const float* __restrict__ ae, float* __restrict__ alpha) {
    constexpr int SLOTS = 256 / H;
    __shared__ float red[256];
    int e = blockIdx.x;
    int off = eoff[e], cnt = eoff[e + 1] - off;
    int t = threadIdx.x;
    int h = t % H, slot = t / H;
    float aeh = ae[(size_t)e * H + h];
    float lmax = -1e30f;
    for (int p = slot; p < cnt; p += SLOTS) {
        int k = elist[off + p];
        int n = nidx[k];
        float v = ax[(size_t)n * H + h] + aeh;
        v = v > 0.f ? v : 0.2f * v;
        alpha[(size_t)k * H + h] = v;
        lmax = fmaxf(lmax, v);
    }
    red[t] = lmax;
    __syncthreads();
    for (int s = SLOTS / 2; s > 0; s >>= 1) {
        if (slot < s) red[slot * H + h] = fmaxf(red[slot * H + h], red[(slot + s) * H + h]);
        __syncthreads();
    }
    float m = red[h];
    __syncthreads();
    float lsum = 0.f;
    for (int p = slot; p < cnt; p += SLOTS) {
        int k = elist[off + p];
        float ex = expf(alpha[(size_t)k * H + h] - m);
        alpha[(size_t)k * H + h] = ex;
        lsum += ex;
    }
    red[t] = lsum;
    __syncthreads();
    for (int s = SLOTS / 2; s > 0; s >>= 1) {
        if (slot < s) red[slot * H + h] += red[(slot + s) * H + h];
        __syncthreads();
    }
    float inv = 1.0f / (red[h] + 1e-16f);
    for (int p = slot; p < cnt; p += SLOTS) {
        int k = elist[off + p];
        alpha[(size_t)k * H + h] *= inv;
    }
}

// ---------------------------------------------------------------- agg_e (128-space)
template<int H>
__global__ void edge_agg128(const int* __restrict__ elist, const int* __restrict__ eoff,
                            const int* __restrict__ nidx, const float* __restrict__ alpha,
                            const float* __restrict__ h, float* __restrict__ agg) {
    int e = blockIdx.x;
    int off = eoff[e], cnt = eoff[e + 1] - off;
    int t = threadIdx.x;            // H*128 threads
    int hh = t >> 7, d = t & 127;
    float acc = 0.f;
    for (int p = 0; p < cnt; ++p) {
        int k = elist[off + p];
        int n = nidx[k];
        acc += alpha[(size_t)k * H + hh] * h[(size_t)n * 128 + d];
    }
    float binv = cnt > 0 ? 1.0f / (float)cnt : 0.0f;
    agg[(size_t)e * (H * 128) + t] = acc * binv;
}

// ---------------------------------------------------------------- oute[e,h,j] = sum_d agg[e,h,d] * lin[d, h*128+j]
template<int H>
__global__ void oute_lin(const float* __restrict__ agg, const float* __restrict__ lin,
                         float* __restrict__ oute) {
    __shared__ float ar[H * 128];
    int e = blockIdx.x;
    int t = threadIdx.x;            // H*128 threads
    ar[t] = agg[(size_t)e * (H * 128) + t];
    __syncthreads();
    int hh = t >> 7;
    float acc = 0.f;
    #pragma unroll 4
    for (int d = 0; d < 128; ++d)
        acc += ar[hh * 128 + d] * lin[(size_t)d * (H * 128) + t];
    oute[(size_t)e * (H * 128) + t] = acc;
}

// ---------------------------------------------------------------- node side v2:
// 1875 blocks x 256 thr; 2 nodes/block x 8 grid-stride sweeps (1875*2*8 = 30000).
// Member lists LDS-staged (parallel index resolution), head-loop in registers,
// BN stats partials fused -> spart.
template<int H>
__global__ __launch_bounds__(256)
void node_aggregate2(const int* __restrict__ nlist, const int* __restrict__ noff,
                     const int* __restrict__ eidx, const float* __restrict__ alpha,
                     const float* __restrict__ oute, const float* __restrict__ bias,
                     float* __restrict__ hout, float* __restrict__ spart) {
    constexpr int MAXM = 32;
    __shared__ int   eLDS[2][MAXM];
    __shared__ float aLDS[2][MAXM][H];
    __shared__ float red[256];
    __shared__ int cshare[2];
    const int tid = threadIdx.x;
    const int sub = tid >> 7, d = tid & 127;
    const float bd = bias[d];
    float sts = 0.f, stq = 0.f;
    for (int sweep = 0; sweep < 8; ++sweep) {
        int n = sweep * 3750 + blockIdx.x * 2 + sub;
        int off = noff[n], cnt = noff[n + 1] - off;
        if (d == 0) cshare[sub] = cnt;
        __syncthreads();
        int cmax = max(cshare[0], cshare[1]);
        float acc[H];
        #pragma unroll
        for (int hh = 0; hh < H; ++hh) acc[hh] = 0.f;
        for (int base = 0; base < cmax; base += MAXM) {
            int chunkN = cnt - base;
            if (chunkN > MAXM) chunkN = MAXM;
            if (d < chunkN) {
                int k = nlist[off + base + d];
                eLDS[sub][d] = eidx[k];
                if (H == 4) {
                    float4 a4 = *(const float4*)(alpha + (size_t)k * 4);
                    aLDS[sub][d][0] = a4.x; aLDS[sub][d][1] = a4.y;
                    aLDS[sub][d][2] = a4.z; aLDS[sub][d][3] = a4.w;
                } else {
                    aLDS[sub][d][0] = alpha[k];
                }
            }
            __syncthreads();
            for (int j = 0; j < chunkN; ++j) {
                int e = eLDS[sub][j];
                #pragma unroll
                for (int hh = 0; hh < H; ++hh)
                    acc[hh] += aLDS[sub][j][hh] * oute[(size_t)e * (H * 128) + hh * 128 + d];
            }
            __syncthreads();
        }
        float s = 0.f;
        #pragma unroll
        for (int hh = 0; hh < H; ++hh) s += acc[hh];
        float dinv = cnt > 0 ? 1.0f / (float)cnt : 0.f;
        float nv = hout[(size_t)n * 128 + d] + s * (1.0f / H) * dinv + bd;
        hout[(size_t)n * 128 + d] = nv;
        sts += nv; stq += nv * nv;
        __syncthreads();   // protect cshare/eLDS for next sweep
    }
    red[tid] = sts;
    __syncthreads();
    float tsum = (sub == 0) ? red[d] + red[128 + d] : 0.f;
    __syncthreads();
    red[tid] = stq;
    __syncthreads();
    if (sub == 0) {
        spart[(size_t)blockIdx.x * 256 + d] = tsum;
        spart[(size_t)blockIdx.x * 256 + 128 + d] = red[d] + red[128 + d];
    }
}

// ---------------------------------------------------------------- launch
extern "C" void kernel_launch(void* const* d_in, const int* in_sizes, int n_in,
                              void* d_out, int out_size, void* d_ws, size_t ws_size,
                              hipStream_t stream) {
    (void)in_sizes; (void)n_in; (void)out_size; (void)ws_size;
    const float* x        = (const float*)d_in[0];
    const int*   node_idx = (const int*)d_in[1];
    const int*   edge_idx = (const int*)d_in[2];
    const float* W1    = (const float*)d_in[4];
    const float* b1    = (const float*)d_in[5];
    const float* bn1_g = (const float*)d_in[6];
    const float* bn1_b = (const float*)d_in[7];
    const float* h1_lin  = (const float*)d_in[8];
    const float* h1_att  = (const float*)d_in[9];
    const float* h1_bias = (const float*)d_in[10];
    const float* bn2_g = (const float*)d_in[11];
    const float* bn2_b = (const float*)d_in[12];
    const float* h2_lin  = (const float*)d_in[13];
    const float* h2_att  = (const float*)d_in[14];
    const float* h2_bias = (const float*)d_in[15];
    const float* bn3_g = (const float*)d_in[16];
    const float* bn3_b = (const float*)d_in[17];
    const float* W2    = (const float*)d_in[18];
    const float* b2    = (const float*)d_in[19];
    const float* bn4_g = (const float*)d_in[20];
    const float* bn4_b = (const float*)d_in[21];
    float* out = (float*)d_out;

    char* ws = (char*)d_ws;
    size_t off = 0;
    auto alloc = [&](size_t bytes) -> void* {
        void* p = ws + off;
        off = (off + bytes + 255) & ~(size_t)255;
        return p;
    };
    float* h     = (float*)alloc((size_t)NN * 128 * 4);
    float* scratch = (float*)alloc((size_t)NN * 512 * 4);   // pre-BN4 bf16 home
    float* he    = (float*)alloc((size_t)EE * 128 * 4);
    float* agg   = (float*)alloc((size_t)EE * 512 * 4);
    float* oute  = (float*)alloc((size_t)EE * 512 * 4);
    float* ax    = (float*)alloc((size_t)NN * 4 * 4);
    float* ae    = (float*)alloc((size_t)EE * 4 * 4);
    float* alpha = (float*)alloc((size_t)NNZC * 4 * 4);
    float* accum = (float*)alloc(256 * 4);
    float* spart = (float*)alloc((size_t)1880 * 256 * 4);
    float* wax   = (float*)alloc(512 * 4);
    float* wae   = (float*)alloc(512 * 4);
    short* hb    = (short*)alloc((size_t)NN * 128 * 2);    // bf16 shadow of h (BN3)
    short* W1T   = (short*)alloc((size_t)128 * DIN * 2);
    short* W2T   = (short*)alloc((size_t)DIN * 128 * 2);
    int* ecnt  = (int*)alloc(EE * 4);
    int* eoff  = (int*)alloc((EE + 1) * 4);
    int* ecur  = (int*)alloc(EE * 4);
    int* elist = (int*)alloc(NNZC * 4);
    int* ncnt  = (int*)alloc(NN * 4);
    int* noff  = (int*)alloc((NN + 1) * 4);
    int* ncur  = (int*)alloc(NN * 4);
    int* nlist = (int*)alloc(NNZC * 4);

    short* xb   = (short*)d_out;       // bf16 copy of x in dead space of d_out
    short* outb = (short*)scratch;     // pre-BN4 bf16 scratch

    hipMemsetAsync(ecnt, 0, EE * 4, stream);
    hipMemsetAsync(ncnt, 0, NN * 4, stream);
    hipMemsetAsync(ecur, 0, EE * 4, stream);
    hipMemsetAsync(ncur, 0, NN * 4, stream);

    count_kernel<<<(NNZC + 255) / 256, 256, 0, stream>>>(edge_idx, node_idx, ecnt, ncnt);
    transpose_to_bf16<<<dim3(4, 32), 256, 0, stream>>>(W1, W1T, DIN, 128);
    transpose_to_bf16<<<dim3(32, 4), 256, 0, stream>>>(W2, W2T, 128, DIN);
    scan_two<<<2, 1024, 0, stream>>>(ecnt, eoff, ncnt, noff);
    fill_lists<<<(NNZC + 255) / 256, 256, 0, stream>>>(edge_idx, node_idx, eoff, noff,
                                                       ecur, ncur, elist, nlist);

    const int MB64  = (NN + 63) / 64;     // 469
    const int MB128 = (NN + 127) / 128;   // 235

    // h = leaky(x @ W1 + b1)   [MFMA, BM=64, f32-A cvt-on-stage + xb dump, BN1 partial stats]
    hipMemsetAsync(accum, 0, 256 * 4, stream);
    gemm_mfma<1, true, true, true, true, false, true, false, false>
        <<<MB64, 256, 0, stream>>>(x, W1T, b1, nullptr, h, spart, xb, NN, DIN, 128, 1);
    reduce_stats<<<32, 256, 0, stream>>>(spart, MB64, accum);
    bn_apply_f<false><<<1024, 256, 0, stream>>>(h, nullptr, (long long)NN * 128 / 4, accum,
                                                bn1_g, bn1_b, 1.0f / NN);

    // ---- hconv1 (heads=4), linearity-refactored ----
    edge_feat<<<EE, 256, 0, stream>>>(elist, eoff, node_idx, h, he);
    watt_kernel<4><<<1, 512, 0, stream>>>(h1_lin, h1_att, wax, wae);
    dots128<4><<<(NN + 3) / 4, 256, 0, stream>>>(h, wax, ax, NN);
    dots128<4><<<(EE + 3) / 4, 256, 0, stream>>>(he, wae, ae, EE);
    edge_softmax<4><<<EE, 256, 0, stream>>>(elist, eoff, node_idx, ax, ae, alpha);
    edge_agg128<4><<<EE, 512, 0, stream>>>(elist, eoff, node_idx, alpha, h, agg);
    oute_lin<4><<<EE, 512, 0, stream>>>(agg, h1_lin, oute);
    node_aggregate2<4><<<1875, 256, 0, stream>>>(nlist, noff, edge_idx, alpha, oute, h1_bias,
                                                 h, spart);

    // BN2 (stats fused in node_aggregate2)
    hipMemsetAsync(accum, 0, 256 * 4, stream);
    reduce_stats<<<32, 256, 0, stream>>>(spart, 1875, accum);
    bn_apply_f<false><<<1024, 256, 0, stream>>>(h, nullptr, (long long)NN * 128 / 4, accum,
                                                bn2_g, bn2_b, 1.0f / NN);

    // ---- hconv2 (heads=1), linearity-refactored ----
    edge_feat<<<EE, 256, 0, stream>>>(elist, eoff, node_idx, h, he);
    watt_kernel<1><<<1, 128, 0, stream>>>(h2_lin, h2_att, wax, wae);
    dots128<1><<<(NN + 3) / 4, 256, 0, stream>>>(h, wax, ax, NN);
    dots128<1><<<(EE + 3) / 4, 256, 0, stream>>>(he, wae, ae, EE);
    edge_softmax<1><<<EE, 256, 0, stream>>>(elist, eoff, node_idx, ax, ae, alpha);
    edge_agg128<1><<<EE, 128, 0, stream>>>(elist, eoff, node_idx, alpha, h, agg);
    oute_lin<1><<<EE, 128, 0, stream>>>(agg, h2_lin, oute);
    node_aggregate2<1><<<1875, 256, 0, stream>>>(nlist, noff, edge_idx, alpha, oute, h2_bias,
                                                 h, spart);

    // BN3 (stats fused; shadow feeds W2)
    hipMemsetAsync(accum, 0, 256 * 4, stream);
    reduce_stats<<<32, 256, 0, stream>>>(spart, 1875, accum);
    bn_apply_f<true><<<1024, 256, 0, stream>>>(h, hb, (long long)NN * 128 / 4, accum,
                                               bn3_g, bn3_b, 1.0f / NN);

    // out_pre = xb + leaky(hb @ W2 + b2) -> bf16 scratch
    // [MFMA + BN4 partial stats + XCD-bijective swizzle: grid 1880]
    hipMemsetAsync(accum, 0, 256 * 4, stream);
    gemm_mfma<2, false, false, true, true, true, true, true, true>
        <<<8 * MB128, 256, 0, stream>>>(hb, W2T, b2, xb, outb, spart, nullptr, NN, 128, DIN, 8);
    reduce_stats<<<32, 256, 0, stream>>>(spart, 8 * MB128, accum);

    // BN4: bf16 -> f32 out (overwrites all of d_out incl. xb scratch)
    bn_apply_b2f<<<2048, 256, 0, stream>>>(outb, out, (long long)NN * DIN / 4, accum,
                                           bn4_g, bn4_b, 1.0f / (NN * PP));
}

// Round 16
// 583.051 us; speedup vs baseline: 1.4954x; 1.2470x over previous
//
#include <hip/hip_runtime.h>
#include <math.h>

#define NN 30000
#define PP 8
#define DM 128
#define EE 1000
#define NNZC 120000
#define DIN (PP*DM)   // 1024

typedef __attribute__((ext_vector_type(8))) short bf16x8;
typedef __attribute__((ext_vector_type(4))) float f32x4;

__device__ __forceinline__ short f2bf(float f) {
    union { float f; unsigned u; } v; v.f = f;
    unsigned r = v.u + 0x7fffu + ((v.u >> 16) & 1u);
    return (short)(r >> 16);
}
__device__ __forceinline__ float bf2f(short s) {
    union { unsigned u; float f; } v;
    v.u = ((unsigned)(unsigned short)s) << 16;
    return v.f;
}

// ---------------------------------------------------------------- CSR build
__global__ void count_kernel(const int* __restrict__ ei, const int* __restrict__ ni,
                             int* __restrict__ ecnt, int* __restrict__ ncnt) {
    int k = blockIdx.x * 256 + threadIdx.x;
    if (k >= NNZC) return;
    atomicAdd(&ecnt[ei[k]], 1);
    atomicAdd(&ncnt[ni[k]], 1);
}

__global__ __launch_bounds__(1024)
void scan_two(const int* __restrict__ ecnt, int* __restrict__ eoff,
              const int* __restrict__ ncnt, int* __restrict__ noff) {
    const int* cnt; int* off; int len;
    if (blockIdx.x == 0) { cnt = ecnt; off = eoff; len = EE; }
    else                 { cnt = ncnt; off = noff; len = NN; }
    __shared__ int wsum[16];
    __shared__ int carrysh;
    int t = threadIdx.x;
    int lane = t & 63, w = t >> 6;
    if (t == 0) carrysh = 0;
    __syncthreads();
    for (int base = 0; base < len; base += 1024) {
        int v = (base + t < len) ? cnt[base + t] : 0;
        int s = v;
        #pragma unroll
        for (int d = 1; d < 64; d <<= 1) {
            int u = __shfl_up(s, d);
            if (lane >= d) s += u;
        }
        if (lane == 63) wsum[w] = s;
        __syncthreads();
        if (t < 16) {
            int ws = wsum[t];
            #pragma unroll
            for (int d = 1; d < 16; d <<= 1) {
                int u = __shfl_up(ws, d);
                if (t >= d) ws += u;
            }
            wsum[t] = ws;
        }
        __syncthreads();
        int c = carrysh;
        int woff = (w > 0) ? wsum[w - 1] : 0;
        if (base + t < len) off[base + t] = c + woff + s - v;
        int total = wsum[15];
        __syncthreads();
        if (t == 0) carrysh = c + total;
    }
    __syncthreads();
    if (t == 0) off[len] = carrysh;
}

__global__ void fill_lists(const int* __restrict__ ei, const int* __restrict__ ni,
                           const int* __restrict__ eoff, const int* __restrict__ noff,
                           int* __restrict__ ecur, int* __restrict__ ncur,
                           int* __restrict__ elist, int* __restrict__ nlist) {
    int k = blockIdx.x * 256 + threadIdx.x;
    if (k >= NNZC) return;
    int e = ei[k];
    int p = atomicAdd(&ecur[e], 1);
    elist[eoff[e] + p] = k;
    int n = ni[k];
    int q = atomicAdd(&ncur[n], 1);
    nlist[noff[n] + q] = k;
}

// ---------------------------------------------------------------- weight transpose+convert
__global__ void transpose_to_bf16(const float* __restrict__ B, short* __restrict__ BT,
                                  int K, int N) {
    __shared__ float tile[32][33];
    int bn = blockIdx.x * 32, bk = blockIdx.y * 32;
    int tx = threadIdx.x & 31, ty = threadIdx.x >> 5;
    #pragma unroll
    for (int yy = ty; yy < 32; yy += 8) {
        int k = bk + yy, n = bn + tx;
        tile[yy][tx] = (k < K && n < N) ? B[(size_t)k * N + n] : 0.f;
    }
    __syncthreads();
    #pragma unroll
    for (int yy = ty; yy < 32; yy += 8) {
        int n = bn + yy, k = bk + tx;
        if (n < N && k < K) BT[(size_t)n * K + k] = f2bf(tile[tx][yy]);
    }
}

// ---------------------------------------------------------------- GEMM1 split-K:
// hp[khalf][n][c] = x[n, kbase:kbase+512] @ W1[kbase:kbase+512, c]; xb dumped on stage.
// grid = 938 (469 panels x 2 khalves), BM=64, BK=32, 4 waves.
__global__ __launch_bounds__(256)
void gemm1_splitk(const float* __restrict__ x, const short* __restrict__ W1T,
                  float* __restrict__ hp, short* __restrict__ xb) {
    __shared__ short As[64 * 40];
    __shared__ short Bs[128 * 40];
    const int tid = threadIdx.x;
    const int lane = tid & 63, wid = tid >> 6;
    const int wm = wid >> 1, wn = wid & 1;
    const int panel = blockIdx.x >> 1, khalf = blockIdx.x & 1;
    const int row0 = panel * 64;
    const int kbase = khalf * 512;
    const int srow = tid >> 2, skq = tid & 3;

    f32x4 acc[2][4] = {};
    struct Stage { float4 fa[2]; bf16x8 b[2]; };
    Stage s0, s1;

    auto loadT = [&](int t, Stage& s) {
        int k0 = kbase + (t << 5);
        int gr = row0 + srow;
        float4 z = make_float4(0.f, 0.f, 0.f, 0.f);
        s.fa[0] = z; s.fa[1] = z;
        if (gr < NN) {
            const float4* p = (const float4*)(x + (size_t)gr * DIN + k0 + skq * 8);
            s.fa[0] = p[0]; s.fa[1] = p[1];
        }
        #pragma unroll
        for (int c = 0; c < 2; ++c)
            s.b[c] = *(const bf16x8*)(W1T + (size_t)(srow + 64 * c) * DIN + k0 + skq * 8);
    };
    auto writeT = [&](int t, Stage& s) {
        int k0 = kbase + (t << 5);
        bf16x8 t8;
        t8[0] = f2bf(s.fa[0].x); t8[1] = f2bf(s.fa[0].y);
        t8[2] = f2bf(s.fa[0].z); t8[3] = f2bf(s.fa[0].w);
        t8[4] = f2bf(s.fa[1].x); t8[5] = f2bf(s.fa[1].y);
        t8[6] = f2bf(s.fa[1].z); t8[7] = f2bf(s.fa[1].w);
        int gr = row0 + srow;
        if (gr < NN)
            *(bf16x8*)(xb + (size_t)gr * DIN + k0 + skq * 8) = t8;
        *(bf16x8*)&As[srow * 40 + skq * 8] = t8;
        #pragma unroll
        for (int c = 0; c < 2; ++c)
            *(bf16x8*)&Bs[(srow + 64 * c) * 40 + skq * 8] = s.b[c];
    };
    auto compute = [&]() {
        bf16x8 av[2], bv[4];
        #pragma unroll
        for (int i = 0; i < 2; ++i)
            av[i] = *(const bf16x8*)&As[(wm * 32 + i * 16 + (lane & 15)) * 40 + (lane >> 4) * 8];
        #pragma unroll
        for (int j = 0; j < 4; ++j)
            bv[j] = *(const bf16x8*)&Bs[(wn * 64 + j * 16 + (lane & 15)) * 40 + (lane >> 4) * 8];
        #pragma unroll
        for (int i = 0; i < 2; ++i)
            #pragma unroll
            for (int j = 0; j < 4; ++j)
                acc[i][j] = __builtin_amdgcn_mfma_f32_16x16x32_bf16(av[i], bv[j], acc[i][j], 0, 0, 0);
    };

    loadT(0, s0);
    for (int t = 0; t < 16; t += 2) {
        __syncthreads();
        loadT(t + 1, s1);
        writeT(t, s0);
        __syncthreads();
        compute();
        __syncthreads();
        if (t + 2 < 16) loadT(t + 2, s0);
        writeT(t + 1, s1);
        __syncthreads();
        compute();
    }

    float* o = hp + (size_t)khalf * NN * 128;
    #pragma unroll
    for (int i = 0; i < 2; ++i) {
        #pragma unroll
        for (int q = 0; q < 4; ++q) {
            int row = row0 + wm * 32 + i * 16 + (lane >> 4) * 4 + q;
            if (row < NN) {
                #pragma unroll
                for (int j = 0; j < 4; ++j) {
                    int col = wn * 64 + j * 16 + (lane & 15);
                    o[(size_t)row * 128 + col] = acc[i][j][q];
                }
            }
        }
    }
}

// ---------------------------------------------------------------- combine: h = leaky(hp0+hp1+b1), BN1 stats partials
__global__ void combine_bn1(const float* __restrict__ hp, const float* __restrict__ b1,
                            float* __restrict__ h, float* __restrict__ spart) {
    int t = threadIdx.x;
    const float4* p0 = (const float4*)hp;
    const float4* p1 = (const float4*)(hp + (size_t)NN * 128);
    float4* o = (float4*)h;
    int c = (t & 31) * 4;
    float4 bb = *(const float4*)(b1 + c);
    long long idx = (long long)blockIdx.x * 256 + t;
    long long stride = (long long)gridDim.x * 256;
    float s1[4] = {0.f,0.f,0.f,0.f}, s2[4] = {0.f,0.f,0.f,0.f};
    for (; idx < (long long)NN * 32; idx += stride) {
        float4 a = p0[idx], b = p1[idx];
        float v0 = a.x + b.x + bb.x; v0 = v0 > 0.f ? v0 : 0.2f * v0;
        float v1 = a.y + b.y + bb.y; v1 = v1 > 0.f ? v1 : 0.2f * v1;
        float v2 = a.z + b.z + bb.z; v2 = v2 > 0.f ? v2 : 0.2f * v2;
        float v3 = a.w + b.w + bb.w; v3 = v3 > 0.f ? v3 : 0.2f * v3;
        o[idx] = make_float4(v0, v1, v2, v3);
        s1[0] += v0; s2[0] += v0 * v0;
        s1[1] += v1; s2[1] += v1 * v1;
        s1[2] += v2; s2[2] += v2 * v2;
        s1[3] += v3; s2[3] += v3 * v3;
    }
    __shared__ float r1[256][4], r2[256][4];
    #pragma unroll
    for (int k = 0; k < 4; ++k) { r1[t][k] = s1[k]; r2[t][k] = s2[k]; }
    __syncthreads();
    if (t < 32) {
        #pragma unroll
        for (int k = 0; k < 4; ++k) {
            float a1 = 0.f, a2 = 0.f;
            #pragma unroll
            for (int u = 0; u < 8; ++u) { a1 += r1[t + u * 32][k]; a2 += r2[t + u * 32][k]; }
            spart[(size_t)blockIdx.x * 256 + t * 4 + k] = a1;
            spart[(size_t)blockIdx.x * 256 + 128 + t * 4 + k] = a2;
        }
    }
}

// ---------------------------------------------------------------- bf16 MFMA GEMM (W2 only)
template<int RG, bool HASBIAS, bool LEAKY, bool ADDSRC, bool STATS, bool OUTBF16, bool SWZ>
__global__ __launch_bounds__(256)
void gemm_mfma(const short* __restrict__ Ain, const short* __restrict__ BT,
               const float* __restrict__ bias, const short* __restrict__ srcb,
               void* __restrict__ Cout, float* __restrict__ spart,
               int M, int K, int Nc, int colB) {
    constexpr int BM = 64 * RG;
    __shared__ short As[BM * 40];
    __shared__ short Bs[128 * 40];
    const int tid = threadIdx.x;
    const int lane = tid & 63, wid = tid >> 6;
    const int wm = wid >> 1, wn = wid & 1;

    int row0, col0;
    {
        int w = blockIdx.x;
        int l;
        if (SWZ) { int cpx = gridDim.x >> 3; l = (w & 7) * cpx + (w >> 3); }
        else     { l = w; }
        row0 = (l / colB) * BM;
        col0 = (l % colB) * 128;
    }
    const int srow = tid >> 2, skq = tid & 3;

    f32x4 acc[RG * 2][4] = {};
    const int NT = K >> 5;

    struct Stage { bf16x8 a[RG]; bf16x8 b[2]; };
    Stage s0, s1;

    auto loadT = [&](int t, Stage& s) {
        int k0 = t << 5;
        #pragma unroll
        for (int c = 0; c < RG; ++c) {
            int gr = row0 + srow + 64 * c;
            s.a[c] = bf16x8{0, 0, 0, 0, 0, 0, 0, 0};
            if (gr < M)
                s.a[c] = *(const bf16x8*)(Ain + (size_t)gr * K + k0 + skq * 8);
        }
        #pragma unroll
        for (int c = 0; c < 2; ++c) {
            int gc = col0 + srow + 64 * c;
            s.b[c] = *(const bf16x8*)(BT + (size_t)gc * K + k0 + skq * 8);
        }
    };
    auto writeT = [&](Stage& s) {
        #pragma unroll
        for (int c = 0; c < RG; ++c)
            *(bf16x8*)&As[(srow + 64 * c) * 40 + skq * 8] = s.a[c];
        #pragma unroll
        for (int c = 0; c < 2; ++c)
            *(bf16x8*)&Bs[(srow + 64 * c) * 40 + skq * 8] = s.b[c];
    };
    auto compute = [&]() {
        bf16x8 av[RG * 2], bv[4];
        #pragma unroll
        for (int i = 0; i < RG * 2; ++i)
            av[i] = *(const bf16x8*)&As[(wm * (RG * 32) + i * 16 + (lane & 15)) * 40 + (lane >> 4) * 8];
        #pragma unroll
        for (int j = 0; j < 4; ++j)
            bv[j] = *(const bf16x8*)&Bs[(wn * 64 + j * 16 + (lane & 15)) * 40 + (lane >> 4) * 8];
        #pragma unroll
        for (int i = 0; i < RG * 2; ++i)
            #pragma unroll
            for (int j = 0; j < 4; ++j)
                acc[i][j] = __builtin_amdgcn_mfma_f32_16x16x32_bf16(av[i], bv[j], acc[i][j], 0, 0, 0);
    };

    loadT(0, s0);
    for (int t = 0; t < NT; t += 2) {
        __syncthreads();
        loadT(t + 1, s1);
        writeT(s0);
        __syncthreads();
        compute();
        __syncthreads();
        if (t + 2 < NT) loadT(t + 2, s0);
        writeT(s1);
        __syncthreads();
        compute();
    }

    float* Cf = (float*)Cout;
    short* Cb = (short*)Cout;
    float lsum[4] = {0.f, 0.f, 0.f, 0.f}, lsq[4] = {0.f, 0.f, 0.f, 0.f};
    #pragma unroll
    for (int i = 0; i < RG * 2; ++i) {
        #pragma unroll
        for (int q = 0; q < 4; ++q) {
            int row = row0 + wm * (RG * 32) + i * 16 + (lane >> 4) * 4 + q;
            if (row < M) {
                #pragma unroll
                for (int j = 0; j < 4; ++j) {
                    int col = col0 + wn * 64 + j * 16 + (lane & 15);
                    float val = acc[i][j][q];
                    if (HASBIAS) val += bias[col];
                    if (LEAKY)   val = val > 0.f ? val : 0.2f * val;
                    if (ADDSRC)  val += bf2f(srcb[(size_t)row * Nc + col]);
                    if (STATS) { lsum[j] += val; lsq[j] += val * val; }
                    if (OUTBF16) Cb[(size_t)row * Nc + col] = f2bf(val);
                    else         Cf[(size_t)row * Nc + col] = val;
                }
            }
        }
    }
    if (STATS) {
        __syncthreads();
        float* sred = (float*)As;
        sred[tid] = 0.f;
        __syncthreads();
        int ch = wn * 64 + (lane & 15);
        #pragma unroll
        for (int j = 0; j < 4; ++j) {
            atomicAdd(&sred[ch + j * 16], lsum[j]);
            atomicAdd(&sred[128 + ch + j * 16], lsq[j]);
        }
        __syncthreads();
        spart[(size_t)blockIdx.x * 256 + tid] = sred[tid];
    }
}

// ---------------------------------------------------------------- fold per-block partials into accum[256]
__global__ void reduce_stats(const float* __restrict__ part, int nblk, float* __restrict__ accum) {
    int t = threadIdx.x;
    float s = 0.f;
    for (int b = blockIdx.x; b < nblk; b += gridDim.x)
        s += part[(size_t)b * 256 + t];
    atomicAdd(&accum[t], s);
}

// ---------------------------------------------------------------- BN finalize+apply (f32 in/out, optional bf16 shadow)
template<bool SHADOW>
__global__ void bn_apply_f(float* __restrict__ a, short* __restrict__ shadow, long long total4,
                           const float* __restrict__ accum, const float* __restrict__ g,
                           const float* __restrict__ b, float invM) {
    __shared__ float scs[256];
    int t = threadIdx.x;
    if (t < 128) {
        float mean = accum[t] * invM;
        float var = accum[128 + t] * invM - mean * mean;
        float s = g[t] * rsqrtf(var + 1e-5f);
        scs[t] = s;
        scs[128 + t] = b[t] - mean * s;
    }
    __syncthreads();
    long long idx = (long long)blockIdx.x * 256 + t;
    long long stride = (long long)gridDim.x * 256;
    float4* a4 = (float4*)a;
    short4* s4p = (short4*)shadow;
    for (; idx < total4; idx += stride) {
        int c = (int)((idx & 31) * 4);
        float4 v = a4[idx];
        v.x = v.x * scs[c + 0] + scs[128 + c + 0];
        v.y = v.y * scs[c + 1] + scs[128 + c + 1];
        v.z = v.z * scs[c + 2] + scs[128 + c + 2];
        v.w = v.w * scs[c + 3] + scs[128 + c + 3];
        a4[idx] = v;
        if (SHADOW)
            s4p[idx] = make_short4(f2bf(v.x), f2bf(v.y), f2bf(v.z), f2bf(v.w));
    }
}

// ---------------------------------------------------------------- BN apply bf16 -> f32
__global__ void bn_apply_b2f(const short* __restrict__ inb, float* __restrict__ outp,
                             long long total4, const float* __restrict__ accum,
                             const float* __restrict__ g, const float* __restrict__ b, float invM) {
    __shared__ float scs[256];
    int t = threadIdx.x;
    if (t < 128) {
        float mean = accum[t] * invM;
        float var = accum[128 + t] * invM - mean * mean;
        float s = g[t] * rsqrtf(var + 1e-5f);
        scs[t] = s;
        scs[128 + t] = b[t] - mean * s;
    }
    __syncthreads();
    long long idx = (long long)blockIdx.x * 256 + t;
    long long stride = (long long)gridDim.x * 256;
    const short4* in4 = (const short4*)inb;
    float4* o4 = (float4*)outp;
    for (; idx < total4; idx += stride) {
        int c = (int)((idx & 31) * 4);
        short4 sv = in4[idx];
        float4 v;
        v.x = bf2f(sv.x) * scs[c + 0] + scs[128 + c + 0];
        v.y = bf2f(sv.y) * scs[c + 1] + scs[128 + c + 1];
        v.z = bf2f(sv.z) * scs[c + 2] + scs[128 + c + 2];
        v.w = bf2f(sv.w) * scs[c + 3] + scs[128 + c + 3];
        o4[idx] = v;
    }
}

// ---------------------------------------------------------------- he_attr: LDS-staged member indices
__global__ void edge_feat(const int* __restrict__ elist, const int* __restrict__ eoff,
                          const int* __restrict__ nidx, const float* __restrict__ h,
                          float* __restrict__ he) {
    __shared__ int nIdx[128];
    int e = blockIdx.x;
    int off = eoff[e], cnt = eoff[e + 1] - off;
    int d = threadIdx.x;  // 128
    float acc = 0.f;
    for (int base = 0; base < cnt; base += 128) {
        int c = cnt - base; if (c > 128) c = 128;
        if (d < c) nIdx[d] = nidx[elist[off + base + d]];
        __syncthreads();
        #pragma unroll 4
        for (int j = 0; j < c; ++j)
            acc += h[(size_t)nIdx[j] * 128 + d];
        __syncthreads();
    }
    he[(size_t)e * 128 + d] = acc;
}

// ---------------------------------------------------------------- w_att precompute
template<int H>
__global__ void watt_kernel(const float* __restrict__ lin, const float* __restrict__ att,
                            float* __restrict__ wx, float* __restrict__ we) {
    int t = threadIdx.x;            // H*128 threads
    int hh = t >> 7, d = t & 127;
    float sx = 0.f, se = 0.f;
    for (int j = 0; j < 128; ++j) {
        float l = lin[(size_t)d * (H * 128) + hh * 128 + j];
        sx += l * att[hh * 256 + j];
        se += l * att[hh * 256 + 128 + j];
    }
    wx[t] = sx;
    we[t] = se;
}

// ---------------------------------------------------------------- dots: out[row,h] = h_row . w[h]
template<int H>
__global__ void dots128(const float* __restrict__ feat, const float* __restrict__ w,
                        float* __restrict__ out, int M) {
    int wv = threadIdx.x >> 6;
    int lane = threadIdx.x & 63;
    int row = blockIdx.x * 4 + wv;
    if (row >= M) return;
    const float* fr = feat + (size_t)row * 128;
    float f0 = fr[lane], f1 = fr[lane + 64];
    #pragma unroll
    for (int h = 0; h < H; ++h) {
        float v = f0 * w[h * 128 + lane] + f1 * w[h * 128 + lane + 64];
        #pragma unroll
        for (int s = 32; s > 0; s >>= 1) v += __shfl_xor(v, s);
        if (lane == 0) out[(size_t)row * H + h] = v;
    }
}

// ---------------------------------------------------------------- per-edge segment softmax
template<int H>
__global__ void edge_softmax(const int* __restrict__ elist, const int* __restrict__ eoff,
                             const int* __restrict__ nidx, const float* __restrict__ ax,
                             const float* __restrict__ ae, float* __restrict__ alpha) {
    constexpr int SLOTS = 256 / H;
    __shared__ float red[256];
    int e = blockIdx.x;
    int off = eoff[e], cnt = eoff[e + 1] - off;
    int t = threadIdx.x;
    int h = t % H, slot = t / H;
    float aeh = ae[(size_t)e * H + h];
    float lmax = -1e30f;
    for (int p = slot; p < cnt; p += SLOTS) {
        int k = elist[off + p];
        int n = nidx[k];
        float v = ax[(size_t)n * H + h] + aeh;
        v = v > 0.f ? v : 0.2f * v;
        alpha[(size_t)k * H + h] = v;
        lmax = fmaxf(lmax, v);
    }
    red[t] = lmax;
    __syncthreads();
    for (int s = SLOTS / 2; s > 0; s >>= 1) {
        if (slot < s) red[slot * H + h] = fmaxf(red[slot * H + h], red[(slot + s) * H + h]);
        __syncthreads();
    }
    float m = red[h];
    __syncthreads();
    float lsum = 0.f;
    for (int p = slot; p < cnt; p += SLOTS) {
        int k = elist[off + p];
        float ex = expf(alpha[(size_t)k * H + h] - m);
        alpha[(size_t)k * H + h] = ex;
        lsum += ex;
    }
    red[t] = lsum;
    __syncthreads();
    for (int s = SLOTS / 2; s > 0; s >>= 1) {
        if (slot < s) red[slot * H + h] += red[(slot + s) * H + h];
        __syncthreads();
    }
    float inv = 1.0f / (red[h] + 1e-16f);
    for (int p = slot; p < cnt; p += SLOTS) {
        int k = elist[off + p];
        alpha[(size_t)k * H + h] *= inv;
    }
}

// ---------------------------------------------------------------- agg_e (128-space), LDS-staged
template<int H>
__global__ void edge_agg128(const int* __restrict__ elist, const int* __restrict__ eoff,
                            const int* __restrict__ nidx, const float* __restrict__ alpha,
                            const float* __restrict__ h, float* __restrict__ agg) {
    __shared__ int nIdx[128];
    __shared__ float aBuf[128 * H];
    int e = blockIdx.x;
    int off = eoff[e], cnt = eoff[e + 1] - off;
    int t = threadIdx.x;            // H*128 threads
    int hh = t >> 7, d = t & 127;
    float acc = 0.f;
    for (int base = 0; base < cnt; base += 128) {
        int c = cnt - base; if (c > 128) c = 128;
        if (t < c) {
            int k = elist[off + base + t];
            nIdx[t] = nidx[k];
            if (H == 4) {
                float4 a4 = *(const float4*)(alpha + (size_t)k * 4);
                aBuf[t * 4 + 0] = a4.x; aBuf[t * 4 + 1] = a4.y;
                aBuf[t * 4 + 2] = a4.z; aBuf[t * 4 + 3] = a4.w;
            } else {
                aBuf[t] = alpha[k];
            }
        }
        __syncthreads();
        #pragma unroll 4
        for (int j = 0; j < c; ++j)
            acc += aBuf[j * H + hh] * h[(size_t)nIdx[j] * 128 + d];
        __syncthreads();
    }
    float binv = cnt > 0 ? 1.0f / (float)cnt : 0.0f;
    agg[(size_t)e * (H * 128) + t] = acc * binv;
}

// ---------------------------------------------------------------- oute[e,h,j] = sum_d agg[e,h,d] * lin[d, h*128+j]
template<int H>
__global__ void oute_lin(const float* __restrict__ agg, const float* __restrict__ lin,
                         float* __restrict__ oute) {
    __shared__ float ar[H * 128];
    int e = blockIdx.x;
    int t = threadIdx.x;            // H*128 threads
    ar[t] = agg[(size_t)e * (H * 128) + t];
    __syncthreads();
    int hh = t >> 7;
    float acc = 0.f;
    #pragma unroll 4
    for (int d = 0; d < 128; ++d)
        acc += ar[hh * 128 + d] * lin[(size_t)d * (H * 128) + t];
    oute[(size_t)e * (H * 128) + t] = acc;
}

// ---------------------------------------------------------------- node side (R15 structure)
template<int H>
__global__ __launch_bounds__(256)
void node_aggregate2(const int* __restrict__ nlist, const int* __restrict__ noff,
                     const int* __restrict__ eidx, const float* __restrict__ alpha,
                     const float* __restrict__ oute, const float* __restrict__ bias,
                     float* __restrict__ hout, float* __restrict__ spart) {
    constexpr int MAXM = 32;
    __shared__ int   eLDS[2][MAXM];
    __shared__ float aLDS[2][MAXM][H];
    __shared__ float red[256];
    __shared__ int cshare[2];
    const int tid = threadIdx.x;
    const int sub = tid >> 7, d = tid & 127;
    const float bd = bias[d];
    float sts = 0.f, stq = 0.f;
    for (int sweep = 0; sweep < 8; ++sweep) {
        int n = sweep * 3750 + blockIdx.x * 2 + sub;
        int off = noff[n], cnt = noff[n + 1] - off;
        if (d == 0) cshare[sub] = cnt;
        __syncthreads();
        int cmax = max(cshare[0], cshare[1]);
        float acc[H];
        #pragma unroll
        for (int hh = 0; hh < H; ++hh) acc[hh] = 0.f;
        for (int base = 0; base < cmax; base += MAXM) {
            int chunkN = cnt - base;
            if (chunkN > MAXM) chunkN = MAXM;
            if (d < chunkN) {
                int k = nlist[off + base + d];
                eLDS[sub][d] = eidx[k];
                if (H == 4) {
                    float4 a4 = *(const float4*)(alpha + (size_t)k * 4);
                    aLDS[sub][d][0] = a4.x; aLDS[sub][d][1] = a4.y;
                    aLDS[sub][d][2] = a4.z; aLDS[sub][d][3] = a4.w;
                } else {
                    aLDS[sub][d][0] = alpha[k];
                }
            }
            __syncthreads();
            for (int j = 0; j < chunkN; ++j) {
                int e = eLDS[sub][j];
                #pragma unroll
                for (int hh = 0; hh < H; ++hh)
                    acc[hh] += aLDS[sub][j][hh] * oute[(size_t)e * (H * 128) + hh * 128 + d];
            }
            __syncthreads();
        }
        float s = 0.f;
        #pragma unroll
        for (int hh = 0; hh < H; ++hh) s += acc[hh];
        float dinv = cnt > 0 ? 1.0f / (float)cnt : 0.f;
        float nv = hout[(size_t)n * 128 + d] + s * (1.0f / H) * dinv + bd;
        hout[(size_t)n * 128 + d] = nv;
        sts += nv; stq += nv * nv;
        __syncthreads();
    }
    red[tid] = sts;
    __syncthreads();
    float tsum = (sub == 0) ? red[d] + red[128 + d] : 0.f;
    __syncthreads();
    red[tid] = stq;
    __syncthreads();
    if (sub == 0) {
        spart[(size_t)blockIdx.x * 256 + d] = tsum;
        spart[(size_t)blockIdx.x * 256 + 128 + d] = red[d] + red[128 + d];
    }
}

// ---------------------------------------------------------------- launch
extern "C" void kernel_launch(void* const* d_in, const int* in_sizes, int n_in,
                              void* d_out, int out_size, void* d_ws, size_t ws_size,
                              hipStream_t stream) {
    (void)in_sizes; (void)n_in; (void)out_size; (void)ws_size;
    const float* x        = (const float*)d_in[0];
    const int*   node_idx = (const int*)d_in[1];
    const int*   edge_idx = (const int*)d_in[2];
    const float* W1    = (const float*)d_in[4];
    const float* b1    = (const float*)d_in[5];
    const float* bn1_g = (const float*)d_in[6];
    const float* bn1_b = (const float*)d_in[7];
    const float* h1_lin  = (const float*)d_in[8];
    const float* h1_att  = (const float*)d_in[9];
    const float* h1_bias = (const float*)d_in[10];
    const float* bn2_g = (const float*)d_in[11];
    const float* bn2_b = (const float*)d_in[12];
    const float* h2_lin  = (const float*)d_in[13];
    const float* h2_att  = (const float*)d_in[14];
    const float* h2_bias = (const float*)d_in[15];
    const float* bn3_g = (const float*)d_in[16];
    const float* bn3_b = (const float*)d_in[17];
    const float* W2    = (const float*)d_in[18];
    const float* b2    = (const float*)d_in[19];
    const float* bn4_g = (const float*)d_in[20];
    const float* bn4_b = (const float*)d_in[21];
    float* out = (float*)d_out;

    char* ws = (char*)d_ws;
    size_t off = 0;
    auto alloc = [&](size_t bytes) -> void* {
        void* p = ws + off;
        off = (off + bytes + 255) & ~(size_t)255;
        return p;
    };
    float* h     = (float*)alloc((size_t)NN * 128 * 4);
    float* scratch = (float*)alloc((size_t)NN * 512 * 4);   // hp[2] early, outb late
    float* he    = (float*)alloc((size_t)EE * 128 * 4);
    float* agg   = (float*)alloc((size_t)EE * 512 * 4);
    float* oute  = (float*)alloc((size_t)EE * 512 * 4);
    float* ax    = (float*)alloc((size_t)NN * 4 * 4);
    float* ae    = (float*)alloc((size_t)EE * 4 * 4);
    float* alpha = (float*)alloc((size_t)NNZC * 4 * 4);
    float* accum = (float*)alloc(256 * 4);
    float* spart = (float*)alloc((size_t)1880 * 256 * 4);
    float* wax   = (float*)alloc(512 * 4);
    float* wae   = (float*)alloc(512 * 4);
    short* hb    = (short*)alloc((size_t)NN * 128 * 2);    // bf16 shadow of h (BN3)
    short* W1T   = (short*)alloc((size_t)128 * DIN * 2);
    short* W2T   = (short*)alloc((size_t)DIN * 128 * 2);
    int* ecnt  = (int*)alloc(EE * 4);
    int* eoff  = (int*)alloc((EE + 1) * 4);
    int* ecur  = (int*)alloc(EE * 4);
    int* elist = (int*)alloc(NNZC * 4);
    int* ncnt  = (int*)alloc(NN * 4);
    int* noff  = (int*)alloc((NN + 1) * 4);
    int* ncur  = (int*)alloc(NN * 4);
    int* nlist = (int*)alloc(NNZC * 4);

    short* xb   = (short*)d_out;       // bf16 copy of x in dead space of d_out
    float* hp   = scratch;             // split-K partials [2][NN][128]
    short* outb = (short*)scratch;     // pre-BN4 bf16 scratch (hp dead by then)

    hipMemsetAsync(ecnt, 0, EE * 4, stream);
    hipMemsetAsync(ncnt, 0, NN * 4, stream);
    hipMemsetAsync(ecur, 0, EE * 4, stream);
    hipMemsetAsync(ncur, 0, NN * 4, stream);

    count_kernel<<<(NNZC + 255) / 256, 256, 0, stream>>>(edge_idx, node_idx, ecnt, ncnt);
    transpose_to_bf16<<<dim3(4, 32), 256, 0, stream>>>(W1, W1T, DIN, 128);
    transpose_to_bf16<<<dim3(32, 4), 256, 0, stream>>>(W2, W2T, 128, DIN);
    scan_two<<<2, 1024, 0, stream>>>(ecnt, eoff, ncnt, noff);
    fill_lists<<<(NNZC + 255) / 256, 256, 0, stream>>>(edge_idx, node_idx, eoff, noff,
                                                       ecur, ncur, elist, nlist);

    const int MB64  = (NN + 63) / 64;     // 469
    const int MB128 = (NN + 127) / 128;   // 235

    // GEMM1 split-K=2 (xb dump fused) + combine (bias/leaky + BN1 stats)
    gemm1_splitk<<<2 * MB64, 256, 0, stream>>>(x, W1T, hp, xb);
    hipMemsetAsync(accum, 0, 256 * 4, stream);
    combine_bn1<<<1024, 256, 0, stream>>>(hp, b1, h, spart);
    reduce_stats<<<32, 256, 0, stream>>>(spart, 1024, accum);
    bn_apply_f<false><<<1024, 256, 0, stream>>>(h, nullptr, (long long)NN * 128 / 4, accum,
                                                bn1_g, bn1_b, 1.0f / NN);

    // ---- hconv1 (heads=4), linearity-refactored ----
    edge_feat<<<EE, 128, 0, stream>>>(elist, eoff, node_idx, h, he);
    watt_kernel<4><<<1, 512, 0, stream>>>(h1_lin, h1_att, wax, wae);
    dots128<4><<<(NN + 3) / 4, 256, 0, stream>>>(h, wax, ax, NN);
    dots128<4><<<(EE + 3) / 4, 256, 0, stream>>>(he, wae, ae, EE);
    edge_softmax<4><<<EE, 256, 0, stream>>>(elist, eoff, node_idx, ax, ae, alpha);
    edge_agg128<4><<<EE, 512, 0, stream>>>(elist, eoff, node_idx, alpha, h, agg);
    oute_lin<4><<<EE, 512, 0, stream>>>(agg, h1_lin, oute);
    node_aggregate2<4><<<1875, 256, 0, stream>>>(nlist, noff, edge_idx, alpha, oute, h1_bias,
                                                 h, spart);

    // BN2 (stats fused in node_aggregate2)
    hipMemsetAsync(accum, 0, 256 * 4, stream);
    reduce_stats<<<32, 256, 0, stream>>>(spart, 1875, accum);
    bn_apply_f<false><<<1024, 256, 0, stream>>>(h, nullptr, (long long)NN * 128 / 4, accum,
                                                bn2_g, bn2_b, 1.0f / NN);

    // ---- hconv2 (heads=1), linearity-refactored ----
    edge_feat<<<EE, 128, 0, stream>>>(elist, eoff, node_idx, h, he);
    watt_kernel<1><<<1, 128, 0, stream>>>(h2_lin, h2_att, wax, wae);
    dots128<1><<<(NN + 3) / 4, 256, 0, stream>>>(h, wax, ax, NN);
    dots128<1><<<(EE + 3) / 4, 256, 0, stream>>>(he, wae, ae, EE);
    edge_softmax<1><<<EE, 256, 0, stream>>>(elist, eoff, node_idx, ax, ae, alpha);
    edge_agg128<1><<<EE, 128, 0, stream>>>(elist, eoff, node_idx, alpha, h, agg);
    oute_lin<1><<<EE, 128, 0, stream>>>(agg, h2_lin, oute);
    node_aggregate2<1><<<1875, 256, 0, stream>>>(nlist, noff, edge_idx, alpha, oute, h2_bias,
                                                 h, spart);

    // BN3 (stats fused; shadow feeds W2)
    hipMemsetAsync(accum, 0, 256 * 4, stream);
    reduce_stats<<<32, 256, 0, stream>>>(spart, 1875, accum);
    bn_apply_f<true><<<1024, 256, 0, stream>>>(h, hb, (long long)NN * 128 / 4, accum,
                                               bn3_g, bn3_b, 1.0f / NN);

    // out_pre = xb + leaky(hb @ W2 + b2) -> bf16 scratch
    // [MFMA + BN4 partial stats + XCD-bijective swizzle: grid 1880]
    hipMemsetAsync(accum, 0, 256 * 4, stream);
    gemm_mfma<2, true, true, true, true, true, true>
        <<<8 * MB128, 256, 0, stream>>>(hb, W2T, b2, xb, outb, spart, NN, 128, DIN, 8);
    reduce_stats<<<32, 256, 0, stream>>>(spart, 8 * MB128, accum);

    // BN4: bf16 -> f32 out (overwrites all of d_out incl. xb scratch)
    bn_apply_b2f<<<2048, 256, 0, stream>>>(outb, out, (long long)NN * DIN / 4, accum,
                                           bn4_g, bn4_b, 1.0f / (NN * PP));
}

// Round 17
// 540.027 us; speedup vs baseline: 1.6146x; 1.0797x over previous
//
#include <hip/hip_runtime.h>
#include <math.h>

#define NN 30000
#define PP 8
#define DM 128
#define EE 1000
#define NNZC 120000
#define DIN (PP*DM)   // 1024

typedef __attribute__((ext_vector_type(8))) short bf16x8;
typedef __attribute__((ext_vector_type(4))) float f32x4;

__device__ __forceinline__ short f2bf(float f) {
    union { float f; unsigned u; } v; v.f = f;
    unsigned r = v.u + 0x7fffu + ((v.u >> 16) & 1u);
    return (short)(r >> 16);
}
__device__ __forceinline__ float bf2f(short s) {
    union { unsigned u; float f; } v;
    v.u = ((unsigned)(unsigned short)s) << 16;
    return v.f;
}

// ---------------------------------------------------------------- CSR build
__global__ void count_kernel(const int* __restrict__ ei, const int* __restrict__ ni,
                             int* __restrict__ ecnt, int* __restrict__ ncnt) {
    int k = blockIdx.x * 256 + threadIdx.x;
    if (k >= NNZC) return;
    atomicAdd(&ecnt[ei[k]], 1);
    atomicAdd(&ncnt[ni[k]], 1);
}

__global__ __launch_bounds__(1024)
void scan_two(const int* __restrict__ ecnt, int* __restrict__ eoff,
              const int* __restrict__ ncnt, int* __restrict__ noff) {
    const int* cnt; int* off; int len;
    if (blockIdx.x == 0) { cnt = ecnt; off = eoff; len = EE; }
    else                 { cnt = ncnt; off = noff; len = NN; }
    __shared__ int wsum[16];
    __shared__ int carrysh;
    int t = threadIdx.x;
    int lane = t & 63, w = t >> 6;
    if (t == 0) carrysh = 0;
    __syncthreads();
    for (int base = 0; base < len; base += 1024) {
        int v = (base + t < len) ? cnt[base + t] : 0;
        int s = v;
        #pragma unroll
        for (int d = 1; d < 64; d <<= 1) {
            int u = __shfl_up(s, d);
            if (lane >= d) s += u;
        }
        if (lane == 63) wsum[w] = s;
        __syncthreads();
        if (t < 16) {
            int ws = wsum[t];
            #pragma unroll
            for (int d = 1; d < 16; d <<= 1) {
                int u = __shfl_up(ws, d);
                if (t >= d) ws += u;
            }
            wsum[t] = ws;
        }
        __syncthreads();
        int c = carrysh;
        int woff = (w > 0) ? wsum[w - 1] : 0;
        if (base + t < len) off[base + t] = c + woff + s - v;
        int total = wsum[15];
        __syncthreads();
        if (t == 0) carrysh = c + total;
    }
    __syncthreads();
    if (t == 0) off[len] = carrysh;
}

__global__ void fill_lists(const int* __restrict__ ei, const int* __restrict__ ni,
                           const int* __restrict__ eoff, const int* __restrict__ noff,
                           int* __restrict__ ecur, int* __restrict__ ncur,
                           int* __restrict__ elist, int* __restrict__ nlist) {
    int k = blockIdx.x * 256 + threadIdx.x;
    if (k >= NNZC) return;
    int e = ei[k];
    int p = atomicAdd(&ecur[e], 1);
    elist[eoff[e] + p] = k;
    int n = ni[k];
    int q = atomicAdd(&ncur[n], 1);
    nlist[noff[n] + q] = k;
}

// ---------------------------------------------------------------- weight transpose+convert
__global__ void transpose_to_bf16(const float* __restrict__ B, short* __restrict__ BT,
                                  int K, int N) {
    __shared__ float tile[32][33];
    int bn = blockIdx.x * 32, bk = blockIdx.y * 32;
    int tx = threadIdx.x & 31, ty = threadIdx.x >> 5;
    #pragma unroll
    for (int yy = ty; yy < 32; yy += 8) {
        int k = bk + yy, n = bn + tx;
        tile[yy][tx] = (k < K && n < N) ? B[(size_t)k * N + n] : 0.f;
    }
    __syncthreads();
    #pragma unroll
    for (int yy = ty; yy < 32; yy += 8) {
        int n = bn + yy, k = bk + tx;
        if (n < N && k < K) BT[(size_t)n * K + k] = f2bf(tile[tx][yy]);
    }
}

// ---------------------------------------------------------------- GEMM1 split-K=4:
// hp[kq][n][c] = x[n, kq*256:(kq+1)*256] @ W1[...]  (pure loads in pipeline; no dump)
// grid = 1876 (469 panels x 4 k-quarters), BM=64, BK=32, 4 waves.
__global__ __launch_bounds__(256)
void gemm1_splitk(const float* __restrict__ x, const short* __restrict__ W1T,
                  float* __restrict__ hp) {
    __shared__ short As[64 * 40];
    __shared__ short Bs[128 * 40];
    const int tid = threadIdx.x;
    const int lane = tid & 63, wid = tid >> 6;
    const int wm = wid >> 1, wn = wid & 1;
    const int panel = blockIdx.x >> 2, kq = blockIdx.x & 3;
    const int row0 = panel * 64;
    const int kbase = kq * 256;
    const int srow = tid >> 2, skq = tid & 3;

    f32x4 acc[2][4] = {};
    struct Stage { float4 fa[2]; bf16x8 b[2]; };
    Stage s0, s1;

    auto loadT = [&](int t, Stage& s) {
        int k0 = kbase + (t << 5);
        int gr = row0 + srow;
        float4 z = make_float4(0.f, 0.f, 0.f, 0.f);
        s.fa[0] = z; s.fa[1] = z;
        if (gr < NN) {
            const float4* p = (const float4*)(x + (size_t)gr * DIN + k0 + skq * 8);
            s.fa[0] = p[0]; s.fa[1] = p[1];
        }
        #pragma unroll
        for (int c = 0; c < 2; ++c)
            s.b[c] = *(const bf16x8*)(W1T + (size_t)(srow + 64 * c) * DIN + k0 + skq * 8);
    };
    auto writeT = [&](Stage& s) {
        bf16x8 t8;
        t8[0] = f2bf(s.fa[0].x); t8[1] = f2bf(s.fa[0].y);
        t8[2] = f2bf(s.fa[0].z); t8[3] = f2bf(s.fa[0].w);
        t8[4] = f2bf(s.fa[1].x); t8[5] = f2bf(s.fa[1].y);
        t8[6] = f2bf(s.fa[1].z); t8[7] = f2bf(s.fa[1].w);
        *(bf16x8*)&As[srow * 40 + skq * 8] = t8;
        #pragma unroll
        for (int c = 0; c < 2; ++c)
            *(bf16x8*)&Bs[(srow + 64 * c) * 40 + skq * 8] = s.b[c];
    };
    auto compute = [&]() {
        bf16x8 av[2], bv[4];
        #pragma unroll
        for (int i = 0; i < 2; ++i)
            av[i] = *(const bf16x8*)&As[(wm * 32 + i * 16 + (lane & 15)) * 40 + (lane >> 4) * 8];
        #pragma unroll
        for (int j = 0; j < 4; ++j)
            bv[j] = *(const bf16x8*)&Bs[(wn * 64 + j * 16 + (lane & 15)) * 40 + (lane >> 4) * 8];
        #pragma unroll
        for (int i = 0; i < 2; ++i)
            #pragma unroll
            for (int j = 0; j < 4; ++j)
                acc[i][j] = __builtin_amdgcn_mfma_f32_16x16x32_bf16(av[i], bv[j], acc[i][j], 0, 0, 0);
    };

    loadT(0, s0);
    for (int t = 0; t < 8; t += 2) {
        __syncthreads();
        loadT(t + 1, s1);
        writeT(s0);
        __syncthreads();
        compute();
        __syncthreads();
        if (t + 2 < 8) loadT(t + 2, s0);
        writeT(s1);
        __syncthreads();
        compute();
    }

    float* o = hp + (size_t)kq * NN * 128;
    #pragma unroll
    for (int i = 0; i < 2; ++i) {
        #pragma unroll
        for (int q = 0; q < 4; ++q) {
            int row = row0 + wm * 32 + i * 16 + (lane >> 4) * 4 + q;
            if (row < NN) {
                #pragma unroll
                for (int j = 0; j < 4; ++j) {
                    int col = wn * 64 + j * 16 + (lane & 15);
                    o[(size_t)row * 128 + col] = acc[i][j][q];
                }
            }
        }
    }
}

// ---------------------------------------------------------------- combine: h = leaky(hp0+hp1+hp2+hp3+b1), BN1 stats
__global__ void combine_bn1(const float* __restrict__ hp, const float* __restrict__ b1,
                            float* __restrict__ h, float* __restrict__ spart) {
    int t = threadIdx.x;
    const float4* p0 = (const float4*)hp;
    const float4* p1 = (const float4*)(hp + (size_t)NN * 128);
    const float4* p2 = (const float4*)(hp + (size_t)2 * NN * 128);
    const float4* p3 = (const float4*)(hp + (size_t)3 * NN * 128);
    float4* o = (float4*)h;
    int c = (t & 31) * 4;
    float4 bb = *(const float4*)(b1 + c);
    long long idx = (long long)blockIdx.x * 256 + t;
    long long stride = (long long)gridDim.x * 256;
    float s1[4] = {0.f,0.f,0.f,0.f}, s2[4] = {0.f,0.f,0.f,0.f};
    for (; idx < (long long)NN * 32; idx += stride) {
        float4 a = p0[idx], b = p1[idx], cc = p2[idx], dd = p3[idx];
        float v0 = a.x + b.x + cc.x + dd.x + bb.x; v0 = v0 > 0.f ? v0 : 0.2f * v0;
        float v1 = a.y + b.y + cc.y + dd.y + bb.y; v1 = v1 > 0.f ? v1 : 0.2f * v1;
        float v2 = a.z + b.z + cc.z + dd.z + bb.z; v2 = v2 > 0.f ? v2 : 0.2f * v2;
        float v3 = a.w + b.w + cc.w + dd.w + bb.w; v3 = v3 > 0.f ? v3 : 0.2f * v3;
        o[idx] = make_float4(v0, v1, v2, v3);
        s1[0] += v0; s2[0] += v0 * v0;
        s1[1] += v1; s2[1] += v1 * v1;
        s1[2] += v2; s2[2] += v2 * v2;
        s1[3] += v3; s2[3] += v3 * v3;
    }
    __shared__ float r1[256][4], r2[256][4];
    #pragma unroll
    for (int k = 0; k < 4; ++k) { r1[t][k] = s1[k]; r2[t][k] = s2[k]; }
    __syncthreads();
    if (t < 32) {
        #pragma unroll
        for (int k = 0; k < 4; ++k) {
            float a1 = 0.f, a2 = 0.f;
            #pragma unroll
            for (int u = 0; u < 8; ++u) { a1 += r1[t + u * 32][k]; a2 += r2[t + u * 32][k]; }
            spart[(size_t)blockIdx.x * 256 + t * 4 + k] = a1;
            spart[(size_t)blockIdx.x * 256 + 128 + t * 4 + k] = a2;
        }
    }
}

// ---------------------------------------------------------------- bf16 MFMA GEMM (W2; f32 src)
template<int RG, bool HASBIAS, bool LEAKY, bool ADDSRC, bool STATS, bool OUTBF16, bool SWZ>
__global__ __launch_bounds__(256)
void gemm_mfma(const short* __restrict__ Ain, const short* __restrict__ BT,
               const float* __restrict__ bias, const float* __restrict__ srcf,
               void* __restrict__ Cout, float* __restrict__ spart,
               int M, int K, int Nc, int colB) {
    constexpr int BM = 64 * RG;
    __shared__ short As[BM * 40];
    __shared__ short Bs[128 * 40];
    const int tid = threadIdx.x;
    const int lane = tid & 63, wid = tid >> 6;
    const int wm = wid >> 1, wn = wid & 1;

    int row0, col0;
    {
        int w = blockIdx.x;
        int l;
        if (SWZ) { int cpx = gridDim.x >> 3; l = (w & 7) * cpx + (w >> 3); }
        else     { l = w; }
        row0 = (l / colB) * BM;
        col0 = (l % colB) * 128;
    }
    const int srow = tid >> 2, skq = tid & 3;

    f32x4 acc[RG * 2][4] = {};
    const int NT = K >> 5;

    struct Stage { bf16x8 a[RG]; bf16x8 b[2]; };
    Stage s0, s1;

    auto loadT = [&](int t, Stage& s) {
        int k0 = t << 5;
        #pragma unroll
        for (int c = 0; c < RG; ++c) {
            int gr = row0 + srow + 64 * c;
            s.a[c] = bf16x8{0, 0, 0, 0, 0, 0, 0, 0};
            if (gr < M)
                s.a[c] = *(const bf16x8*)(Ain + (size_t)gr * K + k0 + skq * 8);
        }
        #pragma unroll
        for (int c = 0; c < 2; ++c) {
            int gc = col0 + srow + 64 * c;
            s.b[c] = *(const bf16x8*)(BT + (size_t)gc * K + k0 + skq * 8);
        }
    };
    auto writeT = [&](Stage& s) {
        #pragma unroll
        for (int c = 0; c < RG; ++c)
            *(bf16x8*)&As[(srow + 64 * c) * 40 + skq * 8] = s.a[c];
        #pragma unroll
        for (int c = 0; c < 2; ++c)
            *(bf16x8*)&Bs[(srow + 64 * c) * 40 + skq * 8] = s.b[c];
    };
    auto compute = [&]() {
        bf16x8 av[RG * 2], bv[4];
        #pragma unroll
        for (int i = 0; i < RG * 2; ++i)
            av[i] = *(const bf16x8*)&As[(wm * (RG * 32) + i * 16 + (lane & 15)) * 40 + (lane >> 4) * 8];
        #pragma unroll
        for (int j = 0; j < 4; ++j)
            bv[j] = *(const bf16x8*)&Bs[(wn * 64 + j * 16 + (lane & 15)) * 40 + (lane >> 4) * 8];
        #pragma unroll
        for (int i = 0; i < RG * 2; ++i)
            #pragma unroll
            for (int j = 0; j < 4; ++j)
                acc[i][j] = __builtin_amdgcn_mfma_f32_16x16x32_bf16(av[i], bv[j], acc[i][j], 0, 0, 0);
    };

    loadT(0, s0);
    for (int t = 0; t < NT; t += 2) {
        __syncthreads();
        loadT(t + 1, s1);
        writeT(s0);
        __syncthreads();
        compute();
        __syncthreads();
        if (t + 2 < NT) loadT(t + 2, s0);
        writeT(s1);
        __syncthreads();
        compute();
    }

    float* Cf = (float*)Cout;
    short* Cb = (short*)Cout;
    float lsum[4] = {0.f, 0.f, 0.f, 0.f}, lsq[4] = {0.f, 0.f, 0.f, 0.f};
    #pragma unroll
    for (int i = 0; i < RG * 2; ++i) {
        #pragma unroll
        for (int q = 0; q < 4; ++q) {
            int row = row0 + wm * (RG * 32) + i * 16 + (lane >> 4) * 4 + q;
            if (row < M) {
                #pragma unroll
                for (int j = 0; j < 4; ++j) {
                    int col = col0 + wn * 64 + j * 16 + (lane & 15);
                    float val = acc[i][j][q];
                    if (HASBIAS) val += bias[col];
                    if (LEAKY)   val = val > 0.f ? val : 0.2f * val;
                    if (ADDSRC)  val += srcf[(size_t)row * Nc + col];
                    if (STATS) { lsum[j] += val; lsq[j] += val * val; }
                    if (OUTBF16) Cb[(size_t)row * Nc + col] = f2bf(val);
                    else         Cf[(size_t)row * Nc + col] = val;
                }
            }
        }
    }
    if (STATS) {
        __syncthreads();
        float* sred = (float*)As;
        sred[tid] = 0.f;
        __syncthreads();
        int ch = wn * 64 + (lane & 15);
        #pragma unroll
        for (int j = 0; j < 4; ++j) {
            atomicAdd(&sred[ch + j * 16], lsum[j]);
            atomicAdd(&sred[128 + ch + j * 16], lsq[j]);
        }
        __syncthreads();
        spart[(size_t)blockIdx.x * 256 + tid] = sred[tid];
    }
}

// ---------------------------------------------------------------- fold per-block partials into accum[256]
__global__ void reduce_stats(const float* __restrict__ part, int nblk, float* __restrict__ accum) {
    int t = threadIdx.x;
    float s = 0.f;
    for (int b = blockIdx.x; b < nblk; b += gridDim.x)
        s += part[(size_t)b * 256 + t];
    atomicAdd(&accum[t], s);
}

// ---------------------------------------------------------------- BN finalize+apply (f32 in/out, optional bf16 shadow)
template<bool SHADOW>
__global__ void bn_apply_f(float* __restrict__ a, short* __restrict__ shadow, long long total4,
                           const float* __restrict__ accum, const float* __restrict__ g,
                           const float* __restrict__ b, float invM) {
    __shared__ float scs[256];
    int t = threadIdx.x;
    if (t < 128) {
        float mean = accum[t] * invM;
        float var = accum[128 + t] * invM - mean * mean;
        float s = g[t] * rsqrtf(var + 1e-5f);
        scs[t] = s;
        scs[128 + t] = b[t] - mean * s;
    }
    __syncthreads();
    long long idx = (long long)blockIdx.x * 256 + t;
    long long stride = (long long)gridDim.x * 256;
    float4* a4 = (float4*)a;
    short4* s4p = (short4*)shadow;
    for (; idx < total4; idx += stride) {
        int c = (int)((idx & 31) * 4);
        float4 v = a4[idx];
        v.x = v.x * scs[c + 0] + scs[128 + c + 0];
        v.y = v.y * scs[c + 1] + scs[128 + c + 1];
        v.z = v.z * scs[c + 2] + scs[128 + c + 2];
        v.w = v.w * scs[c + 3] + scs[128 + c + 3];
        a4[idx] = v;
        if (SHADOW)
            s4p[idx] = make_short4(f2bf(v.x), f2bf(v.y), f2bf(v.z), f2bf(v.w));
    }
}

// ---------------------------------------------------------------- BN apply bf16 -> f32
__global__ void bn_apply_b2f(const short* __restrict__ inb, float* __restrict__ outp,
                             long long total4, const float* __restrict__ accum,
                             const float* __restrict__ g, const float* __restrict__ b, float invM) {
    __shared__ float scs[256];
    int t = threadIdx.x;
    if (t < 128) {
        float mean = accum[t] * invM;
        float var = accum[128 + t] * invM - mean * mean;
        float s = g[t] * rsqrtf(var + 1e-5f);
        scs[t] = s;
        scs[128 + t] = b[t] - mean * s;
    }
    __syncthreads();
    long long idx = (long long)blockIdx.x * 256 + t;
    long long stride = (long long)gridDim.x * 256;
    const short4* in4 = (const short4*)inb;
    float4* o4 = (float4*)outp;
    for (; idx < total4; idx += stride) {
        int c = (int)((idx & 31) * 4);
        short4 sv = in4[idx];
        float4 v;
        v.x = bf2f(sv.x) * scs[c + 0] + scs[128 + c + 0];
        v.y = bf2f(sv.y) * scs[c + 1] + scs[128 + c + 1];
        v.z = bf2f(sv.z) * scs[c + 2] + scs[128 + c + 2];
        v.w = bf2f(sv.w) * scs[c + 3] + scs[128 + c + 3];
        o4[idx] = v;
    }
}

// ---------------------------------------------------------------- w_att precompute
template<int H>
__global__ void watt_kernel(const float* __restrict__ lin, const float* __restrict__ att,
                            float* __restrict__ wx, float* __restrict__ we) {
    int t = threadIdx.x;            // H*128 threads
    int hh = t >> 7, d = t & 127;
    float sx = 0.f, se = 0.f;
    for (int j = 0; j < 128; ++j) {
        float l = lin[(size_t)d * (H * 128) + hh * 128 + j];
        sx += l * att[hh * 256 + j];
        se += l * att[hh * 256 + 128 + j];
    }
    wx[t] = sx;
    we[t] = se;
}

// ---------------------------------------------------------------- dual dots: ax = h.wx, axe = h.we (one h read)
template<int H>
__global__ void dots128_2(const float* __restrict__ feat, const float* __restrict__ wx,
                          const float* __restrict__ we, float* __restrict__ oax,
                          float* __restrict__ oaxe, int M) {
    int wv = threadIdx.x >> 6;
    int lane = threadIdx.x & 63;
    int row = blockIdx.x * 4 + wv;
    if (row >= M) return;
    const float* fr = feat + (size_t)row * 128;
    float f0 = fr[lane], f1 = fr[lane + 64];
    #pragma unroll
    for (int h = 0; h < H; ++h) {
        float va = f0 * wx[h * 128 + lane] + f1 * wx[h * 128 + lane + 64];
        float vb = f0 * we[h * 128 + lane] + f1 * we[h * 128 + lane + 64];
        #pragma unroll
        for (int s = 32; s > 0; s >>= 1) { va += __shfl_xor(va, s); vb += __shfl_xor(vb, s); }
        if (lane == 0) {
            oax[(size_t)row * H + h] = va;
            oaxe[(size_t)row * H + h] = vb;
        }
    }
}

// ---------------------------------------------------------------- ae[e,h] = sum_{k in e} axe[n_k, h]
template<int H>
__global__ void edge_sum_ae(const int* __restrict__ elist, const int* __restrict__ eoff,
                            const int* __restrict__ nidx, const float* __restrict__ axe,
                            float* __restrict__ ae) {
    __shared__ float red[4 * 128];
    int e = blockIdx.x;
    int off = eoff[e], cnt = eoff[e + 1] - off;
    int t = threadIdx.x;  // 128
    float acc[H];
    #pragma unroll
    for (int hh = 0; hh < H; ++hh) acc[hh] = 0.f;
    for (int p = t; p < cnt; p += 128) {
        int n = nidx[elist[off + p]];
        #pragma unroll
        for (int hh = 0; hh < H; ++hh) acc[hh] += axe[(size_t)n * H + hh];
    }
    #pragma unroll
    for (int hh = 0; hh < H; ++hh) red[hh * 128 + t] = acc[hh];
    __syncthreads();
    for (int s = 64; s > 0; s >>= 1) {
        if (t < s) {
            #pragma unroll
            for (int hh = 0; hh < H; ++hh) red[hh * 128 + t] += red[hh * 128 + t + s];
        }
        __syncthreads();
    }
    if (t < H) ae[(size_t)e * H + t] = red[t * 128];
}

// ---------------------------------------------------------------- per-edge segment softmax
template<int H>
__global__ void edge_softmax(const int* __restrict__ elist, const int* __restrict__ eoff,
                             const int* __restrict__ nidx, const float* __restrict__ ax,
                             const float* __restrict__ ae, float* __restrict__ alpha) {
    constexpr int SLOTS = 256 / H;
    __shared__ float red[256];
    int e = blockIdx.x;
    int off = eoff[e], cnt = eoff[e + 1] - off;
    int t = threadIdx.x;
    int h = t % H, slot = t / H;
    float aeh = ae[(size_t)e * H + h];
    float lmax = -1e30f;
    for (int p = slot; p < cnt; p += SLOTS) {
        int k = elist[off + p];
        int n = nidx[k];
        float v = ax[(size_t)n * H + h] + aeh;
        v = v > 0.f ? v : 0.2f * v;
        alpha[(size_t)k * H + h] = v;
        lmax = fmaxf(lmax, v);
    }
    red[t] = lmax;
    __syncthreads();
    for (int s = SLOTS / 2; s > 0; s >>= 1) {
        if (slot < s) red[slot * H + h] = fmaxf(red[slot * H + h], red[(slot + s) * H + h]);
        __syncthreads();
    }
    float m = red[h];
    __syncthreads();
    float lsum = 0.f;
    for (int p = slot; p < cnt; p += SLOTS) {
        int k = elist[off + p];
        float ex = expf(alpha[(size_t)k * H + h] - m);
        alpha[(size_t)k * H + h] = ex;
        lsum += ex;
    }
    red[t] = lsum;
    __syncthreads();
    for (int s = SLOTS / 2; s > 0; s >>= 1) {
        if (slot < s) red[slot * H + h] += red[(slot + s) * H + h];
        __syncthreads();
    }
    float inv = 1.0f / (red[h] + 1e-16f);
    for (int p = slot; p < cnt; p += SLOTS) {
        int k = elist[off + p];
        alpha[(size_t)k * H + h] *= inv;
    }
}

// ---------------------------------------------------------------- agg_e (128-space), LDS-staged
template<int H>
__global__ void edge_agg128(const int* __restrict__ elist, const int* __restrict__ eoff,
                            const int* __restrict__ nidx, const float* __restrict__ alpha,
                            const float* __restrict__ h, float* __restrict__ agg) {
    __shared__ int nIdx[128];
    __shared__ float aBuf[128 * H];
    int e = blockIdx.x;
    int off = eoff[e], cnt = eoff[e + 1] - off;
    int t = threadIdx.x;            // H*128 threads
    int hh = t >> 7, d = t & 127;
    float acc = 0.f;
    for (int base = 0; base < cnt; base += 128) {
        int c = cnt - base; if (c > 128) c = 128;
        if (t < c) {
            int k = elist[off + base + t];
            nIdx[t] = nidx[k];
            if (H == 4) {
                float4 a4 = *(const float4*)(alpha + (size_t)k * 4);
                aBuf[t * 4 + 0] = a4.x; aBuf[t * 4 + 1] = a4.y;
                aBuf[t * 4 + 2] = a4.z; aBuf[t * 4 + 3] = a4.w;
            } else {
                aBuf[t] = alpha[k];
            }
        }
        __syncthreads();
        #pragma unroll 4
        for (int j = 0; j < c; ++j)
            acc += aBuf[j * H + hh] * h[(size_t)nIdx[j] * 128 + d];
        __syncthreads();
    }
    float binv = cnt > 0 ? 1.0f / (float)cnt : 0.0f;
    agg[(size_t)e * (H * 128) + t] = acc * binv;
}

// ---------------------------------------------------------------- oute[e,h,j] = sum_d agg[e,h,d] * lin[d, h*128+j]
template<int H>
__global__ void oute_lin(const float* __restrict__ agg, const float* __restrict__ lin,
                         float* __restrict__ oute) {
    __shared__ float ar[H * 128];
    int e = blockIdx.x;
    int t = threadIdx.x;            // H*128 threads
    ar[t] = agg[(size_t)e * (H * 128) + t];
    __syncthreads();
    int hh = t >> 7;
    float acc = 0.f;
    #pragma unroll 4
    for (int d = 0; d < 128; ++d)
        acc += ar[hh * 128 + d] * lin[(size_t)d * (H * 128) + t];
    oute[(size_t)e * (H * 128) + t] = acc;
}

// ---------------------------------------------------------------- node side (R15/R16 structure)
template<int H>
__global__ __launch_bounds__(256)
void node_aggregate2(const int* __restrict__ nlist, const int* __restrict__ noff,
                     const int* __restrict__ eidx, const float* __restrict__ alpha,
                     const float* __restrict__ oute, const float* __restrict__ bias,
                     float* __restrict__ hout, float* __restrict__ spart) {
    constexpr int MAXM = 32;
    __shared__ int   eLDS[2][MAXM];
    __shared__ float aLDS[2][MAXM][H];
    __shared__ float red[256];
    __shared__ int cshare[2];
    const int tid = threadIdx.x;
    const int sub = tid >> 7, d = tid & 127;
    const float bd = bias[d];
    float sts = 0.f, stq = 0.f;
    for (int sweep = 0; sweep < 8; ++sweep) {
        int n = sweep * 3750 + blockIdx.x * 2 + sub;
        int off = noff[n], cnt = noff[n + 1] - off;
        if (d == 0) cshare[sub] = cnt;
        __syncthreads();
        int cmax = max(cshare[0], cshare[1]);
        float acc[H];
        #pragma unroll
        for (int hh = 0; hh < H; ++hh) acc[hh] = 0.f;
        for (int base = 0; base < cmax; base += MAXM) {
            int chunkN = cnt - base;
            if (chunkN > MAXM) chunkN = MAXM;
            if (d < chunkN) {
                int k = nlist[off + base + d];
                eLDS[sub][d] = eidx[k];
                if (H == 4) {
                    float4 a4 = *(const float4*)(alpha + (size_t)k * 4);
                    aLDS[sub][d][0] = a4.x; aLDS[sub][d][1] = a4.y;
                    aLDS[sub][d][2] = a4.z; aLDS[sub][d][3] = a4.w;
                } else {
                    aLDS[sub][d][0] = alpha[k];
                }
            }
            __syncthreads();
            for (int j = 0; j < chunkN; ++j) {
                int e = eLDS[sub][j];
                #pragma unroll
                for (int hh = 0; hh < H; ++hh)
                    acc[hh] += aLDS[sub][j][hh] * oute[(size_t)e * (H * 128) + hh * 128 + d];
            }
            __syncthreads();
        }
        float s = 0.f;
        #pragma unroll
        for (int hh = 0; hh < H; ++hh) s += acc[hh];
        float dinv = cnt > 0 ? 1.0f / (float)cnt : 0.f;
        float nv = hout[(size_t)n * 128 + d] + s * (1.0f / H) * dinv + bd;
        hout[(size_t)n * 128 + d] = nv;
        sts += nv; stq += nv * nv;
        __syncthreads();
    }
    red[tid] = sts;
    __syncthreads();
    float tsum = (sub == 0) ? red[d] + red[128 + d] : 0.f;
    __syncthreads();
    red[tid] = stq;
    __syncthreads();
    if (sub == 0) {
        spart[(size_t)blockIdx.x * 256 + d] = tsum;
        spart[(size_t)blockIdx.x * 256 + 128 + d] = red[d] + red[128 + d];
    }
}

// ---------------------------------------------------------------- launch
extern "C" void kernel_launch(void* const* d_in, const int* in_sizes, int n_in,
                              void* d_out, int out_size, void* d_ws, size_t ws_size,
                              hipStream_t stream) {
    (void)in_sizes; (void)n_in; (void)out_size; (void)ws_size;
    const float* x        = (const float*)d_in[0];
    const int*   node_idx = (const int*)d_in[1];
    const int*   edge_idx = (const int*)d_in[2];
    const float* W1    = (const float*)d_in[4];
    const float* b1    = (const float*)d_in[5];
    const float* bn1_g = (const float*)d_in[6];
    const float* bn1_b = (const float*)d_in[7];
    const float* h1_lin  = (const float*)d_in[8];
    const float* h1_att  = (const float*)d_in[9];
    const float* h1_bias = (const float*)d_in[10];
    const float* bn2_g = (const float*)d_in[11];
    const float* bn2_b = (const float*)d_in[12];
    const float* h2_lin  = (const float*)d_in[13];
    const float* h2_att  = (const float*)d_in[14];
    const float* h2_bias = (const float*)d_in[15];
    const float* bn3_g = (const float*)d_in[16];
    const float* bn3_b = (const float*)d_in[17];
    const float* W2    = (const float*)d_in[18];
    const float* b2    = (const float*)d_in[19];
    const float* bn4_g = (const float*)d_in[20];
    const float* bn4_b = (const float*)d_in[21];
    float* out = (float*)d_out;

    char* ws = (char*)d_ws;
    size_t off = 0;
    auto alloc = [&](size_t bytes) -> void* {
        void* p = ws + off;
        off = (off + bytes + 255) & ~(size_t)255;
        return p;
    };
    float* h     = (float*)alloc((size_t)NN * 128 * 4);
    float* scratch = (float*)alloc((size_t)NN * 512 * 4);   // hp[4] early, outb late
    float* agg   = (float*)alloc((size_t)EE * 512 * 4);
    float* oute  = (float*)alloc((size_t)EE * 512 * 4);
    float* ax    = (float*)alloc((size_t)NN * 4 * 4);
    float* axe   = (float*)alloc((size_t)NN * 4 * 4);
    float* ae    = (float*)alloc((size_t)EE * 4 * 4);
    float* alpha = (float*)alloc((size_t)NNZC * 4 * 4);
    float* accum = (float*)alloc(256 * 4);
    float* spart = (float*)alloc((size_t)1880 * 256 * 4);
    float* wax   = (float*)alloc(512 * 4);
    float* wae   = (float*)alloc(512 * 4);
    short* hb    = (short*)alloc((size_t)NN * 128 * 2);    // bf16 shadow of h (BN3)
    short* W1T   = (short*)alloc((size_t)128 * DIN * 2);
    short* W2T   = (short*)alloc((size_t)DIN * 128 * 2);
    int* ecnt  = (int*)alloc(EE * 4);
    int* eoff  = (int*)alloc((EE + 1) * 4);
    int* ecur  = (int*)alloc(EE * 4);
    int* elist = (int*)alloc(NNZC * 4);
    int* ncnt  = (int*)alloc(NN * 4);
    int* noff  = (int*)alloc((NN + 1) * 4);
    int* ncur  = (int*)alloc(NN * 4);
    int* nlist = (int*)alloc(NNZC * 4);

    float* hp   = scratch;             // split-K partials [4][NN][128]
    short* outb = (short*)scratch;     // pre-BN4 bf16 scratch (hp dead by then)

    hipMemsetAsync(ecnt, 0, EE * 4, stream);
    hipMemsetAsync(ncnt, 0, NN * 4, stream);
    hipMemsetAsync(ecur, 0, EE * 4, stream);
    hipMemsetAsync(ncur, 0, NN * 4, stream);

    count_kernel<<<(NNZC + 255) / 256, 256, 0, stream>>>(edge_idx, node_idx, ecnt, ncnt);
    transpose_to_bf16<<<dim3(4, 32), 256, 0, stream>>>(W1, W1T, DIN, 128);
    transpose_to_bf16<<<dim3(32, 4), 256, 0, stream>>>(W2, W2T, 128, DIN);
    scan_two<<<2, 1024, 0, stream>>>(ecnt, eoff, ncnt, noff);
    fill_lists<<<(NNZC + 255) / 256, 256, 0, stream>>>(edge_idx, node_idx, eoff, noff,
                                                       ecur, ncur, elist, nlist);

    const int MB64  = (NN + 63) / 64;     // 469
    const int MB128 = (NN + 127) / 128;   // 235

    // GEMM1 split-K=4 (pure-load pipeline) + combine (bias/leaky + BN1 stats)
    gemm1_splitk<<<4 * MB64, 256, 0, stream>>>(x, W1T, hp);
    hipMemsetAsync(accum, 0, 256 * 4, stream);
    combine_bn1<<<1024, 256, 0, stream>>>(hp, b1, h, spart);
    reduce_stats<<<32, 256, 0, stream>>>(spart, 1024, accum);
    bn_apply_f<false><<<1024, 256, 0, stream>>>(h, nullptr, (long long)NN * 128 / 4, accum,
                                                bn1_g, bn1_b, 1.0f / NN);

    // ---- hconv1 (heads=4), fully linearity-refactored ----
    watt_kernel<4><<<1, 512, 0, stream>>>(h1_lin, h1_att, wax, wae);
    dots128_2<4><<<(NN + 3) / 4, 256, 0, stream>>>(h, wax, wae, ax, axe, NN);
    edge_sum_ae<4><<<EE, 128, 0, stream>>>(elist, eoff, node_idx, axe, ae);
    edge_softmax<4><<<EE, 256, 0, stream>>>(elist, eoff, node_idx, ax, ae, alpha);
    edge_agg128<4><<<EE, 512, 0, stream>>>(elist, eoff, node_idx, alpha, h, agg);
    oute_lin<4><<<EE, 512, 0, stream>>>(agg, h1_lin, oute);
    node_aggregate2<4><<<1875, 256, 0, stream>>>(nlist, noff, edge_idx, alpha, oute, h1_bias,
                                                 h, spart);

    // BN2 (stats fused in node_aggregate2)
    hipMemsetAsync(accum, 0, 256 * 4, stream);
    reduce_stats<<<32, 256, 0, stream>>>(spart, 1875, accum);
    bn_apply_f<false><<<1024, 256, 0, stream>>>(h, nullptr, (long long)NN * 128 / 4, accum,
                                                bn2_g, bn2_b, 1.0f / NN);

    // ---- hconv2 (heads=1) ----
    watt_kernel<1><<<1, 128, 0, stream>>>(h2_lin, h2_att, wax, wae);
    dots128_2<1><<<(NN + 3) / 4, 256, 0, stream>>>(h, wax, wae, ax, axe, NN);
    edge_sum_ae<1><<<EE, 128, 0, stream>>>(elist, eoff, node_idx, axe, ae);
    edge_softmax<1><<<EE, 256, 0, stream>>>(elist, eoff, node_idx, ax, ae, alpha);
    edge_agg128<1><<<EE, 128, 0, stream>>>(elist, eoff, node_idx, alpha, h, agg);
    oute_lin<1><<<EE, 128, 0, stream>>>(agg, h2_lin, oute);
    node_aggregate2<1><<<1875, 256, 0, stream>>>(nlist, noff, edge_idx, alpha, oute, h2_bias,
                                                 h, spart);

    // BN3 (stats fused; shadow feeds W2)
    hipMemsetAsync(accum, 0, 256 * 4, stream);
    reduce_stats<<<32, 256, 0, stream>>>(spart, 1875, accum);
    bn_apply_f<true><<<1024, 256, 0, stream>>>(h, hb, (long long)NN * 128 / 4, accum,
                                               bn3_g, bn3_b, 1.0f / NN);

    // out_pre = x + leaky(hb @ W2 + b2) -> bf16 scratch
    // [MFMA + BN4 partial stats + XCD-bijective swizzle: grid 1880]
    hipMemsetAsync(accum, 0, 256 * 4, stream);
    gemm_mfma<2, true, true, true, true, true, true>
        <<<8 * MB128, 256, 0, stream>>>(hb, W2T, b2, x, outb, spart, NN, 128, DIN, 8);
    reduce_stats<<<32, 256, 0, stream>>>(spart, 8 * MB128, accum);

    // BN4: bf16 -> f32 out
    bn_apply_b2f<<<2048, 256, 0, stream>>>(outb, out, (long long)NN * DIN / 4, accum,
                                           bn4_g, bn4_b, 1.0f / (NN * PP));
}